// Round 1
// baseline (6406.096 us; speedup 1.0000x reference)
//
#include <hip/hip_runtime.h>
#include <stdint.h>

#define TPB 256

static inline int nblk(long n) { return (int)((n + TPB - 1) / TPB); }

// Derive active mask from x (x = randn * mask, so nonzero <=> active, a.s.)
__global__ void make_mask_k(const float* __restrict__ x, uint8_t* __restrict__ m, long n) {
  long i = (long)blockIdx.x * TPB + threadIdx.x;
  if (i < n) m[i] = (x[2 * i] != 0.f) || (x[2 * i + 1] != 0.f);
}

// Generic dense 3x3 SAME conv, NHWC in/out, HWIO weights with slicing strides.
// Output zeroed at inactive sites (submanifold). Inputs assumed zero at inactive.
__global__ void conv3x3_k(const float* __restrict__ x, const float* __restrict__ Wt,
                          float* __restrict__ y, const uint8_t* __restrict__ mask,
                          int H, int W, int Cin, int Cout, int wci, int wco, long total) {
  long tid = (long)blockIdx.x * TPB + threadIdx.x;
  if (tid >= total) return;
  int co = (int)(tid % Cout);
  long site = tid / Cout;
  if (!mask[site]) { y[tid] = 0.f; return; }
  int w = (int)(site % W);
  long t = site / W;
  int h = (int)(t % H);
  int b = (int)(t / H);
  float acc = 0.f;
  for (int kh = 0; kh < 3; ++kh) {
    int hh = h + kh - 1;
    if ((unsigned)hh >= (unsigned)H) continue;
    for (int kw = 0; kw < 3; ++kw) {
      int ww = w + kw - 1;
      if ((unsigned)ww >= (unsigned)W) continue;
      const float* xp = x + (((long)b * H + hh) * W + ww) * Cin;
      const float* wp = Wt + (long)(kh * 3 + kw) * wci * wco + co;
      #pragma unroll 4
      for (int ci = 0; ci < Cin; ++ci)
        acc += xp[ci] * wp[(long)ci * wco];
    }
  }
  y[tid] = acc;
}

// Count active sites -> stats[0]
__global__ void mask_count_k(const uint8_t* __restrict__ m, long n, float* __restrict__ stats) {
  __shared__ float s[TPB];
  float v = 0.f;
  for (long i = (long)blockIdx.x * TPB + threadIdx.x; i < n; i += (long)gridDim.x * TPB)
    v += (float)m[i];
  s[threadIdx.x] = v;
  __syncthreads();
  for (int o = TPB / 2; o > 0; o >>= 1) {
    if (threadIdx.x < o) s[threadIdx.x] += s[threadIdx.x + o];
    __syncthreads();
  }
  if (threadIdx.x == 0) atomicAdd(&stats[0], s[0]);
}

// Per-channel sum & sumsq. C is a power of two <= 256; stride (gridDim*TPB) % C == 0,
// so each thread's channel is constant along its grid-stride walk.
__global__ void bn_stats_k(const float* __restrict__ x, float* __restrict__ stats, long n, int C) {
  __shared__ float ls[512];
  for (int i = threadIdx.x; i < 2 * C; i += TPB) ls[i] = 0.f;
  __syncthreads();
  long t0 = (long)blockIdx.x * TPB + threadIdx.x;
  long stride = (long)gridDim.x * TPB;
  int c = (int)(t0 % C);
  float s = 0.f, s2 = 0.f;
  for (long i = t0; i < n; i += stride) {
    float v = x[i];
    s += v;
    s2 += v * v;
  }
  atomicAdd(&ls[c], s);
  atomicAdd(&ls[C + c], s2);
  __syncthreads();
  for (int i = threadIdx.x; i < 2 * C; i += TPB) atomicAdd(&stats[1 + i], ls[i]);
}

__global__ void bn_apply_k(float* __restrict__ x, const uint8_t* __restrict__ mask,
                           const float* __restrict__ stats, const float* __restrict__ gamma,
                           const float* __restrict__ beta, long n, int C) {
  long i = (long)blockIdx.x * TPB + threadIdx.x;
  if (i >= n) return;
  int c = (int)(i % C);
  long site = i / C;
  if (!mask[site]) { x[i] = 0.f; return; }
  float cnt = fmaxf(stats[0], 1.f);
  float mean = stats[1 + c] / cnt;
  float var = fmaxf(stats[1 + C + c] / cnt - mean * mean, 0.f);
  float v = (x[i] - mean) * rsqrtf(var + 1e-4f) * gamma[c] + beta[c];
  x[i] = fmaxf(v, 0.f);
}

// MaxPool 3x3 stride 2 VALID over active sites; writes new mask (c==0 lane).
__global__ void maxpool_k(const float* __restrict__ x, const uint8_t* __restrict__ min_,
                          float* __restrict__ y, uint8_t* __restrict__ mout,
                          int H, int W, int Ho, int Wo, int C, long total) {
  long tid = (long)blockIdx.x * TPB + threadIdx.x;
  if (tid >= total) return;
  int c = (int)(tid % C);
  long os = tid / C;
  int wo = (int)(os % Wo);
  long t = os / Wo;
  int ho = (int)(t % Ho);
  int b = (int)(t / Ho);
  float best = -1e30f;
  int any = 0;
  for (int kh = 0; kh < 3; ++kh) {
    int h = 2 * ho + kh;
    for (int kw = 0; kw < 3; ++kw) {
      int w = 2 * wo + kw;
      long is = ((long)b * H + h) * W + w;
      if (min_[is]) {
        any = 1;
        best = fmaxf(best, x[is * C + c]);
      }
    }
  }
  y[tid] = any ? best : 0.f;
  if (c == 0) mout[os] = (uint8_t)any;
}

// h = sigmoid(yg) * tanh(yc) * mask
__global__ void gru_pw_k(const float* __restrict__ yg, const float* __restrict__ yc,
                         const uint8_t* __restrict__ m, float* __restrict__ h, long n, int C) {
  long i = (long)blockIdx.x * TPB + threadIdx.x;
  if (i >= n) return;
  long site = i / C;
  float u = 1.f / (1.f + expf(-yg[i]));
  float c = tanhf(yc[i]);
  h[i] = m[site] ? (u * c) : 0.f;
}

// linear1 partials: dense[b, k=c*35+s] = h2[b*8960 + s*256 + c]; W1 [8960,1024]
// grid (KSPLIT=16, 4), 256 thr; each block: k-chunk of 560 (=16*35), j-chunk of 256.
#define KSPLIT 16
__global__ void lin1_part_k(const float* __restrict__ h2, const float* __restrict__ W1,
                            float* __restrict__ part) {
  int j = blockIdx.y * TPB + threadIdx.x;
  int kc = blockIdx.x;
  float acc[32];
  #pragma unroll
  for (int b = 0; b < 32; ++b) acc[b] = 0.f;
  int k0 = kc * 560, k1 = k0 + 560;
  for (int k = k0; k < k1; ++k) {
    float w = W1[(long)k * 1024 + j];
    int c = k / 35, s = k - c * 35;
    const float* hp = h2 + s * 256 + c;
    #pragma unroll
    for (int b = 0; b < 32; ++b) acc[b] += hp[(long)b * 8960] * w;
  }
  #pragma unroll
  for (int b = 0; b < 32; ++b) part[((long)(kc * 32 + b)) * 1024 + j] = acc[b];
}

__global__ void lin1_reduce_k(const float* __restrict__ part, const float* __restrict__ b1,
                              float* __restrict__ y1) {
  int i = blockIdx.x * TPB + threadIdx.x;
  if (i >= 32 * 1024) return;
  int b = i >> 10, j = i & 1023;
  float a = b1[j];
  #pragma unroll
  for (int kc = 0; kc < KSPLIT; ++kc) a += part[((long)(kc * 32 + b)) * 1024 + j];
  y1[i] = fmaxf(a, 0.f);
}

__global__ void lin2_k(const float* __restrict__ y1, const float* __restrict__ W2,
                       const float* __restrict__ b2, float* __restrict__ out) {
  int i = blockIdx.x * TPB + threadIdx.x;
  if (i >= 32 * 420) return;
  int b = i / 420, o = i - b * 420;
  float a = b2[o];
  const float* yp = y1 + b * 1024;
  for (int j = 0; j < 1024; ++j) a += yp[j] * W2[(long)j * 420 + o];
  out[i] = a;
}

extern "C" void kernel_launch(void* const* d_in, const int* in_sizes, int n_in,
                              void* d_out, int out_size, void* d_ws, size_t ws_size,
                              hipStream_t stream) {
  const float* x = (const float*)d_in[0];
  const float* ca[5] = {(const float*)d_in[2], (const float*)d_in[6], (const float*)d_in[10],
                        (const float*)d_in[14], (const float*)d_in[18]};
  const float* bg[5] = {(const float*)d_in[3], (const float*)d_in[7], (const float*)d_in[11],
                        (const float*)d_in[15], (const float*)d_in[19]};
  const float* bb[5] = {(const float*)d_in[4], (const float*)d_in[8], (const float*)d_in[12],
                        (const float*)d_in[16], (const float*)d_in[20]};
  const float* cb[5] = {(const float*)d_in[5], (const float*)d_in[9], (const float*)d_in[13],
                        (const float*)d_in[17], (const float*)d_in[21]};
  const float* g1Wg = (const float*)d_in[22];
  const float* g1Wc = (const float*)d_in[23];
  const float* g2Wg = (const float*)d_in[24];
  const float* g2Wc = (const float*)d_in[25];
  const float* W1 = (const float*)d_in[26];
  const float* b1 = (const float*)d_in[27];
  const float* W2 = (const float*)d_in[28];
  const float* b2 = (const float*)d_in[29];

  const int Hs[6] = {191, 95, 47, 23, 11, 5};
  const int Ws_[6] = {255, 127, 63, 31, 15, 7};
  const int Cs[6] = {2, 16, 32, 64, 128, 256};

  float* ws = (float*)d_ws;
  const long NS1 = 32L * 191 * 255;   // 1,558,560 sites at level-1 input
  const long BUF = NS1 * 16;          // 24,936,960 floats (max feature map)
  long off = 0;
  float* bufA = ws + off;  off += BUF;
  float* bufB = ws + off;  off += BUF;
  float* stats = ws + off; off += 1024;
  float* y1 = ws + off;    off += 32L * 1024;
  float* part = ws + off;  off += (long)KSPLIT * 32 * 1024;
  float* yg = ws + off;    off += 286720;
  float* yc = ws + off;    off += 286720;
  uint8_t* mb = (uint8_t*)(ws + off);
  long msz[6], mo[6], mtot = 0;
  for (int l = 0; l < 6; ++l) {
    msz[l] = 32L * Hs[l] * Ws_[l];
    mo[l] = mtot;
    mtot += msz[l];
  }
  size_t needed = (size_t)off * 4 + (size_t)mtot;
  if (ws_size < needed) return;  // scratch too small; bail without corrupting memory

  uint8_t* mk[6];
  for (int l = 0; l < 6; ++l) mk[l] = mb + mo[l];

  // mask from x
  make_mask_k<<<nblk(NS1), TPB, 0, stream>>>(x, mk[0], NS1);

  const float* cur = x;
  for (int l = 0; l < 5; ++l) {
    int H = Hs[l], W = Ws_[l], Ci = Cs[l], Co = Cs[l + 1];
    long nsites = 32L * H * W;
    long ncA = nsites * Co;
    float* t1 = (cur == bufA) ? bufB : bufA;
    float* t2 = (t1 == bufA) ? bufB : bufA;
    // conv a
    conv3x3_k<<<nblk(ncA), TPB, 0, stream>>>(cur, ca[l], t1, mk[l], H, W, Ci, Co, Ci, Co, ncA);
    // BN + ReLU over active sites
    hipMemsetAsync(stats, 0, 1024 * 4, stream);
    mask_count_k<<<(nsites > 512L * TPB ? 512 : nblk(nsites)), TPB, 0, stream>>>(mk[l], nsites, stats);
    int sblk = nblk(ncA); if (sblk > 4096) sblk = 4096;
    bn_stats_k<<<sblk, TPB, 0, stream>>>(t1, stats, ncA, Co);
    bn_apply_k<<<nblk(ncA), TPB, 0, stream>>>(t1, mk[l], stats, bg[l], bb[l], ncA, Co);
    // conv b
    conv3x3_k<<<nblk(ncA), TPB, 0, stream>>>(t1, cb[l], t2, mk[l], H, W, Co, Co, Co, Co, ncA);
    // pool
    int Ho = Hs[l + 1], Wo = Ws_[l + 1];
    long ncP = 32L * Ho * Wo * Co;
    maxpool_k<<<nblk(ncP), TPB, 0, stream>>>(t2, mk[l], t1, mk[l + 1], H, W, Ho, Wo, Co, ncP);
    cur = t1;
  }

  // GRUs (hidden state zero => only first 256 input channels / u-half of Wg matter)
  float* h1 = (float*)d_out + 13440;
  float* h2 = h1 + 286720;
  long ng = 286720;
  // GRU 1
  conv3x3_k<<<nblk(ng), TPB, 0, stream>>>(cur, g1Wg, yg, mk[5], 5, 7, 256, 256, 512, 512, ng);
  conv3x3_k<<<nblk(ng), TPB, 0, stream>>>(cur, g1Wc, yc, mk[5], 5, 7, 256, 256, 512, 256, ng);
  gru_pw_k<<<nblk(ng), TPB, 0, stream>>>(yg, yc, mk[5], h1, ng, 256);
  // GRU 2
  conv3x3_k<<<nblk(ng), TPB, 0, stream>>>(h1, g2Wg, yg, mk[5], 5, 7, 256, 256, 512, 512, ng);
  conv3x3_k<<<nblk(ng), TPB, 0, stream>>>(h1, g2Wc, yc, mk[5], 5, 7, 256, 256, 512, 256, ng);
  gru_pw_k<<<nblk(ng), TPB, 0, stream>>>(yg, yc, mk[5], h2, ng, 256);

  // Head
  lin1_part_k<<<dim3(KSPLIT, 4), TPB, 0, stream>>>(h2, W1, part);
  lin1_reduce_k<<<nblk(32L * 1024), TPB, 0, stream>>>(part, b1, y1);
  lin2_k<<<nblk(32L * 420), TPB, 0, stream>>>(y1, W2, b2, (float*)d_out);
}

// Round 2
// 2377.875 us; speedup vs baseline: 2.6940x; 2.6940x over previous
//
#include <hip/hip_runtime.h>
#include <stdint.h>

#define TPB 256

static inline int nblk(long n) { return (int)((n + TPB - 1) / TPB); }
static inline int gmin(long a, long b) { return (int)(a < b ? a : b); }

// ---------- compaction ----------
__device__ __forceinline__ int ballot_pos(bool a, int* cnt) {
  unsigned long long b = __ballot(a);
  int lane = threadIdx.x & 63;
  int base = 0;
  if (b) {
    int leader = __ffsll((long long)b) - 1;
    if (lane == leader) base = atomicAdd(cnt, __popcll(b));
    base = __shfl(base, leader);
  }
  if (!a) return -1;
  return base + __popcll(b & ((1ull << lane) - 1));
}

__global__ void compact0_k(const float* __restrict__ x, int n, int* __restrict__ list,
                           int* __restrict__ inv, int* __restrict__ cnt, int cap) {
  int i = blockIdx.x * TPB + threadIdx.x;
  bool a = (i < n) && ((x[2L * i] != 0.f) || (x[2L * i + 1] != 0.f));
  int pos = ballot_pos(a, cnt);
  if (i < n) {
    if (a && pos < cap) { list[pos] = i; inv[i] = pos; }
    else inv[i] = -1;
  }
}

// new-level activity from prev-level inv (3x3 stride-2 window)
__global__ void pool_compact_k(const int* __restrict__ invp, int Hp, int Wp, int Ho, int Wo,
                               int n, int* __restrict__ list, int* __restrict__ inv,
                               int* __restrict__ cnt, int cap) {
  int i = blockIdx.x * TPB + threadIdx.x;
  bool a = false;
  if (i < n) {
    int wo = i % Wo; int t = i / Wo; int ho = t % Ho; int bb = t / Ho;
    long rb = ((long)bb * Hp + 2 * ho) * Wp + 2 * wo;
    for (int kh = 0; kh < 3; ++kh)
      for (int kw = 0; kw < 3; ++kw)
        a |= (invp[rb + kh * Wp + kw] >= 0);
  }
  int pos = ballot_pos(a, cnt);
  if (i < n) {
    if (a && pos < cap) { list[pos] = i; inv[i] = pos; }
    else inv[i] = -1;
  }
}

// ---------- pooled values (compact rows) ----------
template <int C>
__global__ void pool_val_k(const float* __restrict__ xin, const int* __restrict__ invp,
                           const int* __restrict__ list, const int* __restrict__ cnt,
                           int Hp, int Wp, int Ho, int Wo, float* __restrict__ y) {
  long total = (long)cnt[0] * C;
  for (long i = (long)blockIdx.x * TPB + threadIdx.x; i < total; i += (long)gridDim.x * TPB) {
    int c = (int)(i & (C - 1));
    int r = (int)(i / C);
    int site = list[r];
    int wo = site % Wo; int t = site / Wo; int ho = t % Ho; int bb = t / Ho;
    long rb = ((long)bb * Hp + 2 * ho) * Wp + 2 * wo;
    float best = -1e30f;
    #pragma unroll
    for (int kh = 0; kh < 3; ++kh)
      #pragma unroll
      for (int kw = 0; kw < 3; ++kw) {
        int j = invp[rb + kh * Wp + kw];
        if (j >= 0) best = fmaxf(best, xin[(long)j * C + c]);
      }
    y[i] = best;
  }
}

// ---------- submanifold conv over compacted active list ----------
// block: NCOL=CO/4 weight-columns x SG site-groups; thread: 4(co) x ACC(sites) accs.
template <int CI, int CO, int ACC, bool BN, int NSP>
__global__ void sconv_k(const float* __restrict__ xin, const float* __restrict__ Wt,
                        float* __restrict__ y, const int* __restrict__ inv,
                        const int* __restrict__ list, const int* __restrict__ cnt,
                        const float* __restrict__ bnsc, int H, int W, int wci, int wco,
                        int dense_in) {
  constexpr int CW = 4;
  constexpr int NCOL = CO / CW;
  constexpr int SG = TPB / NCOL;
  constexpr int S = SG * ACC;
  constexpr int CIP = CI + 1;
  __shared__ float st[S * CIP];
  __shared__ int nbr[S * 9];
  const int nact = cnt[0];
  const int col = threadIdx.x % NCOL;
  const int sg = threadIdx.x / NCOL;
  const int co0 = col * CW;
  const int nb0 = (NSP > 1) ? blockIdx.y * (9 / NSP) : 0;
  const int nb1 = (NSP > 1) ? nb0 + (9 / NSP) : 9;
  for (int base = blockIdx.x * S; base < nact; base += gridDim.x * S) {
    int ns = min(S, nact - base);
    // phase A: neighbor rows for this chunk
    for (int i = threadIdx.x; i < ns * 9; i += TPB) {
      int s = i / 9, nb = i - s * 9;
      int site = list[base + s];
      int w = site % W; int t = site / W; int h = t % H; int bb = t / H;
      int hh = h + nb / 3 - 1, ww = w + (nb - (nb / 3) * 3) - 1;
      int j = -1;
      if ((unsigned)hh < (unsigned)H && (unsigned)ww < (unsigned)W) {
        int ss = (bb * H + hh) * W + ww;
        j = dense_in ? ss : inv[ss];
      }
      nbr[i] = j;
    }
    __syncthreads();
    float acc[CW][ACC];
    #pragma unroll
    for (int q = 0; q < CW; ++q)
      #pragma unroll
      for (int a = 0; a < ACC; ++a) acc[q][a] = 0.f;
    for (int nb = nb0; nb < nb1; ++nb) {
      // stage S x CI inputs for this tap (BN/ReLU fused for conv_b)
      for (int i = threadIdx.x; i < ns * CI; i += TPB) {
        int s = i / CI, ci = i - s * CI;
        int j = nbr[s * 9 + nb];
        float v = 0.f;
        if (j >= 0) {
          v = xin[(long)j * CI + ci];
          if (BN) v = fmaxf(fmaf(v, bnsc[ci], bnsc[CI + ci]), 0.f);
        }
        st[s * CIP + ci] = v;
      }
      __syncthreads();
      const float* wp = Wt + (long)(nb * wci) * wco + co0;
      const float* sp = st + sg * ACC * CIP;
      #pragma unroll 4
      for (int ci = 0; ci < CI; ++ci) {
        float4 wv = *(const float4*)(wp + (long)ci * wco);
        #pragma unroll
        for (int a = 0; a < ACC; ++a) {
          float xv = sp[a * CIP + ci];
          acc[0][a] = fmaf(xv, wv.x, acc[0][a]);
          acc[1][a] = fmaf(xv, wv.y, acc[1][a]);
          acc[2][a] = fmaf(xv, wv.z, acc[2][a]);
          acc[3][a] = fmaf(xv, wv.w, acc[3][a]);
        }
      }
      __syncthreads();
    }
    #pragma unroll
    for (int a = 0; a < ACC; ++a) {
      int s = sg * ACC + a;
      if (s < ns) {
        float* yp = y + (long)(base + s) * CO + co0;
        if (NSP > 1) {
          atomicAdd(yp + 0, acc[0][a]); atomicAdd(yp + 1, acc[1][a]);
          atomicAdd(yp + 2, acc[2][a]); atomicAdd(yp + 3, acc[3][a]);
        } else {
          float4 o; o.x = acc[0][a]; o.y = acc[1][a]; o.z = acc[2][a]; o.w = acc[3][a];
          *(float4*)yp = o;
        }
      }
    }
  }
}

// ---------- BN stats over compacted rows ----------
template <int CO>
__global__ void bn_stats2_k(const float* __restrict__ y, const int* __restrict__ cnt,
                            float* __restrict__ stats) {
  __shared__ float ls[512];
  for (int i = threadIdx.x; i < 2 * CO; i += TPB) ls[i] = 0.f;
  __syncthreads();
  long total = (long)cnt[0] * CO;
  long i0 = (long)blockIdx.x * TPB + threadIdx.x;
  int c = (int)(i0 & (CO - 1));
  float s = 0.f, s2 = 0.f;
  for (long i = i0; i < total; i += (long)gridDim.x * TPB) {
    float v = y[i];
    s += v; s2 += v * v;
  }
  atomicAdd(&ls[c], s);
  atomicAdd(&ls[CO + c], s2);
  __syncthreads();
  for (int i = threadIdx.x; i < 2 * CO; i += TPB) atomicAdd(&stats[i], ls[i]);
}

__global__ void bn_fin_k(const float* __restrict__ stats, const int* __restrict__ cnt,
                         const float* __restrict__ gamma, const float* __restrict__ beta,
                         float* __restrict__ bnsc, int CO) {
  int c = threadIdx.x;
  if (c >= CO) return;
  float n = fmaxf((float)cnt[0], 1.f);
  float mean = stats[c] / n;
  float var = fmaxf(stats[CO + c] / n - mean * mean, 0.f);
  float sc = gamma[c] * rsqrtf(var + 1e-4f);
  bnsc[c] = sc;
  bnsc[CO + c] = beta[c] - mean * sc;
}

// ---------- GRU pointwise: h = sigmoid(yg)*tanh(yc); scatter to dense ----------
__global__ void gru_pw2_k(const float* __restrict__ yg, const float* __restrict__ yc,
                          const int* __restrict__ list, const int* __restrict__ cnt,
                          float* __restrict__ hdense, float* __restrict__ hcomp) {
  long total = (long)cnt[0] * 256;
  for (long i = (long)blockIdx.x * TPB + threadIdx.x; i < total; i += (long)gridDim.x * TPB) {
    float u = 1.f / (1.f + expf(-yg[i]));
    float c = tanhf(yc[i]);
    float v = u * c;
    if (hcomp) hcomp[i] = v;
    int r = (int)(i >> 8), co = (int)(i & 255);
    hdense[(long)list[r] * 256 + co] = v;
  }
}

// ---------- head ----------
#define KSPLIT 16
__global__ void lin1_part_k(const float* __restrict__ h2, const float* __restrict__ W1,
                            float* __restrict__ part) {
  int j = blockIdx.y * TPB + threadIdx.x;
  int kc = blockIdx.x;
  float acc[32];
  #pragma unroll
  for (int b = 0; b < 32; ++b) acc[b] = 0.f;
  int k0 = kc * 560, k1 = k0 + 560;
  for (int k = k0; k < k1; ++k) {
    float w = W1[(long)k * 1024 + j];
    int c = k / 35, s = k - c * 35;
    const float* hp = h2 + s * 256 + c;
    #pragma unroll
    for (int b = 0; b < 32; ++b) acc[b] += hp[(long)b * 8960] * w;
  }
  #pragma unroll
  for (int b = 0; b < 32; ++b) part[((long)(kc * 32 + b)) * 1024 + j] = acc[b];
}

__global__ void lin1_reduce_k(const float* __restrict__ part, const float* __restrict__ b1,
                              float* __restrict__ y1) {
  int i = blockIdx.x * TPB + threadIdx.x;
  if (i >= 32 * 1024) return;
  int b = i >> 10, j = i & 1023;
  float a = b1[j];
  #pragma unroll
  for (int kc = 0; kc < KSPLIT; ++kc) a += part[((long)(kc * 32 + b)) * 1024 + j];
  y1[i] = fmaxf(a, 0.f);
}

__global__ void lin2_k(const float* __restrict__ y1, const float* __restrict__ W2,
                       const float* __restrict__ b2, float* __restrict__ out) {
  int i = blockIdx.x * TPB + threadIdx.x;
  if (i >= 32 * 420) return;
  int b = i / 420, o = i - b * 420;
  float a = b2[o];
  const float* yp = y1 + b * 1024;
  for (int j = 0; j < 1024; ++j) a += yp[j] * W2[(long)j * 420 + o];
  out[i] = a;
}

extern "C" void kernel_launch(void* const* d_in, const int* in_sizes, int n_in,
                              void* d_out, int out_size, void* d_ws, size_t ws_size,
                              hipStream_t stream) {
  const float* x = (const float*)d_in[0];
  const float* ca[5] = {(const float*)d_in[2], (const float*)d_in[6], (const float*)d_in[10],
                        (const float*)d_in[14], (const float*)d_in[18]};
  const float* bg[5] = {(const float*)d_in[3], (const float*)d_in[7], (const float*)d_in[11],
                        (const float*)d_in[15], (const float*)d_in[19]};
  const float* bb[5] = {(const float*)d_in[4], (const float*)d_in[8], (const float*)d_in[12],
                        (const float*)d_in[16], (const float*)d_in[20]};
  const float* cb[5] = {(const float*)d_in[5], (const float*)d_in[9], (const float*)d_in[13],
                        (const float*)d_in[17], (const float*)d_in[21]};
  const float* g1Wg = (const float*)d_in[22];
  const float* g1Wc = (const float*)d_in[23];
  const float* g2Wg = (const float*)d_in[24];
  const float* g2Wc = (const float*)d_in[25];
  const float* W1 = (const float*)d_in[26];
  const float* b1 = (const float*)d_in[27];
  const float* W2 = (const float*)d_in[28];
  const float* b2 = (const float*)d_in[29];

  const int Hs[6] = {191, 95, 47, 23, 11, 5};
  const int Wd[6] = {255, 127, 63, 31, 15, 7};
  const long NS[6] = {1558560, 386080, 94752, 22816, 5280, 1120};
  const int cap[6] = {400000, 386080, 94752, 22816, 5280, 1120};

  // ---- workspace layout (floats then ints) ----
  float* ws = (float*)d_ws;
  const long BUF = 12354560;  // max rows*C = NS[1]*32
  long off = 0;
  float* bufA = ws + off; off += BUF;
  float* bufB = ws + off; off += BUF;
  float* yg = ws + off;   off += 286720;
  float* yc = ws + off;   off += 286720;
  float* h1c = ws + off;  off += 286720;
  float* stats = ws + off; off += 512;
  float* bnsc = ws + off;  off += 512;
  float* y1 = ws + off;    off += 32L * 1024;
  float* part = ws + off;  off += (long)KSPLIT * 32 * 1024;
  int* ip = (int*)(ws + off);
  long ioff = 0;
  int* cnt = ip + ioff; ioff += 16;
  int* list[6]; int* inv[6];
  for (int l = 0; l < 6; ++l) { list[l] = ip + ioff; ioff += cap[l]; }
  for (int l = 0; l < 6; ++l) { inv[l] = ip + ioff; ioff += NS[l]; }
  size_t needed = (size_t)off * 4 + (size_t)ioff * 4;
  if (ws_size < needed) return;

  float* h1d = (float*)d_out + 13440;
  float* h2d = h1d + 286720;

  hipMemsetAsync(cnt, 0, 16 * 4, stream);
  compact0_k<<<nblk(NS[0]), TPB, 0, stream>>>(x, (int)NS[0], list[0], inv[0], cnt + 0, cap[0]);

  // ---------- level 1: (2->16), (16->16) ----------
  hipMemsetAsync(stats, 0, 512 * 4, stream);
  sconv_k<2, 16, 8, false, 1><<<gmin((cap[0] + 511) / 512, 1024), TPB, 0, stream>>>(
      x, ca[0], bufA, nullptr, list[0], cnt + 0, nullptr, Hs[0], Wd[0], 2, 16, 1);
  bn_stats2_k<16><<<1024, TPB, 0, stream>>>(bufA, cnt + 0, stats);
  bn_fin_k<<<1, 256, 0, stream>>>(stats, cnt + 0, bg[0], bb[0], bnsc, 16);
  sconv_k<16, 16, 4, true, 1><<<gmin((cap[0] + 255) / 256, 1024), TPB, 0, stream>>>(
      bufA, cb[0], bufB, inv[0], list[0], cnt + 0, bnsc, Hs[0], Wd[0], 16, 16, 0);
  pool_compact_k<<<nblk(NS[1]), TPB, 0, stream>>>(inv[0], Hs[0], Wd[0], Hs[1], Wd[1],
                                                  (int)NS[1], list[1], inv[1], cnt + 1, cap[1]);
  pool_val_k<16><<<2048, TPB, 0, stream>>>(bufB, inv[0], list[1], cnt + 1, Hs[0], Wd[0], Hs[1], Wd[1], bufA);

  // ---------- level 2: (16->32), (32->32) ----------
  hipMemsetAsync(stats, 0, 512 * 4, stream);
  sconv_k<16, 32, 8, false, 1><<<gmin((NS[1] + 255) / 256, 1024), TPB, 0, stream>>>(
      bufA, ca[1], bufB, inv[1], list[1], cnt + 1, nullptr, Hs[1], Wd[1], 16, 32, 0);
  bn_stats2_k<32><<<1024, TPB, 0, stream>>>(bufB, cnt + 1, stats);
  bn_fin_k<<<1, 256, 0, stream>>>(stats, cnt + 1, bg[1], bb[1], bnsc, 32);
  sconv_k<32, 32, 4, true, 1><<<gmin((NS[1] + 127) / 128, 1024), TPB, 0, stream>>>(
      bufB, cb[1], bufA, inv[1], list[1], cnt + 1, bnsc, Hs[1], Wd[1], 32, 32, 0);
  pool_compact_k<<<nblk(NS[2]), TPB, 0, stream>>>(inv[1], Hs[1], Wd[1], Hs[2], Wd[2],
                                                  (int)NS[2], list[2], inv[2], cnt + 2, cap[2]);
  pool_val_k<32><<<2048, TPB, 0, stream>>>(bufA, inv[1], list[2], cnt + 2, Hs[1], Wd[1], Hs[2], Wd[2], bufB);

  // ---------- level 3: (32->64), (64->64) ----------
  hipMemsetAsync(stats, 0, 512 * 4, stream);
  sconv_k<32, 64, 8, false, 1><<<gmin((NS[2] + 127) / 128, 1024), TPB, 0, stream>>>(
      bufB, ca[2], bufA, inv[2], list[2], cnt + 2, nullptr, Hs[2], Wd[2], 32, 64, 0);
  bn_stats2_k<64><<<1024, TPB, 0, stream>>>(bufA, cnt + 2, stats);
  bn_fin_k<<<1, 256, 0, stream>>>(stats, cnt + 2, bg[2], bb[2], bnsc, 64);
  sconv_k<64, 64, 4, true, 1><<<gmin((NS[2] + 63) / 64, 1024), TPB, 0, stream>>>(
      bufA, cb[2], bufB, inv[2], list[2], cnt + 2, bnsc, Hs[2], Wd[2], 64, 64, 0);
  pool_compact_k<<<nblk(NS[3]), TPB, 0, stream>>>(inv[2], Hs[2], Wd[2], Hs[3], Wd[3],
                                                  (int)NS[3], list[3], inv[3], cnt + 3, cap[3]);
  pool_val_k<64><<<2048, TPB, 0, stream>>>(bufB, inv[2], list[3], cnt + 3, Hs[2], Wd[2], Hs[3], Wd[3], bufA);

  // ---------- level 4: (64->128), (128->128) ----------
  hipMemsetAsync(stats, 0, 512 * 4, stream);
  sconv_k<64, 128, 8, false, 1><<<gmin((NS[3] + 63) / 64, 1024), TPB, 0, stream>>>(
      bufA, ca[3], bufB, inv[3], list[3], cnt + 3, nullptr, Hs[3], Wd[3], 64, 128, 0);
  bn_stats2_k<128><<<1024, TPB, 0, stream>>>(bufB, cnt + 3, stats);
  bn_fin_k<<<1, 256, 0, stream>>>(stats, cnt + 3, bg[3], bb[3], bnsc, 128);
  sconv_k<128, 128, 4, true, 1><<<gmin((NS[3] + 31) / 32, 1024), TPB, 0, stream>>>(
      bufB, cb[3], bufA, inv[3], list[3], cnt + 3, bnsc, Hs[3], Wd[3], 128, 128, 0);
  pool_compact_k<<<nblk(NS[4]), TPB, 0, stream>>>(inv[3], Hs[3], Wd[3], Hs[4], Wd[4],
                                                  (int)NS[4], list[4], inv[4], cnt + 4, cap[4]);
  pool_val_k<128><<<2048, TPB, 0, stream>>>(bufA, inv[3], list[4], cnt + 4, Hs[3], Wd[3], Hs[4], Wd[4], bufB);

  // ---------- level 5: (128->256), (256->256), k-split ----------
  hipMemsetAsync(stats, 0, 512 * 4, stream);
  hipMemsetAsync(bufA, 0, 5280L * 256 * 4, stream);
  sconv_k<128, 256, 8, false, 3><<<dim3((NS[4] + 31) / 32, 3), TPB, 0, stream>>>(
      bufB, ca[4], bufA, inv[4], list[4], cnt + 4, nullptr, Hs[4], Wd[4], 128, 256, 0);
  bn_stats2_k<256><<<1024, TPB, 0, stream>>>(bufA, cnt + 4, stats);
  bn_fin_k<<<1, 256, 0, stream>>>(stats, cnt + 4, bg[4], bb[4], bnsc, 256);
  hipMemsetAsync(bufB, 0, 5280L * 256 * 4, stream);
  sconv_k<256, 256, 8, true, 3><<<dim3((NS[4] + 31) / 32, 3), TPB, 0, stream>>>(
      bufA, cb[4], bufB, inv[4], list[4], cnt + 4, bnsc, Hs[4], Wd[4], 256, 256, 0);
  pool_compact_k<<<nblk(NS[5]), TPB, 0, stream>>>(inv[4], Hs[4], Wd[4], Hs[5], Wd[5],
                                                  (int)NS[5], list[5], inv[5], cnt + 5, cap[5]);
  pool_val_k<256><<<1024, TPB, 0, stream>>>(bufB, inv[4], list[5], cnt + 5, Hs[4], Wd[4], Hs[5], Wd[5], bufA);

  // ---------- GRUs (h=0: h' = sigmoid(conv_u) * tanh(conv_c)) ----------
  long ngb = 286720L * 4;
  hipMemsetAsync(yg, 0, ngb, stream);
  hipMemsetAsync(yc, 0, ngb, stream);
  hipMemsetAsync(h1d, 0, ngb, stream);
  hipMemsetAsync(h2d, 0, ngb, stream);
  sconv_k<256, 256, 4, false, 3><<<dim3((NS[5] + 15) / 16, 3), TPB, 0, stream>>>(
      bufA, g1Wg, yg, inv[5], list[5], cnt + 5, nullptr, Hs[5], Wd[5], 512, 512, 0);
  sconv_k<256, 256, 4, false, 3><<<dim3((NS[5] + 15) / 16, 3), TPB, 0, stream>>>(
      bufA, g1Wc, yc, inv[5], list[5], cnt + 5, nullptr, Hs[5], Wd[5], 512, 256, 0);
  gru_pw2_k<<<512, TPB, 0, stream>>>(yg, yc, list[5], cnt + 5, h1d, h1c);
  hipMemsetAsync(yg, 0, ngb, stream);
  hipMemsetAsync(yc, 0, ngb, stream);
  sconv_k<256, 256, 4, false, 3><<<dim3((NS[5] + 15) / 16, 3), TPB, 0, stream>>>(
      h1c, g2Wg, yg, inv[5], list[5], cnt + 5, nullptr, Hs[5], Wd[5], 512, 512, 0);
  sconv_k<256, 256, 4, false, 3><<<dim3((NS[5] + 15) / 16, 3), TPB, 0, stream>>>(
      h1c, g2Wc, yc, inv[5], list[5], cnt + 5, nullptr, Hs[5], Wd[5], 512, 256, 0);
  gru_pw2_k<<<512, TPB, 0, stream>>>(yg, yc, list[5], cnt + 5, h2d, nullptr);

  // ---------- head ----------
  lin1_part_k<<<dim3(KSPLIT, 4), TPB, 0, stream>>>(h2d, W1, part);
  lin1_reduce_k<<<nblk(32L * 1024), TPB, 0, stream>>>(part, b1, y1);
  lin2_k<<<nblk(32L * 420), TPB, 0, stream>>>(y1, W2, b2, (float*)d_out);
}

// Round 3
// 1918.775 us; speedup vs baseline: 3.3386x; 1.2393x over previous
//
#include <hip/hip_runtime.h>
#include <stdint.h>

#define TPB 256

static inline int nblk(long n) { return (int)((n + TPB - 1) / TPB); }
static inline int gmin(long a, long b) { return (int)(a < b ? a : b); }

// ---------- scan-based compaction (no global atomics) ----------
__device__ __forceinline__ bool act0(const float* x, int i) {
  float2 v = *(const float2*)(x + 2L * i);
  return (v.x != 0.f) || (v.y != 0.f);
}

__global__ void cmpA0_k(const float* __restrict__ x, int n, int* __restrict__ bcnt) {
  int i = blockIdx.x * TPB + threadIdx.x;
  bool a = (i < n) && act0(x, i);
  unsigned long long bal = __ballot(a);
  __shared__ int wc[4];
  if ((threadIdx.x & 63) == 0) wc[threadIdx.x >> 6] = __popcll(bal);
  __syncthreads();
  if (threadIdx.x == 0) bcnt[blockIdx.x] = wc[0] + wc[1] + wc[2] + wc[3];
}

__global__ void cmpB0_k(const float* __restrict__ x, int n, const int* __restrict__ bbase,
                        int* __restrict__ list, int* __restrict__ inv, int cap) {
  int i = blockIdx.x * TPB + threadIdx.x;
  bool a = (i < n) && act0(x, i);
  unsigned long long bal = __ballot(a);
  __shared__ int wc[4];
  int wid = threadIdx.x >> 6, lane = threadIdx.x & 63;
  if (lane == 0) wc[wid] = __popcll(bal);
  __syncthreads();
  int base = bbase[blockIdx.x];
  for (int w = 0; w < wid; ++w) base += wc[w];
  if (i < n) {
    int pos = base + __popcll(bal & ((1ull << lane) - 1));
    if (a && pos < cap) { list[pos] = i; inv[i] = pos; }
    else inv[i] = -1;
  }
}

__device__ __forceinline__ bool actp(const int* invp, int Hp, int Wp, int Ho, int Wo, int i) {
  int wo = i % Wo; int t = i / Wo; int ho = t % Ho; int bb = t / Ho;
  long rb = ((long)bb * Hp + 2 * ho) * Wp + 2 * wo;
  bool a = false;
  #pragma unroll
  for (int kh = 0; kh < 3; ++kh)
    #pragma unroll
    for (int kw = 0; kw < 3; ++kw)
      a |= (invp[rb + kh * Wp + kw] >= 0);
  return a;
}

__global__ void poolA_k(const int* __restrict__ invp, int Hp, int Wp, int Ho, int Wo,
                        int n, int* __restrict__ bcnt) {
  int i = blockIdx.x * TPB + threadIdx.x;
  bool a = (i < n) && actp(invp, Hp, Wp, Ho, Wo, i);
  unsigned long long bal = __ballot(a);
  __shared__ int wc[4];
  if ((threadIdx.x & 63) == 0) wc[threadIdx.x >> 6] = __popcll(bal);
  __syncthreads();
  if (threadIdx.x == 0) bcnt[blockIdx.x] = wc[0] + wc[1] + wc[2] + wc[3];
}

__global__ void poolB_k(const int* __restrict__ invp, int Hp, int Wp, int Ho, int Wo, int n,
                        const int* __restrict__ bbase, int* __restrict__ list,
                        int* __restrict__ inv, int cap) {
  int i = blockIdx.x * TPB + threadIdx.x;
  bool a = (i < n) && actp(invp, Hp, Wp, Ho, Wo, i);
  unsigned long long bal = __ballot(a);
  __shared__ int wc[4];
  int wid = threadIdx.x >> 6, lane = threadIdx.x & 63;
  if (lane == 0) wc[wid] = __popcll(bal);
  __syncthreads();
  int base = bbase[blockIdx.x];
  for (int w = 0; w < wid; ++w) base += wc[w];
  if (i < n) {
    int pos = base + __popcll(bal & ((1ull << lane) - 1));
    if (a && pos < cap) { list[pos] = i; inv[i] = pos; }
    else inv[i] = -1;
  }
}

// single-block exclusive scan of bcnt[0..n); total -> *total
__global__ void scan_k(int* __restrict__ b, int n, int* __restrict__ total) {
  __shared__ int sh[1024];
  __shared__ int sc;
  if (threadIdx.x == 0) sc = 0;
  __syncthreads();
  for (int base = 0; base < n; base += 1024) {
    int i = base + threadIdx.x;
    int v = (i < n) ? b[i] : 0;
    sh[threadIdx.x] = v;
    __syncthreads();
    for (int o = 1; o < 1024; o <<= 1) {
      int t = (threadIdx.x >= o) ? sh[threadIdx.x - o] : 0;
      __syncthreads();
      sh[threadIdx.x] += t;
      __syncthreads();
    }
    if (i < n) b[i] = sh[threadIdx.x] - v + sc;
    __syncthreads();
    if (threadIdx.x == 0) sc += sh[1023];
    __syncthreads();
  }
  if (threadIdx.x == 0) *total = sc;
}

// ---------- pooled values (compact rows) ----------
template <int C>
__global__ void pool_val_k(const float* __restrict__ xin, const int* __restrict__ invp,
                           const int* __restrict__ list, const int* __restrict__ cnt,
                           int Hp, int Wp, int Ho, int Wo, float* __restrict__ y) {
  long total = (long)cnt[0] * C;
  for (long i = (long)blockIdx.x * TPB + threadIdx.x; i < total; i += (long)gridDim.x * TPB) {
    int c = (int)(i & (C - 1));
    int r = (int)(i / C);
    int site = list[r];
    int wo = site % Wo; int t = site / Wo; int ho = t % Ho; int bb = t / Ho;
    long rb = ((long)bb * Hp + 2 * ho) * Wp + 2 * wo;
    float best = -1e30f;
    #pragma unroll
    for (int kh = 0; kh < 3; ++kh)
      #pragma unroll
      for (int kw = 0; kw < 3; ++kw) {
        int j = invp[rb + kh * Wp + kw];
        if (j >= 0) best = fmaxf(best, xin[(long)j * C + c]);
      }
    y[i] = best;
  }
}

// ---------- submanifold conv over compacted active list ----------
template <int CI, int CO, int ACC, bool BN, int NSP>
__global__ void sconv_k(const float* __restrict__ xin, const float* __restrict__ Wt,
                        float* __restrict__ y, const int* __restrict__ inv,
                        const int* __restrict__ list, const int* __restrict__ cnt,
                        const float* __restrict__ bnsc, int H, int W, int wci, int wco,
                        int dense_in) {
  constexpr int CW = 4;
  constexpr int NCOL = CO / CW;
  constexpr int SG = TPB / NCOL;
  constexpr int S = SG * ACC;
  constexpr int CIP = CI + 1;
  __shared__ float st[S * CIP];
  __shared__ int nbr[S * 9];
  const int nact = cnt[0];
  const int col = threadIdx.x % NCOL;
  const int sg = threadIdx.x / NCOL;
  const int co0 = col * CW;
  const int nb0 = (NSP > 1) ? blockIdx.y * (9 / NSP) : 0;
  const int nb1 = (NSP > 1) ? nb0 + (9 / NSP) : 9;
  for (int base = blockIdx.x * S; base < nact; base += gridDim.x * S) {
    int ns = min(S, nact - base);
    for (int i = threadIdx.x; i < ns * 9; i += TPB) {
      int s = i / 9, nb = i - s * 9;
      int site = list[base + s];
      int w = site % W; int t = site / W; int h = t % H; int bb = t / H;
      int hh = h + nb / 3 - 1, ww = w + (nb - (nb / 3) * 3) - 1;
      int j = -1;
      if ((unsigned)hh < (unsigned)H && (unsigned)ww < (unsigned)W) {
        int ss = (bb * H + hh) * W + ww;
        j = dense_in ? ss : inv[ss];
      }
      nbr[i] = j;
    }
    __syncthreads();
    float acc[CW][ACC];
    #pragma unroll
    for (int q = 0; q < CW; ++q)
      #pragma unroll
      for (int a = 0; a < ACC; ++a) acc[q][a] = 0.f;
    for (int nb = nb0; nb < nb1; ++nb) {
      for (int i = threadIdx.x; i < ns * CI; i += TPB) {
        int s = i / CI, ci = i - s * CI;
        int j = nbr[s * 9 + nb];
        float v = 0.f;
        if (j >= 0) {
          v = xin[(long)j * CI + ci];
          if (BN) v = fmaxf(fmaf(v, bnsc[ci], bnsc[CI + ci]), 0.f);
        }
        st[s * CIP + ci] = v;
      }
      __syncthreads();
      const float* wp = Wt + (long)(nb * wci) * wco + co0;
      const float* sp = st + sg * ACC * CIP;
      #pragma unroll 4
      for (int ci = 0; ci < CI; ++ci) {
        float4 wv = *(const float4*)(wp + (long)ci * wco);
        #pragma unroll
        for (int a = 0; a < ACC; ++a) {
          float xv = sp[a * CIP + ci];
          acc[0][a] = fmaf(xv, wv.x, acc[0][a]);
          acc[1][a] = fmaf(xv, wv.y, acc[1][a]);
          acc[2][a] = fmaf(xv, wv.z, acc[2][a]);
          acc[3][a] = fmaf(xv, wv.w, acc[3][a]);
        }
      }
      __syncthreads();
    }
    #pragma unroll
    for (int a = 0; a < ACC; ++a) {
      int s = sg * ACC + a;
      if (s < ns) {
        float* yp = y + (long)(base + s) * CO + co0;
        if (NSP > 1) {
          atomicAdd(yp + 0, acc[0][a]); atomicAdd(yp + 1, acc[1][a]);
          atomicAdd(yp + 2, acc[2][a]); atomicAdd(yp + 3, acc[3][a]);
        } else {
          float4 o; o.x = acc[0][a]; o.y = acc[1][a]; o.z = acc[2][a]; o.w = acc[3][a];
          *(float4*)yp = o;
        }
      }
    }
  }
}

// ---------- BN stats over compacted rows ----------
template <int CO>
__global__ void bn_stats2_k(const float* __restrict__ y, const int* __restrict__ cnt,
                            float* __restrict__ stats) {
  __shared__ float ls[512];
  for (int i = threadIdx.x; i < 2 * CO; i += TPB) ls[i] = 0.f;
  __syncthreads();
  long total = (long)cnt[0] * CO;
  long i0 = (long)blockIdx.x * TPB + threadIdx.x;
  int c = (int)(i0 & (CO - 1));
  float s = 0.f, s2 = 0.f;
  for (long i = i0; i < total; i += (long)gridDim.x * TPB) {
    float v = y[i];
    s += v; s2 += v * v;
  }
  atomicAdd(&ls[c], s);
  atomicAdd(&ls[CO + c], s2);
  __syncthreads();
  for (int i = threadIdx.x; i < 2 * CO; i += TPB) atomicAdd(&stats[i], ls[i]);
}

__global__ void bn_fin_k(const float* __restrict__ stats, const int* __restrict__ cnt,
                         const float* __restrict__ gamma, const float* __restrict__ beta,
                         float* __restrict__ bnsc, int CO) {
  int c = threadIdx.x;
  if (c >= CO) return;
  float n = fmaxf((float)cnt[0], 1.f);
  float mean = stats[c] / n;
  float var = fmaxf(stats[CO + c] / n - mean * mean, 0.f);
  float sc = gamma[c] * rsqrtf(var + 1e-4f);
  bnsc[c] = sc;
  bnsc[CO + c] = beta[c] - mean * sc;
}

// ---------- GRU pointwise ----------
__global__ void gru_pw2_k(const float* __restrict__ yg, const float* __restrict__ yc,
                          const int* __restrict__ list, const int* __restrict__ cnt,
                          float* __restrict__ hdense, float* __restrict__ hcomp) {
  long total = (long)cnt[0] * 256;
  for (long i = (long)blockIdx.x * TPB + threadIdx.x; i < total; i += (long)gridDim.x * TPB) {
    float u = 1.f / (1.f + expf(-yg[i]));
    float c = tanhf(yc[i]);
    float v = u * c;
    if (hcomp) hcomp[i] = v;
    int r = (int)(i >> 8), co = (int)(i & 255);
    hdense[(long)list[r] * 256 + co] = v;
  }
}

// ---------- head ----------
#define KSPLIT 16
__global__ void lin1_part_k(const float* __restrict__ h2, const float* __restrict__ W1,
                            float* __restrict__ part) {
  int j = blockIdx.y * TPB + threadIdx.x;
  int kc = blockIdx.x;
  float acc[32];
  #pragma unroll
  for (int b = 0; b < 32; ++b) acc[b] = 0.f;
  int k0 = kc * 560, k1 = k0 + 560;
  for (int k = k0; k < k1; ++k) {
    float w = W1[(long)k * 1024 + j];
    int c = k / 35, s = k - c * 35;
    const float* hp = h2 + s * 256 + c;
    #pragma unroll
    for (int b = 0; b < 32; ++b) acc[b] += hp[(long)b * 8960] * w;
  }
  #pragma unroll
  for (int b = 0; b < 32; ++b) part[((long)(kc * 32 + b)) * 1024 + j] = acc[b];
}

__global__ void lin1_reduce_k(const float* __restrict__ part, const float* __restrict__ b1,
                              float* __restrict__ y1) {
  int i = blockIdx.x * TPB + threadIdx.x;
  if (i >= 32 * 1024) return;
  int b = i >> 10, j = i & 1023;
  float a = b1[j];
  #pragma unroll
  for (int kc = 0; kc < KSPLIT; ++kc) a += part[((long)(kc * 32 + b)) * 1024 + j];
  y1[i] = fmaxf(a, 0.f);
}

__global__ void lin2_k(const float* __restrict__ y1, const float* __restrict__ W2,
                       const float* __restrict__ b2, float* __restrict__ out) {
  int i = blockIdx.x * TPB + threadIdx.x;
  if (i >= 32 * 420) return;
  int b = i / 420, o = i - b * 420;
  float a = b2[o];
  const float* yp = y1 + b * 1024;
  for (int j = 0; j < 1024; ++j) a += yp[j] * W2[(long)j * 420 + o];
  out[i] = a;
}

extern "C" void kernel_launch(void* const* d_in, const int* in_sizes, int n_in,
                              void* d_out, int out_size, void* d_ws, size_t ws_size,
                              hipStream_t stream) {
  const float* x = (const float*)d_in[0];
  const float* ca[5] = {(const float*)d_in[2], (const float*)d_in[6], (const float*)d_in[10],
                        (const float*)d_in[14], (const float*)d_in[18]};
  const float* bg[5] = {(const float*)d_in[3], (const float*)d_in[7], (const float*)d_in[11],
                        (const float*)d_in[15], (const float*)d_in[19]};
  const float* bb[5] = {(const float*)d_in[4], (const float*)d_in[8], (const float*)d_in[12],
                        (const float*)d_in[16], (const float*)d_in[20]};
  const float* cb[5] = {(const float*)d_in[5], (const float*)d_in[9], (const float*)d_in[13],
                        (const float*)d_in[17], (const float*)d_in[21]};
  const float* g1Wg = (const float*)d_in[22];
  const float* g1Wc = (const float*)d_in[23];
  const float* g2Wg = (const float*)d_in[24];
  const float* g2Wc = (const float*)d_in[25];
  const float* W1 = (const float*)d_in[26];
  const float* b1 = (const float*)d_in[27];
  const float* W2 = (const float*)d_in[28];
  const float* b2 = (const float*)d_in[29];

  const int Hs[6] = {191, 95, 47, 23, 11, 5};
  const int Wd[6] = {255, 127, 63, 31, 15, 7};
  const long NS[6] = {1558560, 386080, 94752, 22816, 5280, 1120};
  const int cap[6] = {400000, 386080, 94752, 22816, 5280, 1120};

  float* ws = (float*)d_ws;
  const long BUF = 12354560;
  long off = 0;
  float* bufA = ws + off; off += BUF;
  float* bufB = ws + off; off += BUF;
  float* yg = ws + off;   off += 286720;
  float* yc = ws + off;   off += 286720;
  float* h1c = ws + off;  off += 286720;
  float* stats = ws + off; off += 512;
  float* bnsc = ws + off;  off += 512;
  float* y1 = ws + off;    off += 32L * 1024;
  float* part = ws + off;  off += (long)KSPLIT * 32 * 1024;
  int* ip = (int*)(ws + off);
  long ioff = 0;
  int* cnt = ip + ioff; ioff += 16;
  int* bcnt = ip + ioff; ioff += 8192;
  int* list[6]; int* inv[6];
  for (int l = 0; l < 6; ++l) { list[l] = ip + ioff; ioff += cap[l]; }
  for (int l = 0; l < 6; ++l) { inv[l] = ip + ioff; ioff += NS[l]; }
  size_t needed = (size_t)off * 4 + (size_t)ioff * 4;
  if (ws_size < needed) return;

  float* h1d = (float*)d_out + 13440;
  float* h2d = h1d + 286720;

  // ---- level-0 compaction (scan-based, no atomics) ----
  {
    int nb = nblk(NS[0]);
    cmpA0_k<<<nb, TPB, 0, stream>>>(x, (int)NS[0], bcnt);
    scan_k<<<1, 1024, 0, stream>>>(bcnt, nb, cnt + 0);
    cmpB0_k<<<nb, TPB, 0, stream>>>(x, (int)NS[0], bcnt, list[0], inv[0], cap[0]);
  }

  // ---------- level 1 ----------
  hipMemsetAsync(stats, 0, 512 * 4, stream);
  sconv_k<2, 16, 8, false, 1><<<gmin((cap[0] + 511) / 512, 1024), TPB, 0, stream>>>(
      x, ca[0], bufA, nullptr, list[0], cnt + 0, nullptr, Hs[0], Wd[0], 2, 16, 1);
  bn_stats2_k<16><<<1024, TPB, 0, stream>>>(bufA, cnt + 0, stats);
  bn_fin_k<<<1, 256, 0, stream>>>(stats, cnt + 0, bg[0], bb[0], bnsc, 16);
  sconv_k<16, 16, 4, true, 1><<<gmin((cap[0] + 255) / 256, 1024), TPB, 0, stream>>>(
      bufA, cb[0], bufB, inv[0], list[0], cnt + 0, bnsc, Hs[0], Wd[0], 16, 16, 0);
  {
    int nb = nblk(NS[1]);
    poolA_k<<<nb, TPB, 0, stream>>>(inv[0], Hs[0], Wd[0], Hs[1], Wd[1], (int)NS[1], bcnt);
    scan_k<<<1, 1024, 0, stream>>>(bcnt, nb, cnt + 1);
    poolB_k<<<nb, TPB, 0, stream>>>(inv[0], Hs[0], Wd[0], Hs[1], Wd[1], (int)NS[1], bcnt,
                                    list[1], inv[1], cap[1]);
  }
  pool_val_k<16><<<2048, TPB, 0, stream>>>(bufB, inv[0], list[1], cnt + 1, Hs[0], Wd[0], Hs[1], Wd[1], bufA);

  // ---------- level 2 ----------
  hipMemsetAsync(stats, 0, 512 * 4, stream);
  sconv_k<16, 32, 8, false, 1><<<gmin((NS[1] + 255) / 256, 1024), TPB, 0, stream>>>(
      bufA, ca[1], bufB, inv[1], list[1], cnt + 1, nullptr, Hs[1], Wd[1], 16, 32, 0);
  bn_stats2_k<32><<<1024, TPB, 0, stream>>>(bufB, cnt + 1, stats);
  bn_fin_k<<<1, 256, 0, stream>>>(stats, cnt + 1, bg[1], bb[1], bnsc, 32);
  sconv_k<32, 32, 4, true, 1><<<gmin((NS[1] + 127) / 128, 1024), TPB, 0, stream>>>(
      bufB, cb[1], bufA, inv[1], list[1], cnt + 1, bnsc, Hs[1], Wd[1], 32, 32, 0);
  {
    int nb = nblk(NS[2]);
    poolA_k<<<nb, TPB, 0, stream>>>(inv[1], Hs[1], Wd[1], Hs[2], Wd[2], (int)NS[2], bcnt);
    scan_k<<<1, 1024, 0, stream>>>(bcnt, nb, cnt + 2);
    poolB_k<<<nb, TPB, 0, stream>>>(inv[1], Hs[1], Wd[1], Hs[2], Wd[2], (int)NS[2], bcnt,
                                    list[2], inv[2], cap[2]);
  }
  pool_val_k<32><<<2048, TPB, 0, stream>>>(bufA, inv[1], list[2], cnt + 2, Hs[1], Wd[1], Hs[2], Wd[2], bufB);

  // ---------- level 3 ----------
  hipMemsetAsync(stats, 0, 512 * 4, stream);
  sconv_k<32, 64, 8, false, 1><<<gmin((NS[2] + 127) / 128, 1024), TPB, 0, stream>>>(
      bufB, ca[2], bufA, inv[2], list[2], cnt + 2, nullptr, Hs[2], Wd[2], 32, 64, 0);
  bn_stats2_k<64><<<1024, TPB, 0, stream>>>(bufA, cnt + 2, stats);
  bn_fin_k<<<1, 256, 0, stream>>>(stats, cnt + 2, bg[2], bb[2], bnsc, 64);
  sconv_k<64, 64, 4, true, 1><<<gmin((NS[2] + 63) / 64, 1024), TPB, 0, stream>>>(
      bufA, cb[2], bufB, inv[2], list[2], cnt + 2, bnsc, Hs[2], Wd[2], 64, 64, 0);
  {
    int nb = nblk(NS[3]);
    poolA_k<<<nb, TPB, 0, stream>>>(inv[2], Hs[2], Wd[2], Hs[3], Wd[3], (int)NS[3], bcnt);
    scan_k<<<1, 1024, 0, stream>>>(bcnt, nb, cnt + 3);
    poolB_k<<<nb, TPB, 0, stream>>>(inv[2], Hs[2], Wd[2], Hs[3], Wd[3], (int)NS[3], bcnt,
                                    list[3], inv[3], cap[3]);
  }
  pool_val_k<64><<<2048, TPB, 0, stream>>>(bufB, inv[2], list[3], cnt + 3, Hs[2], Wd[2], Hs[3], Wd[3], bufA);

  // ---------- level 4 ----------
  hipMemsetAsync(stats, 0, 512 * 4, stream);
  sconv_k<64, 128, 8, false, 1><<<gmin((NS[3] + 63) / 64, 1024), TPB, 0, stream>>>(
      bufA, ca[3], bufB, inv[3], list[3], cnt + 3, nullptr, Hs[3], Wd[3], 64, 128, 0);
  bn_stats2_k<128><<<1024, TPB, 0, stream>>>(bufB, cnt + 3, stats);
  bn_fin_k<<<1, 256, 0, stream>>>(stats, cnt + 3, bg[3], bb[3], bnsc, 128);
  sconv_k<128, 128, 4, true, 1><<<gmin((NS[3] + 31) / 32, 1024), TPB, 0, stream>>>(
      bufB, cb[3], bufA, inv[3], list[3], cnt + 3, bnsc, Hs[3], Wd[3], 128, 128, 0);
  {
    int nb = nblk(NS[4]);
    poolA_k<<<nb, TPB, 0, stream>>>(inv[3], Hs[3], Wd[3], Hs[4], Wd[4], (int)NS[4], bcnt);
    scan_k<<<1, 1024, 0, stream>>>(bcnt, nb, cnt + 4);
    poolB_k<<<nb, TPB, 0, stream>>>(inv[3], Hs[3], Wd[3], Hs[4], Wd[4], (int)NS[4], bcnt,
                                    list[4], inv[4], cap[4]);
  }
  pool_val_k<128><<<2048, TPB, 0, stream>>>(bufA, inv[3], list[4], cnt + 4, Hs[3], Wd[3], Hs[4], Wd[4], bufB);

  // ---------- level 5 (k-split) ----------
  hipMemsetAsync(stats, 0, 512 * 4, stream);
  hipMemsetAsync(bufA, 0, 5280L * 256 * 4, stream);
  sconv_k<128, 256, 8, false, 3><<<dim3((NS[4] + 31) / 32, 3), TPB, 0, stream>>>(
      bufB, ca[4], bufA, inv[4], list[4], cnt + 4, nullptr, Hs[4], Wd[4], 128, 256, 0);
  bn_stats2_k<256><<<1024, TPB, 0, stream>>>(bufA, cnt + 4, stats);
  bn_fin_k<<<1, 256, 0, stream>>>(stats, cnt + 4, bg[4], bb[4], bnsc, 256);
  hipMemsetAsync(bufB, 0, 5280L * 256 * 4, stream);
  sconv_k<256, 256, 8, true, 3><<<dim3((NS[4] + 31) / 32, 3), TPB, 0, stream>>>(
      bufA, cb[4], bufB, inv[4], list[4], cnt + 4, bnsc, Hs[4], Wd[4], 256, 256, 0);
  {
    int nb = nblk(NS[5]);
    poolA_k<<<nb, TPB, 0, stream>>>(inv[4], Hs[4], Wd[4], Hs[5], Wd[5], (int)NS[5], bcnt);
    scan_k<<<1, 1024, 0, stream>>>(bcnt, nb, cnt + 5);
    poolB_k<<<nb, TPB, 0, stream>>>(inv[4], Hs[4], Wd[4], Hs[5], Wd[5], (int)NS[5], bcnt,
                                    list[5], inv[5], cap[5]);
  }
  pool_val_k<256><<<1024, TPB, 0, stream>>>(bufB, inv[4], list[5], cnt + 5, Hs[4], Wd[4], Hs[5], Wd[5], bufA);

  // ---------- GRUs ----------
  long ngb = 286720L * 4;
  hipMemsetAsync(yg, 0, ngb, stream);
  hipMemsetAsync(yc, 0, ngb, stream);
  hipMemsetAsync(h1d, 0, ngb, stream);
  hipMemsetAsync(h2d, 0, ngb, stream);
  sconv_k<256, 256, 4, false, 9><<<dim3((NS[5] + 15) / 16, 9), TPB, 0, stream>>>(
      bufA, g1Wg, yg, inv[5], list[5], cnt + 5, nullptr, Hs[5], Wd[5], 512, 512, 0);
  sconv_k<256, 256, 4, false, 9><<<dim3((NS[5] + 15) / 16, 9), TPB, 0, stream>>>(
      bufA, g1Wc, yc, inv[5], list[5], cnt + 5, nullptr, Hs[5], Wd[5], 512, 256, 0);
  gru_pw2_k<<<512, TPB, 0, stream>>>(yg, yc, list[5], cnt + 5, h1d, h1c);
  hipMemsetAsync(yg, 0, ngb, stream);
  hipMemsetAsync(yc, 0, ngb, stream);
  sconv_k<256, 256, 4, false, 9><<<dim3((NS[5] + 15) / 16, 9), TPB, 0, stream>>>(
      h1c, g2Wg, yg, inv[5], list[5], cnt + 5, nullptr, Hs[5], Wd[5], 512, 512, 0);
  sconv_k<256, 256, 4, false, 9><<<dim3((NS[5] + 15) / 16, 9), TPB, 0, stream>>>(
      h1c, g2Wc, yc, inv[5], list[5], cnt + 5, nullptr, Hs[5], Wd[5], 512, 256, 0);
  gru_pw2_k<<<512, TPB, 0, stream>>>(yg, yc, list[5], cnt + 5, h2d, nullptr);

  // ---------- head ----------
  lin1_part_k<<<dim3(KSPLIT, 4), TPB, 0, stream>>>(h2d, W1, part);
  lin1_reduce_k<<<nblk(32L * 1024), TPB, 0, stream>>>(part, b1, y1);
  lin2_k<<<nblk(32L * 420), TPB, 0, stream>>>(y1, W2, b2, (float*)d_out);
}

// Round 4
// 1670.659 us; speedup vs baseline: 3.8345x; 1.1485x over previous
//
#include <hip/hip_runtime.h>
#include <stdint.h>

#define TPB 256

static inline int nblk(long n) { return (int)((n + TPB - 1) / TPB); }
static inline int gmin(long a, long b) { return (int)(a < b ? a : b); }

// ---------- scan-based compaction (no global atomics) ----------
__device__ __forceinline__ bool act0(const float* x, int i) {
  float2 v = *(const float2*)(x + 2L * i);
  return (v.x != 0.f) || (v.y != 0.f);
}

__global__ void cmpA0_k(const float* __restrict__ x, int n, int* __restrict__ bcnt) {
  int i = blockIdx.x * TPB + threadIdx.x;
  bool a = (i < n) && act0(x, i);
  unsigned long long bal = __ballot(a);
  __shared__ int wc[4];
  if ((threadIdx.x & 63) == 0) wc[threadIdx.x >> 6] = __popcll(bal);
  __syncthreads();
  if (threadIdx.x == 0) bcnt[blockIdx.x] = wc[0] + wc[1] + wc[2] + wc[3];
}

__global__ void cmpB0_k(const float* __restrict__ x, int n, const int* __restrict__ bbase,
                        int* __restrict__ list, int* __restrict__ inv, int cap) {
  int i = blockIdx.x * TPB + threadIdx.x;
  bool a = (i < n) && act0(x, i);
  unsigned long long bal = __ballot(a);
  __shared__ int wc[4];
  int wid = threadIdx.x >> 6, lane = threadIdx.x & 63;
  if (lane == 0) wc[wid] = __popcll(bal);
  __syncthreads();
  int base = bbase[blockIdx.x];
  for (int w = 0; w < wid; ++w) base += wc[w];
  if (i < n) {
    int pos = base + __popcll(bal & ((1ull << lane) - 1));
    if (a && pos < cap) { list[pos] = i; inv[i] = pos; }
    else inv[i] = -1;
  }
}

__device__ __forceinline__ bool actp(const int* invp, int Hp, int Wp, int Ho, int Wo, int i) {
  int wo = i % Wo; int t = i / Wo; int ho = t % Ho; int bb = t / Ho;
  long rb = ((long)bb * Hp + 2 * ho) * Wp + 2 * wo;
  bool a = false;
  #pragma unroll
  for (int kh = 0; kh < 3; ++kh)
    #pragma unroll
    for (int kw = 0; kw < 3; ++kw)
      a |= (invp[rb + kh * Wp + kw] >= 0);
  return a;
}

__global__ void poolA_k(const int* __restrict__ invp, int Hp, int Wp, int Ho, int Wo,
                        int n, int* __restrict__ bcnt) {
  int i = blockIdx.x * TPB + threadIdx.x;
  bool a = (i < n) && actp(invp, Hp, Wp, Ho, Wo, i);
  unsigned long long bal = __ballot(a);
  __shared__ int wc[4];
  if ((threadIdx.x & 63) == 0) wc[threadIdx.x >> 6] = __popcll(bal);
  __syncthreads();
  if (threadIdx.x == 0) bcnt[blockIdx.x] = wc[0] + wc[1] + wc[2] + wc[3];
}

__global__ void poolB_k(const int* __restrict__ invp, int Hp, int Wp, int Ho, int Wo, int n,
                        const int* __restrict__ bbase, int* __restrict__ list,
                        int* __restrict__ inv, int cap) {
  int i = blockIdx.x * TPB + threadIdx.x;
  bool a = (i < n) && actp(invp, Hp, Wp, Ho, Wo, i);
  unsigned long long bal = __ballot(a);
  __shared__ int wc[4];
  int wid = threadIdx.x >> 6, lane = threadIdx.x & 63;
  if (lane == 0) wc[wid] = __popcll(bal);
  __syncthreads();
  int base = bbase[blockIdx.x];
  for (int w = 0; w < wid; ++w) base += wc[w];
  if (i < n) {
    int pos = base + __popcll(bal & ((1ull << lane) - 1));
    if (a && pos < cap) { list[pos] = i; inv[i] = pos; }
    else inv[i] = -1;
  }
}

// single-block exclusive scan of bcnt[0..n); total -> *total
__global__ void scan_k(int* __restrict__ b, int n, int* __restrict__ total) {
  __shared__ int sh[1024];
  __shared__ int sc;
  if (threadIdx.x == 0) sc = 0;
  __syncthreads();
  for (int base = 0; base < n; base += 1024) {
    int i = base + threadIdx.x;
    int v = (i < n) ? b[i] : 0;
    sh[threadIdx.x] = v;
    __syncthreads();
    for (int o = 1; o < 1024; o <<= 1) {
      int t = (threadIdx.x >= o) ? sh[threadIdx.x - o] : 0;
      __syncthreads();
      sh[threadIdx.x] += t;
      __syncthreads();
    }
    if (i < n) b[i] = sh[threadIdx.x] - v + sc;
    __syncthreads();
    if (threadIdx.x == 0) sc += sh[1023];
    __syncthreads();
  }
  if (threadIdx.x == 0) *total = sc;
}

// ---------- pooled values (compact rows) ----------
template <int C>
__global__ void pool_val_k(const float* __restrict__ xin, const int* __restrict__ invp,
                           const int* __restrict__ list, const int* __restrict__ cnt,
                           int Hp, int Wp, int Ho, int Wo, float* __restrict__ y) {
  long total = (long)cnt[0] * C;
  for (long i = (long)blockIdx.x * TPB + threadIdx.x; i < total; i += (long)gridDim.x * TPB) {
    int c = (int)(i & (C - 1));
    int r = (int)(i / C);
    int site = list[r];
    int wo = site % Wo; int t = site / Wo; int ho = t % Ho; int bb = t / Ho;
    long rb = ((long)bb * Hp + 2 * ho) * Wp + 2 * wo;
    float best = -1e30f;
    #pragma unroll
    for (int kh = 0; kh < 3; ++kh)
      #pragma unroll
      for (int kw = 0; kw < 3; ++kw) {
        int j = invp[rb + kh * Wp + kw];
        if (j >= 0) best = fmaxf(best, xin[(long)j * C + c]);
      }
    y[i] = best;
  }
}

// ---------- submanifold conv over compacted active list ----------
template <int CI, int CO, int ACC, bool BN, int NSP>
__global__ void sconv_k(const float* __restrict__ xin, const float* __restrict__ Wt,
                        float* __restrict__ y, const int* __restrict__ inv,
                        const int* __restrict__ list, const int* __restrict__ cnt,
                        const float* __restrict__ bnsc, int H, int W, int wci, int wco,
                        int dense_in) {
  constexpr int CW = 4;
  constexpr int NCOL = CO / CW;
  constexpr int SG = TPB / NCOL;
  constexpr int S = SG * ACC;
  constexpr int CIP = CI + 1;
  __shared__ float st[S * CIP];
  __shared__ int nbr[S * 9];
  const int nact = cnt[0];
  const int col = threadIdx.x % NCOL;
  const int sg = threadIdx.x / NCOL;
  const int co0 = col * CW;
  const int nb0 = (NSP > 1) ? blockIdx.y * (9 / NSP) : 0;
  const int nb1 = (NSP > 1) ? nb0 + (9 / NSP) : 9;
  for (int base = blockIdx.x * S; base < nact; base += gridDim.x * S) {
    int ns = min(S, nact - base);
    for (int i = threadIdx.x; i < ns * 9; i += TPB) {
      int s = i / 9, nb = i - s * 9;
      int site = list[base + s];
      int w = site % W; int t = site / W; int h = t % H; int bb = t / H;
      int hh = h + nb / 3 - 1, ww = w + (nb - (nb / 3) * 3) - 1;
      int j = -1;
      if ((unsigned)hh < (unsigned)H && (unsigned)ww < (unsigned)W) {
        int ss = (bb * H + hh) * W + ww;
        j = dense_in ? ss : inv[ss];
      }
      nbr[i] = j;
    }
    __syncthreads();
    float acc[CW][ACC];
    #pragma unroll
    for (int q = 0; q < CW; ++q)
      #pragma unroll
      for (int a = 0; a < ACC; ++a) acc[q][a] = 0.f;
    for (int nb = nb0; nb < nb1; ++nb) {
      for (int i = threadIdx.x; i < ns * CI; i += TPB) {
        int s = i / CI, ci = i - s * CI;
        int j = nbr[s * 9 + nb];
        float v = 0.f;
        if (j >= 0) {
          v = xin[(long)j * CI + ci];
          if (BN) v = fmaxf(fmaf(v, bnsc[ci], bnsc[CI + ci]), 0.f);
        }
        st[s * CIP + ci] = v;
      }
      __syncthreads();
      const float* wp = Wt + (long)(nb * wci) * wco + co0;
      const float* sp = st + sg * ACC * CIP;
      #pragma unroll 4
      for (int ci = 0; ci < CI; ++ci) {
        float4 wv = *(const float4*)(wp + (long)ci * wco);
        #pragma unroll
        for (int a = 0; a < ACC; ++a) {
          float xv = sp[a * CIP + ci];
          acc[0][a] = fmaf(xv, wv.x, acc[0][a]);
          acc[1][a] = fmaf(xv, wv.y, acc[1][a]);
          acc[2][a] = fmaf(xv, wv.z, acc[2][a]);
          acc[3][a] = fmaf(xv, wv.w, acc[3][a]);
        }
      }
      __syncthreads();
    }
    #pragma unroll
    for (int a = 0; a < ACC; ++a) {
      int s = sg * ACC + a;
      if (s < ns) {
        float* yp = y + (long)(base + s) * CO + co0;
        if (NSP > 1) {
          atomicAdd(yp + 0, acc[0][a]); atomicAdd(yp + 1, acc[1][a]);
          atomicAdd(yp + 2, acc[2][a]); atomicAdd(yp + 3, acc[3][a]);
        } else {
          float4 o; o.x = acc[0][a]; o.y = acc[1][a]; o.z = acc[2][a]; o.w = acc[3][a];
          *(float4*)yp = o;
        }
      }
    }
  }
}

// ---------- BN stats over compacted rows ----------
template <int CO>
__global__ void bn_stats2_k(const float* __restrict__ y, const int* __restrict__ cnt,
                            float* __restrict__ stats) {
  __shared__ float ls[512];
  for (int i = threadIdx.x; i < 2 * CO; i += TPB) ls[i] = 0.f;
  __syncthreads();
  long total = (long)cnt[0] * CO;
  long i0 = (long)blockIdx.x * TPB + threadIdx.x;
  int c = (int)(i0 & (CO - 1));
  float s = 0.f, s2 = 0.f;
  for (long i = i0; i < total; i += (long)gridDim.x * TPB) {
    float v = y[i];
    s += v; s2 += v * v;
  }
  atomicAdd(&ls[c], s);
  atomicAdd(&ls[CO + c], s2);
  __syncthreads();
  for (int i = threadIdx.x; i < 2 * CO; i += TPB) atomicAdd(&stats[i], ls[i]);
}

__global__ void bn_fin_k(const float* __restrict__ stats, const int* __restrict__ cnt,
                         const float* __restrict__ gamma, const float* __restrict__ beta,
                         float* __restrict__ bnsc, int CO) {
  int c = threadIdx.x;
  if (c >= CO) return;
  float n = fmaxf((float)cnt[0], 1.f);
  float mean = stats[c] / n;
  float var = fmaxf(stats[CO + c] / n - mean * mean, 0.f);
  float sc = gamma[c] * rsqrtf(var + 1e-4f);
  bnsc[c] = sc;
  bnsc[CO + c] = beta[c] - mean * sc;
}

// ---------- GRU pointwise ----------
__global__ void gru_pw2_k(const float* __restrict__ yg, const float* __restrict__ yc,
                          const int* __restrict__ list, const int* __restrict__ cnt,
                          float* __restrict__ hdense, float* __restrict__ hcomp) {
  long total = (long)cnt[0] * 256;
  for (long i = (long)blockIdx.x * TPB + threadIdx.x; i < total; i += (long)gridDim.x * TPB) {
    float u = 1.f / (1.f + expf(-yg[i]));
    float c = tanhf(yc[i]);
    float v = u * c;
    if (hcomp) hcomp[i] = v;
    int r = (int)(i >> 8), co = (int)(i & 255);
    hdense[(long)list[r] * 256 + co] = v;
  }
}

// ---------- head: y = relu(dense @ W1 + b1) @ W2 + b2 ----------
// dense[b, k=c*35+s] = h2d[b*8960 + s*256 + c]
#define KS 140
__global__ void lin1_part2_k(const float* __restrict__ h2, const float* __restrict__ W1,
                             float* __restrict__ part) {
  __shared__ float sh[32][65];
  int kc = blockIdx.x;
  int j = blockIdx.y * TPB + threadIdx.x;
  int k0 = kc * 64;
  for (int i = threadIdx.x; i < 32 * 64; i += TPB) {
    int b = i >> 6, kk = i & 63;
    int k = k0 + kk;
    int c = k / 35, s = k - c * 35;
    sh[b][kk] = h2[(long)b * 8960 + s * 256 + c];
  }
  __syncthreads();
  float acc[32];
  #pragma unroll
  for (int b = 0; b < 32; ++b) acc[b] = 0.f;
  #pragma unroll 4
  for (int kk = 0; kk < 64; ++kk) {
    float w = W1[(long)(k0 + kk) * 1024 + j];
    #pragma unroll
    for (int b = 0; b < 32; ++b) acc[b] = fmaf(sh[b][kk], w, acc[b]);
  }
  #pragma unroll
  for (int b = 0; b < 32; ++b) part[((long)(kc * 32 + b)) * 1024 + j] = acc[b];
}

__global__ void lin1_reduce_k(const float* __restrict__ part, const float* __restrict__ b1,
                              float* __restrict__ y1) {
  int i = blockIdx.x * TPB + threadIdx.x;
  if (i >= 32 * 1024) return;
  int b = i >> 10, j = i & 1023;
  float a = b1[j];
  for (int kc = 0; kc < KS; ++kc) a += part[(long)kc * 32768 + b * 1024 + j];
  y1[i] = fmaxf(a, 0.f);
}

#define JS2 8
__global__ void lin2_part_k(const float* __restrict__ y1, const float* __restrict__ W2,
                            float* __restrict__ part2) {
  int i = blockIdx.x * TPB + threadIdx.x;
  if (i >= 32 * 420) return;
  int b = i / 420, o = i - b * 420;
  int j0 = blockIdx.y * 128;
  float a = 0.f;
  const float* yp = y1 + b * 1024 + j0;
  const float* wp = W2 + (long)j0 * 420 + o;
  #pragma unroll 8
  for (int j = 0; j < 128; ++j) a = fmaf(yp[j], wp[(long)j * 420], a);
  part2[(long)blockIdx.y * 13440 + i] = a;
}

__global__ void lin2_fin_k(const float* __restrict__ part2, const float* __restrict__ b2,
                           float* __restrict__ out) {
  int i = blockIdx.x * TPB + threadIdx.x;
  if (i >= 32 * 420) return;
  int o = i % 420;
  float a = b2[o];
  #pragma unroll
  for (int js = 0; js < JS2; ++js) a += part2[(long)js * 13440 + i];
  out[i] = a;
}

extern "C" void kernel_launch(void* const* d_in, const int* in_sizes, int n_in,
                              void* d_out, int out_size, void* d_ws, size_t ws_size,
                              hipStream_t stream) {
  const float* x = (const float*)d_in[0];
  const float* ca[5] = {(const float*)d_in[2], (const float*)d_in[6], (const float*)d_in[10],
                        (const float*)d_in[14], (const float*)d_in[18]};
  const float* bg[5] = {(const float*)d_in[3], (const float*)d_in[7], (const float*)d_in[11],
                        (const float*)d_in[15], (const float*)d_in[19]};
  const float* bb[5] = {(const float*)d_in[4], (const float*)d_in[8], (const float*)d_in[12],
                        (const float*)d_in[16], (const float*)d_in[20]};
  const float* cb[5] = {(const float*)d_in[5], (const float*)d_in[9], (const float*)d_in[13],
                        (const float*)d_in[17], (const float*)d_in[21]};
  const float* g1Wg = (const float*)d_in[22];
  const float* g1Wc = (const float*)d_in[23];
  const float* g2Wg = (const float*)d_in[24];
  const float* g2Wc = (const float*)d_in[25];
  const float* W1 = (const float*)d_in[26];
  const float* b1 = (const float*)d_in[27];
  const float* W2 = (const float*)d_in[28];
  const float* b2 = (const float*)d_in[29];

  const int Hs[6] = {191, 95, 47, 23, 11, 5};
  const int Wd[6] = {255, 127, 63, 31, 15, 7};
  const long NS[6] = {1558560, 386080, 94752, 22816, 5280, 1120};
  const int cap[6] = {400000, 386080, 94752, 22816, 5280, 1120};

  float* ws = (float*)d_ws;
  const long BUF = 12354560;
  long off = 0;
  float* bufA = ws + off; off += BUF;
  float* bufB = ws + off; off += BUF;
  float* yg = ws + off;   off += 286720;
  float* yc = ws + off;   off += 286720;
  float* h1c = ws + off;  off += 286720;
  float* stats = ws + off; off += 512;
  float* bnsc = ws + off;  off += 512;
  float* y1 = ws + off;    off += 32L * 1024;
  int* ip = (int*)(ws + off);
  long ioff = 0;
  int* cnt = ip + ioff; ioff += 16;
  int* bcnt = ip + ioff; ioff += 8192;
  int* list[6]; int* inv[6];
  for (int l = 0; l < 6; ++l) { list[l] = ip + ioff; ioff += cap[l]; }
  for (int l = 0; l < 6; ++l) { inv[l] = ip + ioff; ioff += NS[l]; }
  size_t needed = (size_t)off * 4 + (size_t)ioff * 4;
  if (ws_size < needed) return;

  float* h1d = (float*)d_out + 13440;
  float* h2d = h1d + 286720;

  // ---- level-0 compaction ----
  {
    int nb = nblk(NS[0]);
    cmpA0_k<<<nb, TPB, 0, stream>>>(x, (int)NS[0], bcnt);
    scan_k<<<1, 1024, 0, stream>>>(bcnt, nb, cnt + 0);
    cmpB0_k<<<nb, TPB, 0, stream>>>(x, (int)NS[0], bcnt, list[0], inv[0], cap[0]);
  }

  // ---------- level 1 ----------
  hipMemsetAsync(stats, 0, 512 * 4, stream);
  sconv_k<2, 16, 8, false, 1><<<gmin((cap[0] + 511) / 512, 1024), TPB, 0, stream>>>(
      x, ca[0], bufA, nullptr, list[0], cnt + 0, nullptr, Hs[0], Wd[0], 2, 16, 1);
  bn_stats2_k<16><<<1024, TPB, 0, stream>>>(bufA, cnt + 0, stats);
  bn_fin_k<<<1, 256, 0, stream>>>(stats, cnt + 0, bg[0], bb[0], bnsc, 16);
  sconv_k<16, 16, 4, true, 1><<<gmin((cap[0] + 255) / 256, 1024), TPB, 0, stream>>>(
      bufA, cb[0], bufB, inv[0], list[0], cnt + 0, bnsc, Hs[0], Wd[0], 16, 16, 0);
  {
    int nb = nblk(NS[1]);
    poolA_k<<<nb, TPB, 0, stream>>>(inv[0], Hs[0], Wd[0], Hs[1], Wd[1], (int)NS[1], bcnt);
    scan_k<<<1, 1024, 0, stream>>>(bcnt, nb, cnt + 1);
    poolB_k<<<nb, TPB, 0, stream>>>(inv[0], Hs[0], Wd[0], Hs[1], Wd[1], (int)NS[1], bcnt,
                                    list[1], inv[1], cap[1]);
  }
  pool_val_k<16><<<2048, TPB, 0, stream>>>(bufB, inv[0], list[1], cnt + 1, Hs[0], Wd[0], Hs[1], Wd[1], bufA);

  // ---------- level 2 ----------
  hipMemsetAsync(stats, 0, 512 * 4, stream);
  sconv_k<16, 32, 8, false, 1><<<gmin((NS[1] + 255) / 256, 1024), TPB, 0, stream>>>(
      bufA, ca[1], bufB, inv[1], list[1], cnt + 1, nullptr, Hs[1], Wd[1], 16, 32, 0);
  bn_stats2_k<32><<<1024, TPB, 0, stream>>>(bufB, cnt + 1, stats);
  bn_fin_k<<<1, 256, 0, stream>>>(stats, cnt + 1, bg[1], bb[1], bnsc, 32);
  sconv_k<32, 32, 4, true, 1><<<gmin((NS[1] + 127) / 128, 1024), TPB, 0, stream>>>(
      bufB, cb[1], bufA, inv[1], list[1], cnt + 1, bnsc, Hs[1], Wd[1], 32, 32, 0);
  {
    int nb = nblk(NS[2]);
    poolA_k<<<nb, TPB, 0, stream>>>(inv[1], Hs[1], Wd[1], Hs[2], Wd[2], (int)NS[2], bcnt);
    scan_k<<<1, 1024, 0, stream>>>(bcnt, nb, cnt + 2);
    poolB_k<<<nb, TPB, 0, stream>>>(inv[1], Hs[1], Wd[1], Hs[2], Wd[2], (int)NS[2], bcnt,
                                    list[2], inv[2], cap[2]);
  }
  pool_val_k<32><<<2048, TPB, 0, stream>>>(bufA, inv[1], list[2], cnt + 2, Hs[1], Wd[1], Hs[2], Wd[2], bufB);

  // ---------- level 3 ----------
  hipMemsetAsync(stats, 0, 512 * 4, stream);
  sconv_k<32, 64, 8, false, 1><<<gmin((NS[2] + 127) / 128, 1024), TPB, 0, stream>>>(
      bufB, ca[2], bufA, inv[2], list[2], cnt + 2, nullptr, Hs[2], Wd[2], 32, 64, 0);
  bn_stats2_k<64><<<1024, TPB, 0, stream>>>(bufA, cnt + 2, stats);
  bn_fin_k<<<1, 256, 0, stream>>>(stats, cnt + 2, bg[2], bb[2], bnsc, 64);
  sconv_k<64, 64, 4, true, 1><<<gmin((NS[2] + 63) / 64, 1024), TPB, 0, stream>>>(
      bufA, cb[2], bufB, inv[2], list[2], cnt + 2, bnsc, Hs[2], Wd[2], 64, 64, 0);
  {
    int nb = nblk(NS[3]);
    poolA_k<<<nb, TPB, 0, stream>>>(inv[2], Hs[2], Wd[2], Hs[3], Wd[3], (int)NS[3], bcnt);
    scan_k<<<1, 1024, 0, stream>>>(bcnt, nb, cnt + 3);
    poolB_k<<<nb, TPB, 0, stream>>>(inv[2], Hs[2], Wd[2], Hs[3], Wd[3], (int)NS[3], bcnt,
                                    list[3], inv[3], cap[3]);
  }
  pool_val_k<64><<<2048, TPB, 0, stream>>>(bufB, inv[2], list[3], cnt + 3, Hs[2], Wd[2], Hs[3], Wd[3], bufA);

  // ---------- level 4 ----------
  hipMemsetAsync(stats, 0, 512 * 4, stream);
  sconv_k<64, 128, 8, false, 1><<<gmin((NS[3] + 63) / 64, 1024), TPB, 0, stream>>>(
      bufA, ca[3], bufB, inv[3], list[3], cnt + 3, nullptr, Hs[3], Wd[3], 64, 128, 0);
  bn_stats2_k<128><<<1024, TPB, 0, stream>>>(bufB, cnt + 3, stats);
  bn_fin_k<<<1, 256, 0, stream>>>(stats, cnt + 3, bg[3], bb[3], bnsc, 128);
  sconv_k<128, 128, 4, true, 1><<<gmin((NS[3] + 31) / 32, 1024), TPB, 0, stream>>>(
      bufB, cb[3], bufA, inv[3], list[3], cnt + 3, bnsc, Hs[3], Wd[3], 128, 128, 0);
  {
    int nb = nblk(NS[4]);
    poolA_k<<<nb, TPB, 0, stream>>>(inv[3], Hs[3], Wd[3], Hs[4], Wd[4], (int)NS[4], bcnt);
    scan_k<<<1, 1024, 0, stream>>>(bcnt, nb, cnt + 4);
    poolB_k<<<nb, TPB, 0, stream>>>(inv[3], Hs[3], Wd[3], Hs[4], Wd[4], (int)NS[4], bcnt,
                                    list[4], inv[4], cap[4]);
  }
  pool_val_k<128><<<2048, TPB, 0, stream>>>(bufA, inv[3], list[4], cnt + 4, Hs[3], Wd[3], Hs[4], Wd[4], bufB);

  // ---------- level 5 (k-split) ----------
  hipMemsetAsync(stats, 0, 512 * 4, stream);
  hipMemsetAsync(bufA, 0, 5280L * 256 * 4, stream);
  sconv_k<128, 256, 8, false, 3><<<dim3((NS[4] + 31) / 32, 3), TPB, 0, stream>>>(
      bufB, ca[4], bufA, inv[4], list[4], cnt + 4, nullptr, Hs[4], Wd[4], 128, 256, 0);
  bn_stats2_k<256><<<1024, TPB, 0, stream>>>(bufA, cnt + 4, stats);
  bn_fin_k<<<1, 256, 0, stream>>>(stats, cnt + 4, bg[4], bb[4], bnsc, 256);
  hipMemsetAsync(bufB, 0, 5280L * 256 * 4, stream);
  sconv_k<256, 256, 8, true, 3><<<dim3((NS[4] + 31) / 32, 3), TPB, 0, stream>>>(
      bufA, cb[4], bufB, inv[4], list[4], cnt + 4, bnsc, Hs[4], Wd[4], 256, 256, 0);
  {
    int nb = nblk(NS[5]);
    poolA_k<<<nb, TPB, 0, stream>>>(inv[4], Hs[4], Wd[4], Hs[5], Wd[5], (int)NS[5], bcnt);
    scan_k<<<1, 1024, 0, stream>>>(bcnt, nb, cnt + 5);
    poolB_k<<<nb, TPB, 0, stream>>>(inv[4], Hs[4], Wd[4], Hs[5], Wd[5], (int)NS[5], bcnt,
                                    list[5], inv[5], cap[5]);
  }
  pool_val_k<256><<<1024, TPB, 0, stream>>>(bufB, inv[4], list[5], cnt + 5, Hs[4], Wd[4], Hs[5], Wd[5], bufA);

  // ---------- GRUs ----------
  long ngb = 286720L * 4;
  hipMemsetAsync(yg, 0, ngb, stream);
  hipMemsetAsync(yc, 0, ngb, stream);
  hipMemsetAsync(h1d, 0, ngb, stream);
  hipMemsetAsync(h2d, 0, ngb, stream);
  sconv_k<256, 256, 4, false, 9><<<dim3((NS[5] + 15) / 16, 9), TPB, 0, stream>>>(
      bufA, g1Wg, yg, inv[5], list[5], cnt + 5, nullptr, Hs[5], Wd[5], 512, 512, 0);
  sconv_k<256, 256, 4, false, 9><<<dim3((NS[5] + 15) / 16, 9), TPB, 0, stream>>>(
      bufA, g1Wc, yc, inv[5], list[5], cnt + 5, nullptr, Hs[5], Wd[5], 512, 256, 0);
  gru_pw2_k<<<512, TPB, 0, stream>>>(yg, yc, list[5], cnt + 5, h1d, h1c);
  hipMemsetAsync(yg, 0, ngb, stream);
  hipMemsetAsync(yc, 0, ngb, stream);
  sconv_k<256, 256, 4, false, 9><<<dim3((NS[5] + 15) / 16, 9), TPB, 0, stream>>>(
      h1c, g2Wg, yg, inv[5], list[5], cnt + 5, nullptr, Hs[5], Wd[5], 512, 512, 0);
  sconv_k<256, 256, 4, false, 9><<<dim3((NS[5] + 15) / 16, 9), TPB, 0, stream>>>(
      h1c, g2Wc, yc, inv[5], list[5], cnt + 5, nullptr, Hs[5], Wd[5], 512, 256, 0);
  gru_pw2_k<<<512, TPB, 0, stream>>>(yg, yc, list[5], cnt + 5, h2d, nullptr);

  // ---------- head (partials alias the now-free conv buffers) ----------
  float* part = bufA;    // KS*32*1024 = 4,587,520 floats <= BUF
  float* part2 = bufB;   // JS2*13440 floats
  lin1_part2_k<<<dim3(KS, 4), TPB, 0, stream>>>(h2d, W1, part);
  lin1_reduce_k<<<nblk(32L * 1024), TPB, 0, stream>>>(part, b1, y1);
  lin2_part_k<<<dim3(nblk(32L * 420), JS2), TPB, 0, stream>>>(y1, W2, part2);
  lin2_fin_k<<<nblk(32L * 420), TPB, 0, stream>>>(part2, b2, (float*)d_out);
}

// Round 5
// 1294.031 us; speedup vs baseline: 4.9505x; 1.2911x over previous
//
#include <hip/hip_runtime.h>
#include <stdint.h>

#define TPB 256

typedef _Float16 half_t;
typedef __attribute__((ext_vector_type(8))) _Float16 f16x8;
typedef __attribute__((ext_vector_type(4))) float f32x4;

static inline int nblk(long n) { return (int)((n + TPB - 1) / TPB); }
static inline int gmin(long a, long b) { return (int)(a < b ? a : b); }

// ---------- scan-based compaction (no global atomics) ----------
__device__ __forceinline__ bool act0(const float* x, int i) {
  float2 v = *(const float2*)(x + 2L * i);
  return (v.x != 0.f) || (v.y != 0.f);
}

__global__ void cmpA0_k(const float* __restrict__ x, int n, int* __restrict__ bcnt) {
  int i = blockIdx.x * TPB + threadIdx.x;
  bool a = (i < n) && act0(x, i);
  unsigned long long bal = __ballot(a);
  __shared__ int wc[4];
  if ((threadIdx.x & 63) == 0) wc[threadIdx.x >> 6] = __popcll(bal);
  __syncthreads();
  if (threadIdx.x == 0) bcnt[blockIdx.x] = wc[0] + wc[1] + wc[2] + wc[3];
}

__global__ void cmpB0_k(const float* __restrict__ x, int n, const int* __restrict__ bbase,
                        int* __restrict__ list, int* __restrict__ inv, int cap) {
  int i = blockIdx.x * TPB + threadIdx.x;
  bool a = (i < n) && act0(x, i);
  unsigned long long bal = __ballot(a);
  __shared__ int wc[4];
  int wid = threadIdx.x >> 6, lane = threadIdx.x & 63;
  if (lane == 0) wc[wid] = __popcll(bal);
  __syncthreads();
  int base = bbase[blockIdx.x];
  for (int w = 0; w < wid; ++w) base += wc[w];
  if (i < n) {
    int pos = base + __popcll(bal & ((1ull << lane) - 1));
    if (a && pos < cap) { list[pos] = i; inv[i] = pos; }
    else inv[i] = -1;
  }
}

__device__ __forceinline__ bool actp(const int* invp, int Hp, int Wp, int Ho, int Wo, int i) {
  int wo = i % Wo; int t = i / Wo; int ho = t % Ho; int bb = t / Ho;
  long rb = ((long)bb * Hp + 2 * ho) * Wp + 2 * wo;
  bool a = false;
  #pragma unroll
  for (int kh = 0; kh < 3; ++kh)
    #pragma unroll
    for (int kw = 0; kw < 3; ++kw)
      a |= (invp[rb + kh * Wp + kw] >= 0);
  return a;
}

__global__ void poolA_k(const int* __restrict__ invp, int Hp, int Wp, int Ho, int Wo,
                        int n, int* __restrict__ bcnt) {
  int i = blockIdx.x * TPB + threadIdx.x;
  bool a = (i < n) && actp(invp, Hp, Wp, Ho, Wo, i);
  unsigned long long bal = __ballot(a);
  __shared__ int wc[4];
  if ((threadIdx.x & 63) == 0) wc[threadIdx.x >> 6] = __popcll(bal);
  __syncthreads();
  if (threadIdx.x == 0) bcnt[blockIdx.x] = wc[0] + wc[1] + wc[2] + wc[3];
}

__global__ void poolB_k(const int* __restrict__ invp, int Hp, int Wp, int Ho, int Wo, int n,
                        const int* __restrict__ bbase, int* __restrict__ list,
                        int* __restrict__ inv, int cap) {
  int i = blockIdx.x * TPB + threadIdx.x;
  bool a = (i < n) && actp(invp, Hp, Wp, Ho, Wo, i);
  unsigned long long bal = __ballot(a);
  __shared__ int wc[4];
  int wid = threadIdx.x >> 6, lane = threadIdx.x & 63;
  if (lane == 0) wc[wid] = __popcll(bal);
  __syncthreads();
  int base = bbase[blockIdx.x];
  for (int w = 0; w < wid; ++w) base += wc[w];
  if (i < n) {
    int pos = base + __popcll(bal & ((1ull << lane) - 1));
    if (a && pos < cap) { list[pos] = i; inv[i] = pos; }
    else inv[i] = -1;
  }
}

// single-block exclusive scan of bcnt[0..n); total -> *total
__global__ void scan_k(int* __restrict__ b, int n, int* __restrict__ total) {
  __shared__ int sh[1024];
  __shared__ int sc;
  if (threadIdx.x == 0) sc = 0;
  __syncthreads();
  for (int base = 0; base < n; base += 1024) {
    int i = base + threadIdx.x;
    int v = (i < n) ? b[i] : 0;
    sh[threadIdx.x] = v;
    __syncthreads();
    for (int o = 1; o < 1024; o <<= 1) {
      int t = (threadIdx.x >= o) ? sh[threadIdx.x - o] : 0;
      __syncthreads();
      sh[threadIdx.x] += t;
      __syncthreads();
    }
    if (i < n) b[i] = sh[threadIdx.x] - v + sc;
    __syncthreads();
    if (threadIdx.x == 0) sc += sh[1023];
    __syncthreads();
  }
  if (threadIdx.x == 0) *total = sc;
}

// ---------- pooled values ----------
template <int C>
__global__ void pool_val_k(const float* __restrict__ xin, const int* __restrict__ invp,
                           const int* __restrict__ list, const int* __restrict__ cnt,
                           int Hp, int Wp, int Ho, int Wo, float* __restrict__ y) {
  long total = (long)cnt[0] * C;
  for (long i = (long)blockIdx.x * TPB + threadIdx.x; i < total; i += (long)gridDim.x * TPB) {
    int c = (int)(i & (C - 1));
    int r = (int)(i / C);
    int site = list[r];
    int wo = site % Wo; int t = site / Wo; int ho = t % Ho; int bb = t / Ho;
    long rb = ((long)bb * Hp + 2 * ho) * Wp + 2 * wo;
    float best = -1e30f;
    #pragma unroll
    for (int kh = 0; kh < 3; ++kh)
      #pragma unroll
      for (int kw = 0; kw < 3; ++kw) {
        int j = invp[rb + kh * Wp + kw];
        if (j >= 0) best = fmaxf(best, xin[(long)j * C + c]);
      }
    y[i] = best;
  }
}

template <int C>
__global__ void pool_val_f16_k(const float* __restrict__ xin, const int* __restrict__ invp,
                               const int* __restrict__ list, const int* __restrict__ cnt,
                               int Hp, int Wp, int Ho, int Wo, half_t* __restrict__ y) {
  long total = (long)cnt[0] * C;
  for (long i = (long)blockIdx.x * TPB + threadIdx.x; i < total; i += (long)gridDim.x * TPB) {
    int c = (int)(i & (C - 1));
    int r = (int)(i / C);
    int site = list[r];
    int wo = site % Wo; int t = site / Wo; int ho = t % Ho; int bb = t / Ho;
    long rb = ((long)bb * Hp + 2 * ho) * Wp + 2 * wo;
    float best = -1e30f;
    #pragma unroll
    for (int kh = 0; kh < 3; ++kh)
      #pragma unroll
      for (int kw = 0; kw < 3; ++kw) {
        int j = invp[rb + kh * Wp + kw];
        if (j >= 0) best = fmaxf(best, xin[(long)j * C + c]);
      }
    y[i] = (half_t)best;
  }
}

// ---------- VALU submanifold conv (small CI levels) ----------
template <int CI, int CO, int ACC, bool BN>
__global__ void sconv_k(const float* __restrict__ xin, const float* __restrict__ Wt,
                        float* __restrict__ y, const int* __restrict__ inv,
                        const int* __restrict__ list, const int* __restrict__ cnt,
                        const float* __restrict__ bnsc, int H, int W, int wci, int wco,
                        int dense_in) {
  constexpr int CW = 4;
  constexpr int NCOL = CO / CW;
  constexpr int SG = TPB / NCOL;
  constexpr int S = SG * ACC;
  constexpr int CIP = CI + 1;
  __shared__ float st[S * CIP];
  __shared__ int nbr[S * 9];
  const int nact = cnt[0];
  const int col = threadIdx.x % NCOL;
  const int sg = threadIdx.x / NCOL;
  const int co0 = col * CW;
  for (int base = blockIdx.x * S; base < nact; base += gridDim.x * S) {
    int ns = min(S, nact - base);
    for (int i = threadIdx.x; i < ns * 9; i += TPB) {
      int s = i / 9, nb = i - s * 9;
      int site = list[base + s];
      int w = site % W; int t = site / W; int h = t % H; int bb = t / H;
      int hh = h + nb / 3 - 1, ww = w + (nb - (nb / 3) * 3) - 1;
      int j = -1;
      if ((unsigned)hh < (unsigned)H && (unsigned)ww < (unsigned)W) {
        int ss = (bb * H + hh) * W + ww;
        j = dense_in ? ss : inv[ss];
      }
      nbr[i] = j;
    }
    __syncthreads();
    float acc[CW][ACC];
    #pragma unroll
    for (int q = 0; q < CW; ++q)
      #pragma unroll
      for (int a = 0; a < ACC; ++a) acc[q][a] = 0.f;
    for (int nb = 0; nb < 9; ++nb) {
      for (int i = threadIdx.x; i < ns * CI; i += TPB) {
        int s = i / CI, ci = i - s * CI;
        int j = nbr[s * 9 + nb];
        float v = 0.f;
        if (j >= 0) {
          v = xin[(long)j * CI + ci];
          if (BN) v = fmaxf(fmaf(v, bnsc[ci], bnsc[CI + ci]), 0.f);
        }
        st[s * CIP + ci] = v;
      }
      __syncthreads();
      const float* wp = Wt + (long)(nb * wci) * wco + co0;
      const float* sp = st + sg * ACC * CIP;
      #pragma unroll 4
      for (int ci = 0; ci < CI; ++ci) {
        float4 wv = *(const float4*)(wp + (long)ci * wco);
        #pragma unroll
        for (int a = 0; a < ACC; ++a) {
          float xv = sp[a * CIP + ci];
          acc[0][a] = fmaf(xv, wv.x, acc[0][a]);
          acc[1][a] = fmaf(xv, wv.y, acc[1][a]);
          acc[2][a] = fmaf(xv, wv.z, acc[2][a]);
          acc[3][a] = fmaf(xv, wv.w, acc[3][a]);
        }
      }
      __syncthreads();
    }
    #pragma unroll
    for (int a = 0; a < ACC; ++a) {
      int s = sg * ACC + a;
      if (s < ns) {
        float* yp = y + (long)(base + s) * CO + co0;
        float4 o; o.x = acc[0][a]; o.y = acc[1][a]; o.z = acc[2][a]; o.w = acc[3][a];
        *(float4*)yp = o;
      }
    }
  }
}

// ---------- weight transpose+convert: W[tap][ci][co] f32 -> Wt[tap][co][ci] f16 ----------
__global__ void wtr_k(const float* __restrict__ Wsrc, half_t* __restrict__ dst,
                      int CI, int CO, int wci, int wco) {
  long total = 9L * CO * CI;
  for (long i = (long)blockIdx.x * TPB + threadIdx.x; i < total; i += (long)gridDim.x * TPB) {
    int ci = (int)(i % CI);
    long t = i / CI;
    int co = (int)(t % CO);
    int tap = (int)(t / CO);
    dst[i] = (half_t)Wsrc[((long)tap * wci + ci) * wco + co];
  }
}

// ---------- MFMA submanifold conv: Y[s,co] = sum_tap X[nbr(s,tap),:] @ W[tap] ----------
// block: 4 waves, 64 sites x 64 co; wave: 16 sites x 64 co.
template <int CI, int CO>
__global__ __launch_bounds__(256) void mconv_k(const half_t* __restrict__ X,
                                               const half_t* __restrict__ Wt,
                                               float* __restrict__ y,
                                               const int* __restrict__ inv,
                                               const int* __restrict__ list,
                                               const int* __restrict__ cnt,
                                               int H, int W) {
  const int nact = cnt[0];
  const int base = blockIdx.x * 64;
  if (base >= nact) return;
  const int lane = threadIdx.x & 63;
  const int wv = threadIdx.x >> 6;
  const int srow = lane & 15;   // A row (site) / B col (co)
  const int kseg = lane >> 4;   // k segment
  const int co0 = blockIdx.y * 64;
  const int s = base + wv * 16 + srow;
  int h = 0, w = 0, bb = 0;
  const bool sv = (s < nact);
  if (sv) {
    int site = list[s];
    w = site % W;
    int t = site / W;
    h = t % H;
    bb = t / H;
  }
  f32x4 acc0 = {0.f, 0.f, 0.f, 0.f};
  f32x4 acc1 = acc0, acc2 = acc0, acc3 = acc0;
  for (int tap = 0; tap < 9; ++tap) {
    int j = -1;
    if (sv) {
      int hh = h + tap / 3 - 1, ww = w + tap % 3 - 1;
      if ((unsigned)hh < (unsigned)H && (unsigned)ww < (unsigned)W)
        j = inv[(bb * H + hh) * W + ww];
    }
    const half_t* xp = X + (long)j * CI + kseg * 8;
    const half_t* wp = Wt + ((long)tap * CO + co0 + srow) * CI + kseg * 8;
    #pragma unroll
    for (int k0 = 0; k0 < CI; k0 += 32) {
      f16x8 av;
      #pragma unroll
      for (int z = 0; z < 8; ++z) av[z] = (_Float16)0.f;
      if (j >= 0) av = *(const f16x8*)(xp + k0);
      f16x8 b0 = *(const f16x8*)(wp + k0);
      f16x8 b1 = *(const f16x8*)(wp + 16 * CI + k0);
      f16x8 b2 = *(const f16x8*)(wp + 32 * CI + k0);
      f16x8 b3 = *(const f16x8*)(wp + 48 * CI + k0);
      acc0 = __builtin_amdgcn_mfma_f32_16x16x32_f16(av, b0, acc0, 0, 0, 0);
      acc1 = __builtin_amdgcn_mfma_f32_16x16x32_f16(av, b1, acc1, 0, 0, 0);
      acc2 = __builtin_amdgcn_mfma_f32_16x16x32_f16(av, b2, acc2, 0, 0, 0);
      acc3 = __builtin_amdgcn_mfma_f32_16x16x32_f16(av, b3, acc3, 0, 0, 0);
    }
  }
  // C/D: col = lane&15, row = (lane>>4)*4 + reg
  #pragma unroll
  for (int r = 0; r < 4; ++r) {
    int ss = base + wv * 16 + kseg * 4 + r;
    if (ss < nact) {
      float* yp = y + (long)ss * CO + co0 + srow;
      yp[0] = acc0[r];
      yp[16] = acc1[r];
      yp[32] = acc2[r];
      yp[48] = acc3[r];
    }
  }
}

// ---------- BN stats over compacted rows ----------
template <int CO>
__global__ void bn_stats2_k(const float* __restrict__ y, const int* __restrict__ cnt,
                            float* __restrict__ stats) {
  __shared__ float ls[512];
  for (int i = threadIdx.x; i < 2 * CO; i += TPB) ls[i] = 0.f;
  __syncthreads();
  long total = (long)cnt[0] * CO;
  long i0 = (long)blockIdx.x * TPB + threadIdx.x;
  int c = (int)(i0 & (CO - 1));
  float s = 0.f, s2 = 0.f;
  for (long i = i0; i < total; i += (long)gridDim.x * TPB) {
    float v = y[i];
    s += v; s2 += v * v;
  }
  atomicAdd(&ls[c], s);
  atomicAdd(&ls[CO + c], s2);
  __syncthreads();
  for (int i = threadIdx.x; i < 2 * CO; i += TPB) atomicAdd(&stats[i], ls[i]);
}

__global__ void bn_fin_k(const float* __restrict__ stats, const int* __restrict__ cnt,
                         const float* __restrict__ gamma, const float* __restrict__ beta,
                         float* __restrict__ bnsc, int CO) {
  int c = threadIdx.x;
  if (c >= CO) return;
  float n = fmaxf((float)cnt[0], 1.f);
  float mean = stats[c] / n;
  float var = fmaxf(stats[CO + c] / n - mean * mean, 0.f);
  float sc = gamma[c] * rsqrtf(var + 1e-4f);
  bnsc[c] = sc;
  bnsc[CO + c] = beta[c] - mean * sc;
}

// ---------- BN apply + ReLU + f16 convert ----------
template <int C>
__global__ void bnapply_f16_k(const float* __restrict__ y, const int* __restrict__ cnt,
                              const float* __restrict__ bnsc, half_t* __restrict__ out) {
  long total = (long)cnt[0] * C;
  for (long i = (long)blockIdx.x * TPB + threadIdx.x; i < total; i += (long)gridDim.x * TPB) {
    int c = (int)(i & (C - 1));
    out[i] = (half_t)fmaxf(fmaf(y[i], bnsc[c], bnsc[C + c]), 0.f);
  }
}

// ---------- GRU pointwise ----------
__global__ void gru_pw2_k(const float* __restrict__ yg, const float* __restrict__ yc,
                          const int* __restrict__ list, const int* __restrict__ cnt,
                          float* __restrict__ hdense, half_t* __restrict__ hcomp) {
  long total = (long)cnt[0] * 256;
  for (long i = (long)blockIdx.x * TPB + threadIdx.x; i < total; i += (long)gridDim.x * TPB) {
    float u = 1.f / (1.f + expf(-yg[i]));
    float c = tanhf(yc[i]);
    float v = u * c;
    if (hcomp) hcomp[i] = (half_t)v;
    int r = (int)(i >> 8), co = (int)(i & 255);
    hdense[(long)list[r] * 256 + co] = v;
  }
}

// ---------- head ----------
#define KS 140
__global__ void lin1_part2_k(const float* __restrict__ h2, const float* __restrict__ W1,
                             float* __restrict__ part) {
  __shared__ float sh[32][65];
  int kc = blockIdx.x;
  int j = blockIdx.y * TPB + threadIdx.x;
  int k0 = kc * 64;
  for (int i = threadIdx.x; i < 32 * 64; i += TPB) {
    int b = i >> 6, kk = i & 63;
    int k = k0 + kk;
    int c = k / 35, s = k - c * 35;
    sh[b][kk] = h2[(long)b * 8960 + s * 256 + c];
  }
  __syncthreads();
  float acc[32];
  #pragma unroll
  for (int b = 0; b < 32; ++b) acc[b] = 0.f;
  #pragma unroll 4
  for (int kk = 0; kk < 64; ++kk) {
    float w = W1[(long)(k0 + kk) * 1024 + j];
    #pragma unroll
    for (int b = 0; b < 32; ++b) acc[b] = fmaf(sh[b][kk], w, acc[b]);
  }
  #pragma unroll
  for (int b = 0; b < 32; ++b) part[((long)(kc * 32 + b)) * 1024 + j] = acc[b];
}

__global__ void lin1_reduce_k(const float* __restrict__ part, const float* __restrict__ b1,
                              float* __restrict__ y1) {
  int i = blockIdx.x * TPB + threadIdx.x;
  if (i >= 32 * 1024) return;
  int b = i >> 10, j = i & 1023;
  float a = b1[j];
  for (int kc = 0; kc < KS; ++kc) a += part[(long)kc * 32768 + b * 1024 + j];
  y1[i] = fmaxf(a, 0.f);
}

#define JS2 8
__global__ void lin2_part_k(const float* __restrict__ y1, const float* __restrict__ W2,
                            float* __restrict__ part2) {
  int i = blockIdx.x * TPB + threadIdx.x;
  if (i >= 32 * 420) return;
  int b = i / 420, o = i - b * 420;
  int j0 = blockIdx.y * 128;
  float a = 0.f;
  const float* yp = y1 + b * 1024 + j0;
  const float* wp = W2 + (long)j0 * 420 + o;
  #pragma unroll 8
  for (int j = 0; j < 128; ++j) a = fmaf(yp[j], wp[(long)j * 420], a);
  part2[(long)blockIdx.y * 13440 + i] = a;
}

__global__ void lin2_fin_k(const float* __restrict__ part2, const float* __restrict__ b2,
                           float* __restrict__ out) {
  int i = blockIdx.x * TPB + threadIdx.x;
  if (i >= 32 * 420) return;
  int o = i % 420;
  float a = b2[o];
  #pragma unroll
  for (int js = 0; js < JS2; ++js) a += part2[(long)js * 13440 + i];
  out[i] = a;
}

extern "C" void kernel_launch(void* const* d_in, const int* in_sizes, int n_in,
                              void* d_out, int out_size, void* d_ws, size_t ws_size,
                              hipStream_t stream) {
  const float* x = (const float*)d_in[0];
  const float* ca[5] = {(const float*)d_in[2], (const float*)d_in[6], (const float*)d_in[10],
                        (const float*)d_in[14], (const float*)d_in[18]};
  const float* bg[5] = {(const float*)d_in[3], (const float*)d_in[7], (const float*)d_in[11],
                        (const float*)d_in[15], (const float*)d_in[19]};
  const float* bb[5] = {(const float*)d_in[4], (const float*)d_in[8], (const float*)d_in[12],
                        (const float*)d_in[16], (const float*)d_in[20]};
  const float* cb[5] = {(const float*)d_in[5], (const float*)d_in[9], (const float*)d_in[13],
                        (const float*)d_in[17], (const float*)d_in[21]};
  const float* g1Wg = (const float*)d_in[22];
  const float* g1Wc = (const float*)d_in[23];
  const float* g2Wg = (const float*)d_in[24];
  const float* g2Wc = (const float*)d_in[25];
  const float* W1 = (const float*)d_in[26];
  const float* b1 = (const float*)d_in[27];
  const float* W2 = (const float*)d_in[28];
  const float* b2 = (const float*)d_in[29];

  const int Hs[6] = {191, 95, 47, 23, 11, 5};
  const int Wd[6] = {255, 127, 63, 31, 15, 7};
  const long NS[6] = {1558560, 386080, 94752, 22816, 5280, 1120};
  const int cap[6] = {400000, 386080, 94752, 22816, 5280, 1120};

  // ---- workspace: f32 region, f16 region, int region ----
  float* ws = (float*)d_ws;
  const long BUF = 12354560;
  long off = 0;
  float* bufA = ws + off; off += BUF;
  float* bufB = ws + off; off += BUF;
  float* yg = ws + off;   off += 286720;
  float* yc = ws + off;   off += 286720;
  float* stats = ws + off; off += 512;
  float* bnsc = ws + off;  off += 512;
  float* y1 = ws + off;    off += 32L * 1024;

  half_t* hbase = (half_t*)(ws + off);
  long hoff = 0;
  half_t* hbufA = hbase + hoff; hoff += 6100992;   // max: 94752*64
  half_t* hbufB = hbase + hoff; hoff += 6100992;
  half_t* wt_ca2 = hbase + hoff; hoff += 9L * 64 * 32;
  half_t* wt_cb2 = hbase + hoff; hoff += 9L * 64 * 64;
  half_t* wt_ca3 = hbase + hoff; hoff += 9L * 128 * 64;
  half_t* wt_cb3 = hbase + hoff; hoff += 9L * 128 * 128;
  half_t* wt_ca4 = hbase + hoff; hoff += 9L * 256 * 128;
  half_t* wt_cb4 = hbase + hoff; hoff += 9L * 256 * 256;
  half_t* wt_g1g = hbase + hoff; hoff += 9L * 256 * 256;
  half_t* wt_g1c = hbase + hoff; hoff += 9L * 256 * 256;
  half_t* wt_g2g = hbase + hoff; hoff += 9L * 256 * 256;
  half_t* wt_g2c = hbase + hoff; hoff += 9L * 256 * 256;

  int* ip = (int*)(hbase + hoff);
  long ioff = 0;
  int* cnt = ip + ioff; ioff += 16;
  int* bcnt = ip + ioff; ioff += 8192;
  int* list[6]; int* inv[6];
  for (int l = 0; l < 6; ++l) { list[l] = ip + ioff; ioff += cap[l]; }
  for (int l = 0; l < 6; ++l) { inv[l] = ip + ioff; ioff += NS[l]; }
  size_t needed = (size_t)off * 4 + (size_t)hoff * 2 + (size_t)ioff * 4;
  if (ws_size < needed) return;

  float* h1d = (float*)d_out + 13440;
  float* h2d = h1d + 286720;

  // ---- weight transpose/convert (independent of data flow) ----
  wtr_k<<<nblk(9L * 64 * 32), TPB, 0, stream>>>(ca[2], wt_ca2, 32, 64, 32, 64);
  wtr_k<<<nblk(9L * 64 * 64), TPB, 0, stream>>>(cb[2], wt_cb2, 64, 64, 64, 64);
  wtr_k<<<nblk(9L * 128 * 64), TPB, 0, stream>>>(ca[3], wt_ca3, 64, 128, 64, 128);
  wtr_k<<<nblk(9L * 128 * 128), TPB, 0, stream>>>(cb[3], wt_cb3, 128, 128, 128, 128);
  wtr_k<<<nblk(9L * 256 * 128), TPB, 0, stream>>>(ca[4], wt_ca4, 128, 256, 128, 256);
  wtr_k<<<gmin(nblk(9L * 256 * 256), 2048), TPB, 0, stream>>>(cb[4], wt_cb4, 256, 256, 256, 256);
  wtr_k<<<gmin(nblk(9L * 256 * 256), 2048), TPB, 0, stream>>>(g1Wg, wt_g1g, 256, 256, 512, 512);
  wtr_k<<<gmin(nblk(9L * 256 * 256), 2048), TPB, 0, stream>>>(g1Wc, wt_g1c, 256, 256, 512, 256);
  wtr_k<<<gmin(nblk(9L * 256 * 256), 2048), TPB, 0, stream>>>(g2Wg, wt_g2g, 256, 256, 512, 512);
  wtr_k<<<gmin(nblk(9L * 256 * 256), 2048), TPB, 0, stream>>>(g2Wc, wt_g2c, 256, 256, 512, 256);

  // ---- level-0 compaction ----
  {
    int nb = nblk(NS[0]);
    cmpA0_k<<<nb, TPB, 0, stream>>>(x, (int)NS[0], bcnt);
    scan_k<<<1, 1024, 0, stream>>>(bcnt, nb, cnt + 0);
    cmpB0_k<<<nb, TPB, 0, stream>>>(x, (int)NS[0], bcnt, list[0], inv[0], cap[0]);
  }

  // ---------- level 1 (VALU) ----------
  hipMemsetAsync(stats, 0, 512 * 4, stream);
  sconv_k<2, 16, 8, false><<<gmin((cap[0] + 511) / 512, 1024), TPB, 0, stream>>>(
      x, ca[0], bufA, nullptr, list[0], cnt + 0, nullptr, Hs[0], Wd[0], 2, 16, 1);
  bn_stats2_k<16><<<1024, TPB, 0, stream>>>(bufA, cnt + 0, stats);
  bn_fin_k<<<1, 256, 0, stream>>>(stats, cnt + 0, bg[0], bb[0], bnsc, 16);
  sconv_k<16, 16, 4, true><<<gmin((cap[0] + 255) / 256, 1024), TPB, 0, stream>>>(
      bufA, cb[0], bufB, inv[0], list[0], cnt + 0, bnsc, Hs[0], Wd[0], 16, 16, 0);
  {
    int nb = nblk(NS[1]);
    poolA_k<<<nb, TPB, 0, stream>>>(inv[0], Hs[0], Wd[0], Hs[1], Wd[1], (int)NS[1], bcnt);
    scan_k<<<1, 1024, 0, stream>>>(bcnt, nb, cnt + 1);
    poolB_k<<<nb, TPB, 0, stream>>>(inv[0], Hs[0], Wd[0], Hs[1], Wd[1], (int)NS[1], bcnt,
                                    list[1], inv[1], cap[1]);
  }
  pool_val_k<16><<<2048, TPB, 0, stream>>>(bufB, inv[0], list[1], cnt + 1, Hs[0], Wd[0], Hs[1], Wd[1], bufA);

  // ---------- level 2 (VALU) ----------
  hipMemsetAsync(stats, 0, 512 * 4, stream);
  sconv_k<16, 32, 8, false><<<gmin((NS[1] + 255) / 256, 1024), TPB, 0, stream>>>(
      bufA, ca[1], bufB, inv[1], list[1], cnt + 1, nullptr, Hs[1], Wd[1], 16, 32, 0);
  bn_stats2_k<32><<<1024, TPB, 0, stream>>>(bufB, cnt + 1, stats);
  bn_fin_k<<<1, 256, 0, stream>>>(stats, cnt + 1, bg[1], bb[1], bnsc, 32);
  sconv_k<32, 32, 4, true><<<gmin((NS[1] + 127) / 128, 1024), TPB, 0, stream>>>(
      bufB, cb[1], bufA, inv[1], list[1], cnt + 1, bnsc, Hs[1], Wd[1], 32, 32, 0);
  {
    int nb = nblk(NS[2]);
    poolA_k<<<nb, TPB, 0, stream>>>(inv[1], Hs[1], Wd[1], Hs[2], Wd[2], (int)NS[2], bcnt);
    scan_k<<<1, 1024, 0, stream>>>(bcnt, nb, cnt + 2);
    poolB_k<<<nb, TPB, 0, stream>>>(inv[1], Hs[1], Wd[1], Hs[2], Wd[2], (int)NS[2], bcnt,
                                    list[2], inv[2], cap[2]);
  }
  pool_val_f16_k<32><<<2048, TPB, 0, stream>>>(bufA, inv[1], list[2], cnt + 2, Hs[1], Wd[1], Hs[2], Wd[2], hbufB);

  // ---------- level 3 (MFMA) ----------
  hipMemsetAsync(stats, 0, 512 * 4, stream);
  mconv_k<32, 64><<<dim3((cap[2] + 63) / 64, 1), TPB, 0, stream>>>(
      hbufB, wt_ca2, bufA, inv[2], list[2], cnt + 2, Hs[2], Wd[2]);
  bn_stats2_k<64><<<1024, TPB, 0, stream>>>(bufA, cnt + 2, stats);
  bn_fin_k<<<1, 256, 0, stream>>>(stats, cnt + 2, bg[2], bb[2], bnsc, 64);
  bnapply_f16_k<64><<<2048, TPB, 0, stream>>>(bufA, cnt + 2, bnsc, hbufA);
  mconv_k<64, 64><<<dim3((cap[2] + 63) / 64, 1), TPB, 0, stream>>>(
      hbufA, wt_cb2, bufB, inv[2], list[2], cnt + 2, Hs[2], Wd[2]);
  {
    int nb = nblk(NS[3]);
    poolA_k<<<nb, TPB, 0, stream>>>(inv[2], Hs[2], Wd[2], Hs[3], Wd[3], (int)NS[3], bcnt);
    scan_k<<<1, 1024, 0, stream>>>(bcnt, nb, cnt + 3);
    poolB_k<<<nb, TPB, 0, stream>>>(inv[2], Hs[2], Wd[2], Hs[3], Wd[3], (int)NS[3], bcnt,
                                    list[3], inv[3], cap[3]);
  }
  pool_val_f16_k<64><<<2048, TPB, 0, stream>>>(bufB, inv[2], list[3], cnt + 3, Hs[2], Wd[2], Hs[3], Wd[3], hbufB);

  // ---------- level 4 (MFMA) ----------
  hipMemsetAsync(stats, 0, 512 * 4, stream);
  mconv_k<64, 128><<<dim3((cap[3] + 63) / 64, 2), TPB, 0, stream>>>(
      hbufB, wt_ca3, bufA, inv[3], list[3], cnt + 3, Hs[3], Wd[3]);
  bn_stats2_k<128><<<1024, TPB, 0, stream>>>(bufA, cnt + 3, stats);
  bn_fin_k<<<1, 256, 0, stream>>>(stats, cnt + 3, bg[3], bb[3], bnsc, 128);
  bnapply_f16_k<128><<<2048, TPB, 0, stream>>>(bufA, cnt + 3, bnsc, hbufA);
  mconv_k<128, 128><<<dim3((cap[3] + 63) / 64, 2), TPB, 0, stream>>>(
      hbufA, wt_cb3, bufB, inv[3], list[3], cnt + 3, Hs[3], Wd[3]);
  {
    int nb = nblk(NS[4]);
    poolA_k<<<nb, TPB, 0, stream>>>(inv[3], Hs[3], Wd[3], Hs[4], Wd[4], (int)NS[4], bcnt);
    scan_k<<<1, 1024, 0, stream>>>(bcnt, nb, cnt + 4);
    poolB_k<<<nb, TPB, 0, stream>>>(inv[3], Hs[3], Wd[3], Hs[4], Wd[4], (int)NS[4], bcnt,
                                    list[4], inv[4], cap[4]);
  }
  pool_val_f16_k<128><<<2048, TPB, 0, stream>>>(bufB, inv[3], list[4], cnt + 4, Hs[3], Wd[3], Hs[4], Wd[4], hbufB);

  // ---------- level 5 (MFMA) ----------
  hipMemsetAsync(stats, 0, 512 * 4, stream);
  mconv_k<128, 256><<<dim3((cap[4] + 63) / 64, 4), TPB, 0, stream>>>(
      hbufB, wt_ca4, bufA, inv[4], list[4], cnt + 4, Hs[4], Wd[4]);
  bn_stats2_k<256><<<1024, TPB, 0, stream>>>(bufA, cnt + 4, stats);
  bn_fin_k<<<1, 256, 0, stream>>>(stats, cnt + 4, bg[4], bb[4], bnsc, 256);
  bnapply_f16_k<256><<<2048, TPB, 0, stream>>>(bufA, cnt + 4, bnsc, hbufA);
  mconv_k<256, 256><<<dim3((cap[4] + 63) / 64, 4), TPB, 0, stream>>>(
      hbufA, wt_cb4, bufB, inv[4], list[4], cnt + 4, Hs[4], Wd[4]);
  {
    int nb = nblk(NS[5]);
    poolA_k<<<nb, TPB, 0, stream>>>(inv[4], Hs[4], Wd[4], Hs[5], Wd[5], (int)NS[5], bcnt);
    scan_k<<<1, 1024, 0, stream>>>(bcnt, nb, cnt + 5);
    poolB_k<<<nb, TPB, 0, stream>>>(inv[4], Hs[4], Wd[4], Hs[5], Wd[5], (int)NS[5], bcnt,
                                    list[5], inv[5], cap[5]);
  }
  pool_val_f16_k<256><<<1024, TPB, 0, stream>>>(bufB, inv[4], list[5], cnt + 5, Hs[4], Wd[4], Hs[5], Wd[5], hbufB);

  // ---------- GRUs (MFMA; h=0 => h' = sigmoid(conv_u(x)) * tanh(conv_c(x))) ----------
  long ngb = 286720L * 4;
  hipMemsetAsync(h1d, 0, ngb, stream);
  hipMemsetAsync(h2d, 0, ngb, stream);
  mconv_k<256, 256><<<dim3((cap[5] + 63) / 64, 4), TPB, 0, stream>>>(
      hbufB, wt_g1g, yg, inv[5], list[5], cnt + 5, Hs[5], Wd[5]);
  mconv_k<256, 256><<<dim3((cap[5] + 63) / 64, 4), TPB, 0, stream>>>(
      hbufB, wt_g1c, yc, inv[5], list[5], cnt + 5, Hs[5], Wd[5]);
  gru_pw2_k<<<512, TPB, 0, stream>>>(yg, yc, list[5], cnt + 5, h1d, hbufA);
  mconv_k<256, 256><<<dim3((cap[5] + 63) / 64, 4), TPB, 0, stream>>>(
      hbufA, wt_g2g, yg, inv[5], list[5], cnt + 5, Hs[5], Wd[5]);
  mconv_k<256, 256><<<dim3((cap[5] + 63) / 64, 4), TPB, 0, stream>>>(
      hbufA, wt_g2c, yc, inv[5], list[5], cnt + 5, Hs[5], Wd[5]);
  gru_pw2_k<<<512, TPB, 0, stream>>>(yg, yc, list[5], cnt + 5, h2d, nullptr);

  // ---------- head (partials alias free conv buffers) ----------
  float* part = bufA;
  float* part2 = bufB;
  lin1_part2_k<<<dim3(KS, 4), TPB, 0, stream>>>(h2d, W1, part);
  lin1_reduce_k<<<nblk(32L * 1024), TPB, 0, stream>>>(part, b1, y1);
  lin2_part_k<<<dim3(nblk(32L * 420), JS2), TPB, 0, stream>>>(y1, W2, part2);
  lin2_fin_k<<<nblk(32L * 420), TPB, 0, stream>>>(part2, b2, (float*)d_out);
}

// Round 6
// 1022.115 us; speedup vs baseline: 6.2675x; 1.2660x over previous
//
#include <hip/hip_runtime.h>
#include <stdint.h>

#define TPB 256

typedef _Float16 half_t;
typedef __attribute__((ext_vector_type(8))) _Float16 f16x8;
typedef __attribute__((ext_vector_type(4))) float f32x4;

static inline int nblk(long n) { return (int)((n + TPB - 1) / TPB); }
static inline int gmin(long a, long b) { return (int)(a < b ? a : b); }

// ---------- scan-based compaction ----------
__device__ __forceinline__ bool act0(const float* x, int i) {
  float2 v = *(const float2*)(x + 2L * i);
  return (v.x != 0.f) || (v.y != 0.f);
}

__global__ void cmpA0_k(const float* __restrict__ x, int n, int* __restrict__ bcnt) {
  int i = blockIdx.x * TPB + threadIdx.x;
  bool a = (i < n) && act0(x, i);
  unsigned long long bal = __ballot(a);
  __shared__ int wc[4];
  if ((threadIdx.x & 63) == 0) wc[threadIdx.x >> 6] = __popcll(bal);
  __syncthreads();
  if (threadIdx.x == 0) bcnt[blockIdx.x] = wc[0] + wc[1] + wc[2] + wc[3];
}

__global__ void cmpB0_k(const float* __restrict__ x, int n, const int* __restrict__ bbase,
                        int* __restrict__ list, int* __restrict__ inv, int cap) {
  int i = blockIdx.x * TPB + threadIdx.x;
  bool a = (i < n) && act0(x, i);
  unsigned long long bal = __ballot(a);
  __shared__ int wc[4];
  int wid = threadIdx.x >> 6, lane = threadIdx.x & 63;
  if (lane == 0) wc[wid] = __popcll(bal);
  __syncthreads();
  int base = bbase[blockIdx.x];
  for (int w = 0; w < wid; ++w) base += wc[w];
  if (i < n) {
    int pos = base + __popcll(bal & ((1ull << lane) - 1));
    if (a && pos < cap) { list[pos] = i; inv[i] = pos; }
    else inv[i] = -1;
  }
}

__device__ __forceinline__ bool actp(const int* invp, int Hp, int Wp, int Ho, int Wo, int i) {
  int wo = i % Wo; int t = i / Wo; int ho = t % Ho; int bb = t / Ho;
  long rb = ((long)bb * Hp + 2 * ho) * Wp + 2 * wo;
  bool a = false;
  #pragma unroll
  for (int kh = 0; kh < 3; ++kh)
    #pragma unroll
    for (int kw = 0; kw < 3; ++kw)
      a |= (invp[rb + kh * Wp + kw] >= 0);
  return a;
}

__global__ void poolA_k(const int* __restrict__ invp, int Hp, int Wp, int Ho, int Wo,
                        int n, int* __restrict__ bcnt) {
  int i = blockIdx.x * TPB + threadIdx.x;
  bool a = (i < n) && actp(invp, Hp, Wp, Ho, Wo, i);
  unsigned long long bal = __ballot(a);
  __shared__ int wc[4];
  if ((threadIdx.x & 63) == 0) wc[threadIdx.x >> 6] = __popcll(bal);
  __syncthreads();
  if (threadIdx.x == 0) bcnt[blockIdx.x] = wc[0] + wc[1] + wc[2] + wc[3];
}

__global__ void poolB_k(const int* __restrict__ invp, int Hp, int Wp, int Ho, int Wo, int n,
                        const int* __restrict__ bbase, int* __restrict__ list,
                        int* __restrict__ inv, int cap) {
  int i = blockIdx.x * TPB + threadIdx.x;
  bool a = (i < n) && actp(invp, Hp, Wp, Ho, Wo, i);
  unsigned long long bal = __ballot(a);
  __shared__ int wc[4];
  int wid = threadIdx.x >> 6, lane = threadIdx.x & 63;
  if (lane == 0) wc[wid] = __popcll(bal);
  __syncthreads();
  int base = bbase[blockIdx.x];
  for (int w = 0; w < wid; ++w) base += wc[w];
  if (i < n) {
    int pos = base + __popcll(bal & ((1ull << lane) - 1));
    if (a && pos < cap) { list[pos] = i; inv[i] = pos; }
    else inv[i] = -1;
  }
}

__global__ void scan_k(int* __restrict__ b, int n, int* __restrict__ total) {
  __shared__ int sh[1024];
  __shared__ int sc;
  if (threadIdx.x == 0) sc = 0;
  __syncthreads();
  for (int base = 0; base < n; base += 1024) {
    int i = base + threadIdx.x;
    int v = (i < n) ? b[i] : 0;
    sh[threadIdx.x] = v;
    __syncthreads();
    for (int o = 1; o < 1024; o <<= 1) {
      int t = (threadIdx.x >= o) ? sh[threadIdx.x - o] : 0;
      __syncthreads();
      sh[threadIdx.x] += t;
      __syncthreads();
    }
    if (i < n) b[i] = sh[threadIdx.x] - v + sc;
    __syncthreads();
    if (threadIdx.x == 0) sc += sh[1023];
    __syncthreads();
  }
  if (threadIdx.x == 0) *total = sc;
}

// ---------- pooled values -> f16 compact rows ----------
template <int C>
__global__ void pool_val_f16_k(const float* __restrict__ xin, const int* __restrict__ invp,
                               const int* __restrict__ list, const int* __restrict__ cnt,
                               int Hp, int Wp, int Ho, int Wo, half_t* __restrict__ y) {
  long total = (long)cnt[0] * C;
  for (long i = (long)blockIdx.x * TPB + threadIdx.x; i < total; i += (long)gridDim.x * TPB) {
    int c = (int)(i & (C - 1));
    int r = (int)(i / C);
    int site = list[r];
    int wo = site % Wo; int t = site / Wo; int ho = t % Ho; int bb = t / Ho;
    long rb = ((long)bb * Hp + 2 * ho) * Wp + 2 * wo;
    float best = -1e30f;
    #pragma unroll
    for (int kh = 0; kh < 3; ++kh)
      #pragma unroll
      for (int kw = 0; kw < 3; ++kw) {
        int j = invp[rb + kh * Wp + kw];
        if (j >= 0) best = fmaxf(best, xin[(long)j * C + c]);
      }
    y[i] = (half_t)best;
  }
}

// ---------- dense x -> f16 ----------
__global__ void cvt_x_k(const float* __restrict__ x, half_t* __restrict__ xh, long n) {
  for (long i = (long)blockIdx.x * TPB + threadIdx.x; i < n; i += (long)gridDim.x * TPB)
    xh[i] = (half_t)x[i];
}

// ---------- weight pack: W[tap][ci][co] f32 -> per-tap [tap][co][ci] f16 ----------
__global__ void wtr_k(const float* __restrict__ Wsrc, half_t* __restrict__ dst,
                      int CI, int CO, int wci, int wco) {
  long total = 9L * CO * CI;
  for (long i = (long)blockIdx.x * TPB + threadIdx.x; i < total; i += (long)gridDim.x * TPB) {
    int ci = (int)(i % CI);
    long t = i / CI;
    int co = (int)(t % CO);
    int tap = (int)(t / CO);
    dst[i] = (half_t)Wsrc[((long)tap * wci + ci) * wco + co];
  }
}

// ---------- weight pack: K-packed [co][KP] f16, k = tap*CI+ci, zero pad ----------
__global__ void wtrp_k(const float* __restrict__ Wsrc, half_t* __restrict__ dst,
                       int CI, int CO, int KP, int wci, int wco) {
  long total = (long)CO * KP;
  for (long i = (long)blockIdx.x * TPB + threadIdx.x; i < total; i += (long)gridDim.x * TPB) {
    int k = (int)(i % KP);
    int co = (int)(i / KP);
    int tap = k / CI, ci = k - tap * CI;
    float v = (tap < 9) ? Wsrc[((long)tap * wci + ci) * wco + co] : 0.f;
    dst[i] = (half_t)v;
  }
}

// ---------- K-packed MFMA conv (CO<=32, all co in-wave); 64 sites/block ----------
template <int CI, int CO, bool DENSE>
__global__ __launch_bounds__(256) void mconvp_k(const half_t* __restrict__ X,
                                                const half_t* __restrict__ Wt,
                                                float* __restrict__ y,
                                                const int* __restrict__ inv,
                                                const int* __restrict__ list,
                                                const int* __restrict__ cnt,
                                                int H, int W) {
  constexpr int KP = ((9 * CI + 31) / 32) * 32;
  constexpr int NCO = CO / 16;
  const int nact = cnt[0];
  const int base = blockIdx.x * 64;
  if (base >= nact) return;
  __shared__ int nbr[64 * 9];
  for (int i = threadIdx.x; i < 64 * 9; i += TPB) {
    int s = i / 9, nb = i - s * 9;
    int j = -1;
    if (base + s < nact) {
      int site = list[base + s];
      int w = site % W; int t = site / W; int h = t % H; int bb = t / H;
      int hh = h + nb / 3 - 1, ww = w + nb % 3 - 1;
      if ((unsigned)hh < (unsigned)H && (unsigned)ww < (unsigned)W) {
        int ss = (bb * H + hh) * W + ww;
        j = DENSE ? ss : inv[ss];
      }
    }
    nbr[i] = j;
  }
  __syncthreads();
  const int lane = threadIdx.x & 63, wv = threadIdx.x >> 6;
  const int srow = lane & 15, kseg = lane >> 4;
  const int sloc = wv * 16 + srow;
  f32x4 acc[NCO];
  #pragma unroll
  for (int c = 0; c < NCO; ++c) acc[c] = (f32x4){0.f, 0.f, 0.f, 0.f};
  #pragma unroll
  for (int k0 = 0; k0 < KP; k0 += 32) {
    const int k = k0 + kseg * 8;
    f16x8 av;
    #pragma unroll
    for (int z = 0; z < 8; ++z) av[z] = (_Float16)0.f;
    if (CI >= 8) {
      int tap = k / CI;
      int ci = k - tap * CI;
      if (tap < 9) {
        int j = nbr[sloc * 9 + tap];
        if (j >= 0) av = *(const f16x8*)(X + (long)j * CI + ci);
      }
    } else {  // CI == 2
      #pragma unroll
      for (int q = 0; q < 4; ++q) {
        int kk = k + 2 * q;
        int tap = kk >> 1;
        if (tap < 9) {
          int j = nbr[sloc * 9 + tap];
          if (j >= 0) {
            const half_t* xp = X + (long)j * 2;
            av[2 * q] = xp[0];
            av[2 * q + 1] = xp[1];
          }
        }
      }
    }
    #pragma unroll
    for (int c = 0; c < NCO; ++c) {
      f16x8 bv = *(const f16x8*)(Wt + (long)(c * 16 + srow) * KP + k);
      acc[c] = __builtin_amdgcn_mfma_f32_16x16x32_f16(av, bv, acc[c], 0, 0, 0);
    }
  }
  #pragma unroll
  for (int c = 0; c < NCO; ++c)
    #pragma unroll
    for (int r = 0; r < 4; ++r) {
      int ss = base + wv * 16 + kseg * 4 + r;
      if (ss < nact) y[(long)ss * CO + c * 16 + srow] = acc[c][r];
    }
}

// ---------- per-tap MFMA conv, 64 sites x 64 co per block (mid levels) ----------
template <int CI, int CO>
__global__ __launch_bounds__(256) void mconv_k(const half_t* __restrict__ X,
                                               const half_t* __restrict__ Wt,
                                               float* __restrict__ y,
                                               const int* __restrict__ inv,
                                               const int* __restrict__ list,
                                               const int* __restrict__ cnt,
                                               int H, int W) {
  const int nact = cnt[0];
  const int base = blockIdx.x * 64;
  if (base >= nact) return;
  const int lane = threadIdx.x & 63;
  const int wv = threadIdx.x >> 6;
  const int srow = lane & 15;
  const int kseg = lane >> 4;
  const int co0 = blockIdx.y * 64;
  const int s = base + wv * 16 + srow;
  int h = 0, w = 0, bb = 0;
  const bool sv = (s < nact);
  if (sv) {
    int site = list[s];
    w = site % W;
    int t = site / W;
    h = t % H;
    bb = t / H;
  }
  f32x4 acc0 = {0.f, 0.f, 0.f, 0.f};
  f32x4 acc1 = acc0, acc2 = acc0, acc3 = acc0;
  for (int tap = 0; tap < 9; ++tap) {
    int j = -1;
    if (sv) {
      int hh = h + tap / 3 - 1, ww = w + tap % 3 - 1;
      if ((unsigned)hh < (unsigned)H && (unsigned)ww < (unsigned)W)
        j = inv[(bb * H + hh) * W + ww];
    }
    const half_t* xp = X + (long)j * CI + kseg * 8;
    const half_t* wp = Wt + ((long)tap * CO + co0 + srow) * CI + kseg * 8;
    #pragma unroll
    for (int k0 = 0; k0 < CI; k0 += 32) {
      f16x8 av;
      #pragma unroll
      for (int z = 0; z < 8; ++z) av[z] = (_Float16)0.f;
      if (j >= 0) av = *(const f16x8*)(xp + k0);
      f16x8 b0 = *(const f16x8*)(wp + k0);
      f16x8 b1 = *(const f16x8*)(wp + 16 * CI + k0);
      f16x8 b2 = *(const f16x8*)(wp + 32 * CI + k0);
      f16x8 b3 = *(const f16x8*)(wp + 48 * CI + k0);
      acc0 = __builtin_amdgcn_mfma_f32_16x16x32_f16(av, b0, acc0, 0, 0, 0);
      acc1 = __builtin_amdgcn_mfma_f32_16x16x32_f16(av, b1, acc1, 0, 0, 0);
      acc2 = __builtin_amdgcn_mfma_f32_16x16x32_f16(av, b2, acc2, 0, 0, 0);
      acc3 = __builtin_amdgcn_mfma_f32_16x16x32_f16(av, b3, acc3, 0, 0, 0);
    }
  }
  #pragma unroll
  for (int r = 0; r < 4; ++r) {
    int ss = base + wv * 16 + kseg * 4 + r;
    if (ss < nact) {
      float* yp = y + (long)ss * CO + co0 + srow;
      yp[0] = acc0[r];
      yp[16] = acc1[r];
      yp[32] = acc2[r];
      yp[48] = acc3[r];
    }
  }
}

// ---------- per-tap MFMA conv, 16 sites x 64 co per block (deep-K small-site) ----------
template <int CI, int CO>
__global__ __launch_bounds__(256) void mconv_sm_k(const half_t* __restrict__ X,
                                                  const half_t* __restrict__ Wt,
                                                  float* __restrict__ y,
                                                  const int* __restrict__ inv,
                                                  const int* __restrict__ list,
                                                  const int* __restrict__ cnt,
                                                  int H, int W) {
  const int nact = cnt[0];
  const int base = blockIdx.x * 16;
  if (base >= nact) return;
  __shared__ int nbr[16 * 9];
  for (int i = threadIdx.x; i < 16 * 9; i += TPB) {
    int s = i / 9, nb = i - s * 9;
    int j = -1;
    if (base + s < nact) {
      int site = list[base + s];
      int w = site % W; int t = site / W; int h = t % H; int bb = t / H;
      int hh = h + nb / 3 - 1, ww = w + nb % 3 - 1;
      if ((unsigned)hh < (unsigned)H && (unsigned)ww < (unsigned)W)
        j = inv[(bb * H + hh) * W + ww];
    }
    nbr[i] = j;
  }
  __syncthreads();
  const int lane = threadIdx.x & 63, wv = threadIdx.x >> 6;
  const int srow = lane & 15, kseg = lane >> 4;
  const int co = blockIdx.y * 64 + wv * 16 + srow;
  f32x4 acc = {0.f, 0.f, 0.f, 0.f};
  for (int tap = 0; tap < 9; ++tap) {
    int j = nbr[srow * 9 + tap];
    const half_t* xp = X + (long)j * CI + kseg * 8;
    const half_t* wp = Wt + ((long)tap * CO + co) * CI + kseg * 8;
    #pragma unroll
    for (int k0 = 0; k0 < CI; k0 += 32) {
      f16x8 av;
      #pragma unroll
      for (int z = 0; z < 8; ++z) av[z] = (_Float16)0.f;
      if (j >= 0) av = *(const f16x8*)(xp + k0);
      f16x8 bv = *(const f16x8*)(wp + k0);
      acc = __builtin_amdgcn_mfma_f32_16x16x32_f16(av, bv, acc, 0, 0, 0);
    }
  }
  #pragma unroll
  for (int r = 0; r < 4; ++r) {
    int ss = base + kseg * 4 + r;
    if (ss < nact) y[(long)ss * CO + co] = acc[r];
  }
}

// ---------- BN ----------
template <int CO>
__global__ void bn_stats2_k(const float* __restrict__ y, const int* __restrict__ cnt,
                            float* __restrict__ stats) {
  __shared__ float ls[512];
  for (int i = threadIdx.x; i < 2 * CO; i += TPB) ls[i] = 0.f;
  __syncthreads();
  long total = (long)cnt[0] * CO;
  long i0 = (long)blockIdx.x * TPB + threadIdx.x;
  int c = (int)(i0 & (CO - 1));
  float s = 0.f, s2 = 0.f;
  for (long i = i0; i < total; i += (long)gridDim.x * TPB) {
    float v = y[i];
    s += v; s2 += v * v;
  }
  atomicAdd(&ls[c], s);
  atomicAdd(&ls[CO + c], s2);
  __syncthreads();
  for (int i = threadIdx.x; i < 2 * CO; i += TPB) atomicAdd(&stats[i], ls[i]);
}

__global__ void bn_fin_k(const float* __restrict__ stats, const int* __restrict__ cnt,
                         const float* __restrict__ gamma, const float* __restrict__ beta,
                         float* __restrict__ bnsc, int CO) {
  int c = threadIdx.x;
  if (c >= CO) return;
  float n = fmaxf((float)cnt[0], 1.f);
  float mean = stats[c] / n;
  float var = fmaxf(stats[CO + c] / n - mean * mean, 0.f);
  float sc = gamma[c] * rsqrtf(var + 1e-4f);
  bnsc[c] = sc;
  bnsc[CO + c] = beta[c] - mean * sc;
}

template <int C>
__global__ void bnapply_f16_k(const float* __restrict__ y, const int* __restrict__ cnt,
                              const float* __restrict__ bnsc, half_t* __restrict__ out) {
  long total = (long)cnt[0] * C;
  for (long i = (long)blockIdx.x * TPB + threadIdx.x; i < total; i += (long)gridDim.x * TPB) {
    int c = (int)(i & (C - 1));
    out[i] = (half_t)fmaxf(fmaf(y[i], bnsc[c], bnsc[C + c]), 0.f);
  }
}

// ---------- GRU pointwise ----------
__global__ void gru_pw2_k(const float* __restrict__ yg, const float* __restrict__ yc,
                          const int* __restrict__ list, const int* __restrict__ cnt,
                          float* __restrict__ hdense, half_t* __restrict__ hcomp) {
  long total = (long)cnt[0] * 256;
  for (long i = (long)blockIdx.x * TPB + threadIdx.x; i < total; i += (long)gridDim.x * TPB) {
    float u = 1.f / (1.f + expf(-yg[i]));
    float c = tanhf(yc[i]);
    float v = u * c;
    if (hcomp) hcomp[i] = (half_t)v;
    int r = (int)(i >> 8), co = (int)(i & 255);
    hdense[(long)list[r] * 256 + co] = v;
  }
}

// ---------- head ----------
#define KS 140
__global__ void lin1_part2_k(const float* __restrict__ h2, const float* __restrict__ W1,
                             float* __restrict__ part) {
  __shared__ float sh[32][65];
  int kc = blockIdx.x;
  int j = blockIdx.y * TPB + threadIdx.x;
  int k0 = kc * 64;
  for (int i = threadIdx.x; i < 32 * 64; i += TPB) {
    int b = i >> 6, kk = i & 63;
    int k = k0 + kk;
    int c = k / 35, s = k - c * 35;
    sh[b][kk] = h2[(long)b * 8960 + s * 256 + c];
  }
  __syncthreads();
  float acc[32];
  #pragma unroll
  for (int b = 0; b < 32; ++b) acc[b] = 0.f;
  #pragma unroll 4
  for (int kk = 0; kk < 64; ++kk) {
    float w = W1[(long)(k0 + kk) * 1024 + j];
    #pragma unroll
    for (int b = 0; b < 32; ++b) acc[b] = fmaf(sh[b][kk], w, acc[b]);
  }
  #pragma unroll
  for (int b = 0; b < 32; ++b) part[((long)(kc * 32 + b)) * 1024 + j] = acc[b];
}

__global__ void lin1_reduce_k(const float* __restrict__ part, const float* __restrict__ b1,
                              float* __restrict__ y1) {
  int i = blockIdx.x * TPB + threadIdx.x;
  if (i >= 32 * 1024) return;
  int b = i >> 10, j = i & 1023;
  float a = b1[j];
  for (int kc = 0; kc < KS; ++kc) a += part[(long)kc * 32768 + b * 1024 + j];
  y1[i] = fmaxf(a, 0.f);
}

#define JS2 8
__global__ void lin2_part_k(const float* __restrict__ y1, const float* __restrict__ W2,
                            float* __restrict__ part2) {
  int i = blockIdx.x * TPB + threadIdx.x;
  if (i >= 32 * 420) return;
  int b = i / 420, o = i - b * 420;
  int j0 = blockIdx.y * 128;
  float a = 0.f;
  const float* yp = y1 + b * 1024 + j0;
  const float* wp = W2 + (long)j0 * 420 + o;
  #pragma unroll 8
  for (int j = 0; j < 128; ++j) a = fmaf(yp[j], wp[(long)j * 420], a);
  part2[(long)blockIdx.y * 13440 + i] = a;
}

__global__ void lin2_fin_k(const float* __restrict__ part2, const float* __restrict__ b2,
                           float* __restrict__ out) {
  int i = blockIdx.x * TPB + threadIdx.x;
  if (i >= 32 * 420) return;
  int o = i % 420;
  float a = b2[o];
  #pragma unroll
  for (int js = 0; js < JS2; ++js) a += part2[(long)js * 13440 + i];
  out[i] = a;
}

extern "C" void kernel_launch(void* const* d_in, const int* in_sizes, int n_in,
                              void* d_out, int out_size, void* d_ws, size_t ws_size,
                              hipStream_t stream) {
  const float* x = (const float*)d_in[0];
  const float* ca[5] = {(const float*)d_in[2], (const float*)d_in[6], (const float*)d_in[10],
                        (const float*)d_in[14], (const float*)d_in[18]};
  const float* bg[5] = {(const float*)d_in[3], (const float*)d_in[7], (const float*)d_in[11],
                        (const float*)d_in[15], (const float*)d_in[19]};
  const float* bb[5] = {(const float*)d_in[4], (const float*)d_in[8], (const float*)d_in[12],
                        (const float*)d_in[16], (const float*)d_in[20]};
  const float* cb[5] = {(const float*)d_in[5], (const float*)d_in[9], (const float*)d_in[13],
                        (const float*)d_in[17], (const float*)d_in[21]};
  const float* g1Wg = (const float*)d_in[22];
  const float* g1Wc = (const float*)d_in[23];
  const float* g2Wg = (const float*)d_in[24];
  const float* g2Wc = (const float*)d_in[25];
  const float* W1 = (const float*)d_in[26];
  const float* b1 = (const float*)d_in[27];
  const float* W2 = (const float*)d_in[28];
  const float* b2 = (const float*)d_in[29];

  const int Hs[6] = {191, 95, 47, 23, 11, 5};
  const int Wd[6] = {255, 127, 63, 31, 15, 7};
  const long NS[6] = {1558560, 386080, 94752, 22816, 5280, 1120};
  const int cap[6] = {400000, 386080, 94752, 22816, 5280, 1120};

  float* ws = (float*)d_ws;
  const long BUF = 12354560;
  long off = 0;
  float* bufA = ws + off; off += BUF;
  float* bufB = ws + off; off += BUF;
  float* yg = ws + off;   off += 286720;
  float* yc = ws + off;   off += 286720;
  float* stats = ws + off; off += 512;
  float* bnsc = ws + off;  off += 512;
  float* y1 = ws + off;    off += 32L * 1024;

  half_t* hbase = (half_t*)(ws + off);
  long hoff = 0;
  half_t* hbufA = hbase + hoff; hoff += 6500000;
  half_t* hbufB = hbase + hoff; hoff += 6500000;
  half_t* xh = hbase + hoff;    hoff += 3117120;
  half_t* wp_ca0 = hbase + hoff; hoff += 16L * 32;     // CI=2 KP=32
  half_t* wp_cb0 = hbase + hoff; hoff += 16L * 160;    // CI=16 KP=160
  half_t* wp_ca1 = hbase + hoff; hoff += 32L * 160;    // CI=16 KP=160
  half_t* wp_cb1 = hbase + hoff; hoff += 32L * 288;    // CI=32 KP=288
  half_t* wt_ca2 = hbase + hoff; hoff += 9L * 64 * 32;
  half_t* wt_cb2 = hbase + hoff; hoff += 9L * 64 * 64;
  half_t* wt_ca3 = hbase + hoff; hoff += 9L * 128 * 64;
  half_t* wt_cb3 = hbase + hoff; hoff += 9L * 128 * 128;
  half_t* wt_ca4 = hbase + hoff; hoff += 9L * 256 * 128;
  half_t* wt_cb4 = hbase + hoff; hoff += 9L * 256 * 256;
  half_t* wt_g1g = hbase + hoff; hoff += 9L * 256 * 256;
  half_t* wt_g1c = hbase + hoff; hoff += 9L * 256 * 256;
  half_t* wt_g2g = hbase + hoff; hoff += 9L * 256 * 256;
  half_t* wt_g2c = hbase + hoff; hoff += 9L * 256 * 256;

  int* ip = (int*)(hbase + hoff);
  long ioff = 0;
  int* cnt = ip + ioff; ioff += 16;
  int* bcnt = ip + ioff; ioff += 8192;
  int* list[6]; int* inv[6];
  for (int l = 0; l < 6; ++l) { list[l] = ip + ioff; ioff += cap[l]; }
  for (int l = 0; l < 6; ++l) { inv[l] = ip + ioff; ioff += NS[l]; }
  size_t needed = (size_t)off * 4 + (size_t)hoff * 2 + (size_t)ioff * 4;
  if (ws_size < needed) return;

  float* h1d = (float*)d_out + 13440;
  float* h2d = h1d + 286720;

  // ---- weight packing ----
  wtrp_k<<<nblk(16L * 32), TPB, 0, stream>>>(ca[0], wp_ca0, 2, 16, 32, 2, 16);
  wtrp_k<<<nblk(16L * 160), TPB, 0, stream>>>(cb[0], wp_cb0, 16, 16, 160, 16, 16);
  wtrp_k<<<nblk(32L * 160), TPB, 0, stream>>>(ca[1], wp_ca1, 16, 32, 160, 16, 32);
  wtrp_k<<<nblk(32L * 288), TPB, 0, stream>>>(cb[1], wp_cb1, 32, 32, 288, 32, 32);
  wtr_k<<<nblk(9L * 64 * 32), TPB, 0, stream>>>(ca[2], wt_ca2, 32, 64, 32, 64);
  wtr_k<<<nblk(9L * 64 * 64), TPB, 0, stream>>>(cb[2], wt_cb2, 64, 64, 64, 64);
  wtr_k<<<nblk(9L * 128 * 64), TPB, 0, stream>>>(ca[3], wt_ca3, 64, 128, 64, 128);
  wtr_k<<<nblk(9L * 128 * 128), TPB, 0, stream>>>(cb[3], wt_cb3, 128, 128, 128, 128);
  wtr_k<<<nblk(9L * 256 * 128), TPB, 0, stream>>>(ca[4], wt_ca4, 128, 256, 128, 256);
  wtr_k<<<gmin(nblk(9L * 256 * 256), 2048), TPB, 0, stream>>>(cb[4], wt_cb4, 256, 256, 256, 256);
  wtr_k<<<gmin(nblk(9L * 256 * 256), 2048), TPB, 0, stream>>>(g1Wg, wt_g1g, 256, 256, 512, 512);
  wtr_k<<<gmin(nblk(9L * 256 * 256), 2048), TPB, 0, stream>>>(g1Wc, wt_g1c, 256, 256, 512, 256);
  wtr_k<<<gmin(nblk(9L * 256 * 256), 2048), TPB, 0, stream>>>(g2Wg, wt_g2g, 256, 256, 512, 512);
  wtr_k<<<gmin(nblk(9L * 256 * 256), 2048), TPB, 0, stream>>>(g2Wc, wt_g2c, 256, 256, 512, 256);
  cvt_x_k<<<4096, TPB, 0, stream>>>(x, xh, 3117120);

  // ---- level-0 compaction ----
  {
    int nb = nblk(NS[0]);
    cmpA0_k<<<nb, TPB, 0, stream>>>(x, (int)NS[0], bcnt);
    scan_k<<<1, 1024, 0, stream>>>(bcnt, nb, cnt + 0);
    cmpB0_k<<<nb, TPB, 0, stream>>>(x, (int)NS[0], bcnt, list[0], inv[0], cap[0]);
  }

  // ---------- level 1 (MFMA, K-packed) ----------
  hipMemsetAsync(stats, 0, 512 * 4, stream);
  mconvp_k<2, 16, true><<<(cap[0] + 63) / 64, TPB, 0, stream>>>(
      xh, wp_ca0, bufA, nullptr, list[0], cnt + 0, Hs[0], Wd[0]);
  bn_stats2_k<16><<<1024, TPB, 0, stream>>>(bufA, cnt + 0, stats);
  bn_fin_k<<<1, 256, 0, stream>>>(stats, cnt + 0, bg[0], bb[0], bnsc, 16);
  bnapply_f16_k<16><<<2048, TPB, 0, stream>>>(bufA, cnt + 0, bnsc, hbufA);
  mconvp_k<16, 16, false><<<(cap[0] + 63) / 64, TPB, 0, stream>>>(
      hbufA, wp_cb0, bufB, inv[0], list[0], cnt + 0, Hs[0], Wd[0]);
  {
    int nb = nblk(NS[1]);
    poolA_k<<<nb, TPB, 0, stream>>>(inv[0], Hs[0], Wd[0], Hs[1], Wd[1], (int)NS[1], bcnt);
    scan_k<<<1, 1024, 0, stream>>>(bcnt, nb, cnt + 1);
    poolB_k<<<nb, TPB, 0, stream>>>(inv[0], Hs[0], Wd[0], Hs[1], Wd[1], (int)NS[1], bcnt,
                                    list[1], inv[1], cap[1]);
  }
  pool_val_f16_k<16><<<2048, TPB, 0, stream>>>(bufB, inv[0], list[1], cnt + 1, Hs[0], Wd[0], Hs[1], Wd[1], hbufB);

  // ---------- level 2 (MFMA, K-packed) ----------
  hipMemsetAsync(stats, 0, 512 * 4, stream);
  mconvp_k<16, 32, false><<<(cap[1] + 63) / 64, TPB, 0, stream>>>(
      hbufB, wp_ca1, bufB, inv[1], list[1], cnt + 1, Hs[1], Wd[1]);
  bn_stats2_k<32><<<1024, TPB, 0, stream>>>(bufB, cnt + 1, stats);
  bn_fin_k<<<1, 256, 0, stream>>>(stats, cnt + 1, bg[1], bb[1], bnsc, 32);
  bnapply_f16_k<32><<<2048, TPB, 0, stream>>>(bufB, cnt + 1, bnsc, hbufA);
  mconvp_k<32, 32, false><<<(cap[1] + 63) / 64, TPB, 0, stream>>>(
      hbufA, wp_cb1, bufA, inv[1], list[1], cnt + 1, Hs[1], Wd[1]);
  {
    int nb = nblk(NS[2]);
    poolA_k<<<nb, TPB, 0, stream>>>(inv[1], Hs[1], Wd[1], Hs[2], Wd[2], (int)NS[2], bcnt);
    scan_k<<<1, 1024, 0, stream>>>(bcnt, nb, cnt + 2);
    poolB_k<<<nb, TPB, 0, stream>>>(inv[1], Hs[1], Wd[1], Hs[2], Wd[2], (int)NS[2], bcnt,
                                    list[2], inv[2], cap[2]);
  }
  pool_val_f16_k<32><<<2048, TPB, 0, stream>>>(bufA, inv[1], list[2], cnt + 2, Hs[1], Wd[1], Hs[2], Wd[2], hbufB);

  // ---------- level 3 (MFMA) ----------
  hipMemsetAsync(stats, 0, 512 * 4, stream);
  mconv_k<32, 64><<<dim3((cap[2] + 63) / 64, 1), TPB, 0, stream>>>(
      hbufB, wt_ca2, bufA, inv[2], list[2], cnt + 2, Hs[2], Wd[2]);
  bn_stats2_k<64><<<1024, TPB, 0, stream>>>(bufA, cnt + 2, stats);
  bn_fin_k<<<1, 256, 0, stream>>>(stats, cnt + 2, bg[2], bb[2], bnsc, 64);
  bnapply_f16_k<64><<<2048, TPB, 0, stream>>>(bufA, cnt + 2, bnsc, hbufA);
  mconv_k<64, 64><<<dim3((cap[2] + 63) / 64, 1), TPB, 0, stream>>>(
      hbufA, wt_cb2, bufB, inv[2], list[2], cnt + 2, Hs[2], Wd[2]);
  {
    int nb = nblk(NS[3]);
    poolA_k<<<nb, TPB, 0, stream>>>(inv[2], Hs[2], Wd[2], Hs[3], Wd[3], (int)NS[3], bcnt);
    scan_k<<<1, 1024, 0, stream>>>(bcnt, nb, cnt + 3);
    poolB_k<<<nb, TPB, 0, stream>>>(inv[2], Hs[2], Wd[2], Hs[3], Wd[3], (int)NS[3], bcnt,
                                    list[3], inv[3], cap[3]);
  }
  pool_val_f16_k<64><<<2048, TPB, 0, stream>>>(bufB, inv[2], list[3], cnt + 3, Hs[2], Wd[2], Hs[3], Wd[3], hbufB);

  // ---------- level 4 (MFMA) ----------
  hipMemsetAsync(stats, 0, 512 * 4, stream);
  mconv_k<64, 128><<<dim3((cap[3] + 63) / 64, 2), TPB, 0, stream>>>(
      hbufB, wt_ca3, bufA, inv[3], list[3], cnt + 3, Hs[3], Wd[3]);
  bn_stats2_k<128><<<1024, TPB, 0, stream>>>(bufA, cnt + 3, stats);
  bn_fin_k<<<1, 256, 0, stream>>>(stats, cnt + 3, bg[3], bb[3], bnsc, 128);
  bnapply_f16_k<128><<<2048, TPB, 0, stream>>>(bufA, cnt + 3, bnsc, hbufA);
  mconv_k<128, 128><<<dim3((cap[3] + 63) / 64, 2), TPB, 0, stream>>>(
      hbufA, wt_cb3, bufB, inv[3], list[3], cnt + 3, Hs[3], Wd[3]);
  {
    int nb = nblk(NS[4]);
    poolA_k<<<nb, TPB, 0, stream>>>(inv[3], Hs[3], Wd[3], Hs[4], Wd[4], (int)NS[4], bcnt);
    scan_k<<<1, 1024, 0, stream>>>(bcnt, nb, cnt + 4);
    poolB_k<<<nb, TPB, 0, stream>>>(inv[3], Hs[3], Wd[3], Hs[4], Wd[4], (int)NS[4], bcnt,
                                    list[4], inv[4], cap[4]);
  }
  pool_val_f16_k<128><<<2048, TPB, 0, stream>>>(bufB, inv[3], list[4], cnt + 4, Hs[3], Wd[3], Hs[4], Wd[4], hbufB);

  // ---------- level 5 (MFMA, 16-site tiles) ----------
  hipMemsetAsync(stats, 0, 512 * 4, stream);
  mconv_sm_k<128, 256><<<dim3((cap[4] + 15) / 16, 4), TPB, 0, stream>>>(
      hbufB, wt_ca4, bufA, inv[4], list[4], cnt + 4, Hs[4], Wd[4]);
  bn_stats2_k<256><<<1024, TPB, 0, stream>>>(bufA, cnt + 4, stats);
  bn_fin_k<<<1, 256, 0, stream>>>(stats, cnt + 4, bg[4], bb[4], bnsc, 256);
  bnapply_f16_k<256><<<2048, TPB, 0, stream>>>(bufA, cnt + 4, bnsc, hbufA);
  mconv_sm_k<256, 256><<<dim3((cap[4] + 15) / 16, 4), TPB, 0, stream>>>(
      hbufA, wt_cb4, bufB, inv[4], list[4], cnt + 4, Hs[4], Wd[4]);
  {
    int nb = nblk(NS[5]);
    poolA_k<<<nb, TPB, 0, stream>>>(inv[4], Hs[4], Wd[4], Hs[5], Wd[5], (int)NS[5], bcnt);
    scan_k<<<1, 1024, 0, stream>>>(bcnt, nb, cnt + 5);
    poolB_k<<<nb, TPB, 0, stream>>>(inv[4], Hs[4], Wd[4], Hs[5], Wd[5], (int)NS[5], bcnt,
                                    list[5], inv[5], cap[5]);
  }
  pool_val_f16_k<256><<<1024, TPB, 0, stream>>>(bufB, inv[4], list[5], cnt + 5, Hs[4], Wd[4], Hs[5], Wd[5], hbufB);

  // ---------- GRUs (MFMA, 16-site tiles) ----------
  long ngb = 286720L * 4;
  hipMemsetAsync(h1d, 0, ngb, stream);
  hipMemsetAsync(h2d, 0, ngb, stream);
  mconv_sm_k<256, 256><<<dim3((cap[5] + 15) / 16, 4), TPB, 0, stream>>>(
      hbufB, wt_g1g, yg, inv[5], list[5], cnt + 5, Hs[5], Wd[5]);
  mconv_sm_k<256, 256><<<dim3((cap[5] + 15) / 16, 4), TPB, 0, stream>>>(
      hbufB, wt_g1c, yc, inv[5], list[5], cnt + 5, Hs[5], Wd[5]);
  gru_pw2_k<<<512, TPB, 0, stream>>>(yg, yc, list[5], cnt + 5, h1d, hbufA);
  mconv_sm_k<256, 256><<<dim3((cap[5] + 15) / 16, 4), TPB, 0, stream>>>(
      hbufA, wt_g2g, yg, inv[5], list[5], cnt + 5, Hs[5], Wd[5]);
  mconv_sm_k<256, 256><<<dim3((cap[5] + 15) / 16, 4), TPB, 0, stream>>>(
      hbufA, wt_g2c, yc, inv[5], list[5], cnt + 5, Hs[5], Wd[5]);
  gru_pw2_k<<<512, TPB, 0, stream>>>(yg, yc, list[5], cnt + 5, h2d, nullptr);

  // ---------- head ----------
  float* part = bufA;
  float* part2 = bufB;
  lin1_part2_k<<<dim3(KS, 4), TPB, 0, stream>>>(h2d, W1, part);
  lin1_reduce_k<<<nblk(32L * 1024), TPB, 0, stream>>>(part, b1, y1);
  lin2_part_k<<<dim3(nblk(32L * 420), JS2), TPB, 0, stream>>>(y1, W2, part2);
  lin2_fin_k<<<nblk(32L * 420), TPB, 0, stream>>>(part2, b2, (float*)d_out);
}

// Round 7
// 926.036 us; speedup vs baseline: 6.9178x; 1.1038x over previous
//
#include <hip/hip_runtime.h>
#include <stdint.h>

#define TPB 256

typedef _Float16 half_t;
typedef __attribute__((ext_vector_type(8))) _Float16 f16x8;
typedef __attribute__((ext_vector_type(4))) float f32x4;

static inline int nblk(long n) { return (int)((n + TPB - 1) / TPB); }
static inline int gmin(long a, long b) { return (int)(a < b ? a : b); }

// ---------- scan-based compaction ----------
__device__ __forceinline__ bool act0(const float* x, int i) {
  float2 v = *(const float2*)(x + 2L * i);
  return (v.x != 0.f) || (v.y != 0.f);
}

__global__ void cmpA0_k(const float* __restrict__ x, int n, int* __restrict__ bcnt) {
  int i = blockIdx.x * TPB + threadIdx.x;
  bool a = (i < n) && act0(x, i);
  unsigned long long bal = __ballot(a);
  __shared__ int wc[4];
  if ((threadIdx.x & 63) == 0) wc[threadIdx.x >> 6] = __popcll(bal);
  __syncthreads();
  if (threadIdx.x == 0) bcnt[blockIdx.x] = wc[0] + wc[1] + wc[2] + wc[3];
}

__global__ void cmpB0_k(const float* __restrict__ x, int n, const int* __restrict__ bbase,
                        int* __restrict__ list, int* __restrict__ inv, int cap) {
  int i = blockIdx.x * TPB + threadIdx.x;
  bool a = (i < n) && act0(x, i);
  unsigned long long bal = __ballot(a);
  __shared__ int wc[4];
  int wid = threadIdx.x >> 6, lane = threadIdx.x & 63;
  if (lane == 0) wc[wid] = __popcll(bal);
  __syncthreads();
  int base = bbase[blockIdx.x];
  for (int w = 0; w < wid; ++w) base += wc[w];
  if (i < n) {
    int pos = base + __popcll(bal & ((1ull << lane) - 1));
    if (a && pos < cap) { list[pos] = i; inv[i] = pos; }
    else inv[i] = -1;
  }
}

__device__ __forceinline__ bool actp(const int* invp, int Hp, int Wp, int Ho, int Wo, int i) {
  int wo = i % Wo; int t = i / Wo; int ho = t % Ho; int bb = t / Ho;
  long rb = ((long)bb * Hp + 2 * ho) * Wp + 2 * wo;
  bool a = false;
  #pragma unroll
  for (int kh = 0; kh < 3; ++kh)
    #pragma unroll
    for (int kw = 0; kw < 3; ++kw)
      a |= (invp[rb + kh * Wp + kw] >= 0);
  return a;
}

__global__ void poolA_k(const int* __restrict__ invp, int Hp, int Wp, int Ho, int Wo,
                        int n, int* __restrict__ bcnt) {
  int i = blockIdx.x * TPB + threadIdx.x;
  bool a = (i < n) && actp(invp, Hp, Wp, Ho, Wo, i);
  unsigned long long bal = __ballot(a);
  __shared__ int wc[4];
  if ((threadIdx.x & 63) == 0) wc[threadIdx.x >> 6] = __popcll(bal);
  __syncthreads();
  if (threadIdx.x == 0) bcnt[blockIdx.x] = wc[0] + wc[1] + wc[2] + wc[3];
}

__global__ void poolB_k(const int* __restrict__ invp, int Hp, int Wp, int Ho, int Wo, int n,
                        const int* __restrict__ bbase, int* __restrict__ list,
                        int* __restrict__ inv, int cap) {
  int i = blockIdx.x * TPB + threadIdx.x;
  bool a = (i < n) && actp(invp, Hp, Wp, Ho, Wo, i);
  unsigned long long bal = __ballot(a);
  __shared__ int wc[4];
  int wid = threadIdx.x >> 6, lane = threadIdx.x & 63;
  if (lane == 0) wc[wid] = __popcll(bal);
  __syncthreads();
  int base = bbase[blockIdx.x];
  for (int w = 0; w < wid; ++w) base += wc[w];
  if (i < n) {
    int pos = base + __popcll(bal & ((1ull << lane) - 1));
    if (a && pos < cap) { list[pos] = i; inv[i] = pos; }
    else inv[i] = -1;
  }
}

__global__ void scan_k(int* __restrict__ b, int n, int* __restrict__ total) {
  __shared__ int sh[1024];
  __shared__ int sc;
  if (threadIdx.x == 0) sc = 0;
  __syncthreads();
  for (int base = 0; base < n; base += 1024) {
    int i = base + threadIdx.x;
    int v = (i < n) ? b[i] : 0;
    sh[threadIdx.x] = v;
    __syncthreads();
    for (int o = 1; o < 1024; o <<= 1) {
      int t = (threadIdx.x >= o) ? sh[threadIdx.x - o] : 0;
      __syncthreads();
      sh[threadIdx.x] += t;
      __syncthreads();
    }
    if (i < n) b[i] = sh[threadIdx.x] - v + sc;
    __syncthreads();
    if (threadIdx.x == 0) sc += sh[1023];
    __syncthreads();
  }
  if (threadIdx.x == 0) *total = sc;
}

// ---------- pooled values -> f16 compact rows ----------
template <int C>
__global__ void pool_val_f16_k(const float* __restrict__ xin, const int* __restrict__ invp,
                               const int* __restrict__ list, const int* __restrict__ cnt,
                               int Hp, int Wp, int Ho, int Wo, half_t* __restrict__ y) {
  long total = (long)cnt[0] * C;
  for (long i = (long)blockIdx.x * TPB + threadIdx.x; i < total; i += (long)gridDim.x * TPB) {
    int c = (int)(i & (C - 1));
    int r = (int)(i / C);
    int site = list[r];
    int wo = site % Wo; int t = site / Wo; int ho = t % Ho; int bb = t / Ho;
    long rb = ((long)bb * Hp + 2 * ho) * Wp + 2 * wo;
    float best = -1e30f;
    #pragma unroll
    for (int kh = 0; kh < 3; ++kh)
      #pragma unroll
      for (int kw = 0; kw < 3; ++kw) {
        int j = invp[rb + kh * Wp + kw];
        if (j >= 0) best = fmaxf(best, xin[(long)j * C + c]);
      }
    y[i] = (half_t)best;
  }
}

// ---------- dense x -> f16 ----------
__global__ void cvt_x_k(const float* __restrict__ x, half_t* __restrict__ xh, long n) {
  for (long i = (long)blockIdx.x * TPB + threadIdx.x; i < n; i += (long)gridDim.x * TPB)
    xh[i] = (half_t)x[i];
}

// ---------- weight pack: W[tap][ci][co] f32 -> per-tap [tap][co][ci] f16 ----------
__global__ void wtr_k(const float* __restrict__ Wsrc, half_t* __restrict__ dst,
                      int CI, int CO, int wci, int wco) {
  long total = 9L * CO * CI;
  for (long i = (long)blockIdx.x * TPB + threadIdx.x; i < total; i += (long)gridDim.x * TPB) {
    int ci = (int)(i % CI);
    long t = i / CI;
    int co = (int)(t % CO);
    int tap = (int)(t / CO);
    dst[i] = (half_t)Wsrc[((long)tap * wci + ci) * wco + co];
  }
}

// ---------- weight pack: K-packed [co][KP] f16 ----------
__global__ void wtrp_k(const float* __restrict__ Wsrc, half_t* __restrict__ dst,
                       int CI, int CO, int KP, int wci, int wco) {
  long total = (long)CO * KP;
  for (long i = (long)blockIdx.x * TPB + threadIdx.x; i < total; i += (long)gridDim.x * TPB) {
    int k = (int)(i % KP);
    int co = (int)(i / KP);
    int tap = k / CI, ci = k - tap * CI;
    float v = (tap < 9) ? Wsrc[((long)tap * wci + ci) * wco + co] : 0.f;
    dst[i] = (half_t)v;
  }
}

// ---------- K-packed MFMA conv (CO<=32); 64 sites/block ----------
template <int CI, int CO, bool DENSE>
__global__ __launch_bounds__(256) void mconvp_k(const half_t* __restrict__ X,
                                                const half_t* __restrict__ Wt,
                                                float* __restrict__ y,
                                                const int* __restrict__ inv,
                                                const int* __restrict__ list,
                                                const int* __restrict__ cnt,
                                                int H, int W) {
  constexpr int KP = ((9 * CI + 31) / 32) * 32;
  constexpr int NCO = CO / 16;
  const int nact = cnt[0];
  const int base = blockIdx.x * 64;
  if (base >= nact) return;
  __shared__ int nbr[64 * 9];
  for (int i = threadIdx.x; i < 64 * 9; i += TPB) {
    int s = i / 9, nb = i - s * 9;
    int j = -1;
    if (base + s < nact) {
      int site = list[base + s];
      int w = site % W; int t = site / W; int h = t % H; int bb = t / H;
      int hh = h + nb / 3 - 1, ww = w + nb % 3 - 1;
      if ((unsigned)hh < (unsigned)H && (unsigned)ww < (unsigned)W) {
        int ss = (bb * H + hh) * W + ww;
        j = DENSE ? ss : inv[ss];
      }
    }
    nbr[i] = j;
  }
  __syncthreads();
  const int lane = threadIdx.x & 63, wv = threadIdx.x >> 6;
  const int srow = lane & 15, kseg = lane >> 4;
  const int sloc = wv * 16 + srow;
  f32x4 acc[NCO];
  #pragma unroll
  for (int c = 0; c < NCO; ++c) acc[c] = (f32x4){0.f, 0.f, 0.f, 0.f};
  #pragma unroll
  for (int k0 = 0; k0 < KP; k0 += 32) {
    const int k = k0 + kseg * 8;
    f16x8 av;
    #pragma unroll
    for (int z = 0; z < 8; ++z) av[z] = (_Float16)0.f;
    if (CI >= 8) {
      int tap = k / CI;
      int ci = k - tap * CI;
      if (tap < 9) {
        int j = nbr[sloc * 9 + tap];
        if (j >= 0) av = *(const f16x8*)(X + (long)j * CI + ci);
      }
    } else {  // CI == 2
      #pragma unroll
      for (int q = 0; q < 4; ++q) {
        int kk = k + 2 * q;
        int tap = kk >> 1;
        if (tap < 9) {
          int j = nbr[sloc * 9 + tap];
          if (j >= 0) {
            const half_t* xp = X + (long)j * 2;
            av[2 * q] = xp[0];
            av[2 * q + 1] = xp[1];
          }
        }
      }
    }
    #pragma unroll
    for (int c = 0; c < NCO; ++c) {
      f16x8 bv = *(const f16x8*)(Wt + (long)(c * 16 + srow) * KP + k);
      acc[c] = __builtin_amdgcn_mfma_f32_16x16x32_f16(av, bv, acc[c], 0, 0, 0);
    }
  }
  #pragma unroll
  for (int c = 0; c < NCO; ++c)
    #pragma unroll
    for (int r = 0; r < 4; ++r) {
      int ss = base + wv * 16 + kseg * 4 + r;
      if (ss < nact) y[(long)ss * CO + c * 16 + srow] = acc[c][r];
    }
}

// ---------- per-tap MFMA conv, 64 sites x 64 co per block (mid levels) ----------
template <int CI, int CO>
__global__ __launch_bounds__(256) void mconv_k(const half_t* __restrict__ X,
                                               const half_t* __restrict__ Wt,
                                               float* __restrict__ y,
                                               const int* __restrict__ inv,
                                               const int* __restrict__ list,
                                               const int* __restrict__ cnt,
                                               int H, int W) {
  const int nact = cnt[0];
  const int base = blockIdx.x * 64;
  if (base >= nact) return;
  const int lane = threadIdx.x & 63;
  const int wv = threadIdx.x >> 6;
  const int srow = lane & 15;
  const int kseg = lane >> 4;
  const int co0 = blockIdx.y * 64;
  const int s = base + wv * 16 + srow;
  int h = 0, w = 0, bb = 0;
  const bool sv = (s < nact);
  if (sv) {
    int site = list[s];
    w = site % W;
    int t = site / W;
    h = t % H;
    bb = t / H;
  }
  f32x4 acc0 = {0.f, 0.f, 0.f, 0.f};
  f32x4 acc1 = acc0, acc2 = acc0, acc3 = acc0;
  for (int tap = 0; tap < 9; ++tap) {
    int j = -1;
    if (sv) {
      int hh = h + tap / 3 - 1, ww = w + tap % 3 - 1;
      if ((unsigned)hh < (unsigned)H && (unsigned)ww < (unsigned)W)
        j = inv[(bb * H + hh) * W + ww];
    }
    const half_t* xp = X + (long)j * CI + kseg * 8;
    const half_t* wp = Wt + ((long)tap * CO + co0 + srow) * CI + kseg * 8;
    #pragma unroll
    for (int k0 = 0; k0 < CI; k0 += 32) {
      f16x8 av;
      #pragma unroll
      for (int z = 0; z < 8; ++z) av[z] = (_Float16)0.f;
      if (j >= 0) av = *(const f16x8*)(xp + k0);
      f16x8 b0 = *(const f16x8*)(wp + k0);
      f16x8 b1 = *(const f16x8*)(wp + 16 * CI + k0);
      f16x8 b2 = *(const f16x8*)(wp + 32 * CI + k0);
      f16x8 b3 = *(const f16x8*)(wp + 48 * CI + k0);
      acc0 = __builtin_amdgcn_mfma_f32_16x16x32_f16(av, b0, acc0, 0, 0, 0);
      acc1 = __builtin_amdgcn_mfma_f32_16x16x32_f16(av, b1, acc1, 0, 0, 0);
      acc2 = __builtin_amdgcn_mfma_f32_16x16x32_f16(av, b2, acc2, 0, 0, 0);
      acc3 = __builtin_amdgcn_mfma_f32_16x16x32_f16(av, b3, acc3, 0, 0, 0);
    }
  }
  #pragma unroll
  for (int r = 0; r < 4; ++r) {
    int ss = base + wv * 16 + kseg * 4 + r;
    if (ss < nact) {
      float* yp = y + (long)ss * CO + co0 + srow;
      yp[0] = acc0[r];
      yp[16] = acc1[r];
      yp[32] = acc2[r];
      yp[48] = acc3[r];
    }
  }
}

// ---------- K-split deep conv: 16 sites x 64 co per block, 4 waves split taps ----------
template <int CI, int CO>
__global__ __launch_bounds__(256) void mconv_ks_k(const half_t* __restrict__ X,
                                                  const half_t* __restrict__ Wt,
                                                  float* __restrict__ y,
                                                  const int* __restrict__ inv,
                                                  const int* __restrict__ list,
                                                  const int* __restrict__ cnt,
                                                  int H, int W) {
  const int nact = cnt[0];
  const int base = blockIdx.x * 16;
  if (base >= nact) return;
  __shared__ int nbr[16 * 9];
  __shared__ float red[4][16][65];
  for (int i = threadIdx.x; i < 16 * 9; i += TPB) {
    int s = i / 9, nb = i - s * 9;
    int j = -1;
    if (base + s < nact) {
      int site = list[base + s];
      int w = site % W; int t = site / W; int h = t % H; int bb = t / H;
      int hh = h + nb / 3 - 1, ww = w + nb % 3 - 1;
      if ((unsigned)hh < (unsigned)H && (unsigned)ww < (unsigned)W)
        j = inv[(bb * H + hh) * W + ww];
    }
    nbr[i] = j;
  }
  __syncthreads();
  const int lane = threadIdx.x & 63, wv = threadIdx.x >> 6;
  const int srow = lane & 15, kseg = lane >> 4;
  const int co0 = blockIdx.y * 64;
  const int t0 = (wv * 9) / 4, t1 = ((wv + 1) * 9) / 4;
  f32x4 acc0 = {0.f, 0.f, 0.f, 0.f};
  f32x4 acc1 = acc0, acc2 = acc0, acc3 = acc0;
  for (int tap = t0; tap < t1; ++tap) {
    int j = nbr[srow * 9 + tap];
    const half_t* xp = X + (long)j * CI + kseg * 8;
    const half_t* wp = Wt + ((long)tap * CO + co0 + srow) * CI + kseg * 8;
    #pragma unroll
    for (int k0 = 0; k0 < CI; k0 += 32) {
      f16x8 av;
      #pragma unroll
      for (int z = 0; z < 8; ++z) av[z] = (_Float16)0.f;
      if (j >= 0) av = *(const f16x8*)(xp + k0);
      f16x8 b0 = *(const f16x8*)(wp + k0);
      f16x8 b1 = *(const f16x8*)(wp + 16 * CI + k0);
      f16x8 b2 = *(const f16x8*)(wp + 32 * CI + k0);
      f16x8 b3 = *(const f16x8*)(wp + 48 * CI + k0);
      acc0 = __builtin_amdgcn_mfma_f32_16x16x32_f16(av, b0, acc0, 0, 0, 0);
      acc1 = __builtin_amdgcn_mfma_f32_16x16x32_f16(av, b1, acc1, 0, 0, 0);
      acc2 = __builtin_amdgcn_mfma_f32_16x16x32_f16(av, b2, acc2, 0, 0, 0);
      acc3 = __builtin_amdgcn_mfma_f32_16x16x32_f16(av, b3, acc3, 0, 0, 0);
    }
  }
  #pragma unroll
  for (int r = 0; r < 4; ++r) {
    int s = kseg * 4 + r;
    red[wv][s][srow] = acc0[r];
    red[wv][s][16 + srow] = acc1[r];
    red[wv][s][32 + srow] = acc2[r];
    red[wv][s][48 + srow] = acc3[r];
  }
  __syncthreads();
  for (int i = threadIdx.x; i < 16 * 64; i += TPB) {
    int s = i >> 6, co = i & 63;
    float v = red[0][s][co] + red[1][s][co] + red[2][s][co] + red[3][s][co];
    int ss = base + s;
    if (ss < nact) y[(long)ss * CO + co0 + co] = v;
  }
}

// ---------- fused GRU conv: g=conv(X,Wg), c=conv(X,Wc), h=sigmoid(g)*tanh(c) ----------
// block: 16 sites x 64 co, 4 waves split taps; writes dense f32 + compact f16.
template <int CI>
__global__ __launch_bounds__(256) void gruconv_k(const half_t* __restrict__ X,
                                                 const half_t* __restrict__ Wg,
                                                 const half_t* __restrict__ Wc,
                                                 float* __restrict__ hdense,
                                                 half_t* __restrict__ hcomp,
                                                 const int* __restrict__ inv,
                                                 const int* __restrict__ list,
                                                 const int* __restrict__ cnt,
                                                 int H, int W) {
  constexpr int CO = 256;
  const int nact = cnt[0];
  const int base = blockIdx.x * 16;
  if (base >= nact) return;
  __shared__ int nbr[16 * 9];
  __shared__ float red[4][16][65];
  for (int i = threadIdx.x; i < 16 * 9; i += TPB) {
    int s = i / 9, nb = i - s * 9;
    int j = -1;
    if (base + s < nact) {
      int site = list[base + s];
      int w = site % W; int t = site / W; int h = t % H; int bb = t / H;
      int hh = h + nb / 3 - 1, ww = w + nb % 3 - 1;
      if ((unsigned)hh < (unsigned)H && (unsigned)ww < (unsigned)W)
        j = inv[(bb * H + hh) * W + ww];
    }
    nbr[i] = j;
  }
  __syncthreads();
  const int lane = threadIdx.x & 63, wv = threadIdx.x >> 6;
  const int srow = lane & 15, kseg = lane >> 4;
  const int co0 = blockIdx.y * 64;
  const int t0 = (wv * 9) / 4, t1 = ((wv + 1) * 9) / 4;
  f32x4 g0 = {0.f, 0.f, 0.f, 0.f};
  f32x4 g1 = g0, g2 = g0, g3 = g0, c0 = g0, c1 = g0, c2 = g0, c3 = g0;
  for (int tap = t0; tap < t1; ++tap) {
    int j = nbr[srow * 9 + tap];
    const half_t* xp = X + (long)j * CI + kseg * 8;
    const half_t* wgp = Wg + ((long)tap * CO + co0 + srow) * CI + kseg * 8;
    const half_t* wcp = Wc + ((long)tap * CO + co0 + srow) * CI + kseg * 8;
    #pragma unroll
    for (int k0 = 0; k0 < CI; k0 += 32) {
      f16x8 av;
      #pragma unroll
      for (int z = 0; z < 8; ++z) av[z] = (_Float16)0.f;
      if (j >= 0) av = *(const f16x8*)(xp + k0);
      f16x8 bg0 = *(const f16x8*)(wgp + k0);
      f16x8 bg1 = *(const f16x8*)(wgp + 16 * CI + k0);
      f16x8 bg2 = *(const f16x8*)(wgp + 32 * CI + k0);
      f16x8 bg3 = *(const f16x8*)(wgp + 48 * CI + k0);
      f16x8 bc0 = *(const f16x8*)(wcp + k0);
      f16x8 bc1 = *(const f16x8*)(wcp + 16 * CI + k0);
      f16x8 bc2 = *(const f16x8*)(wcp + 32 * CI + k0);
      f16x8 bc3 = *(const f16x8*)(wcp + 48 * CI + k0);
      g0 = __builtin_amdgcn_mfma_f32_16x16x32_f16(av, bg0, g0, 0, 0, 0);
      g1 = __builtin_amdgcn_mfma_f32_16x16x32_f16(av, bg1, g1, 0, 0, 0);
      g2 = __builtin_amdgcn_mfma_f32_16x16x32_f16(av, bg2, g2, 0, 0, 0);
      g3 = __builtin_amdgcn_mfma_f32_16x16x32_f16(av, bg3, g3, 0, 0, 0);
      c0 = __builtin_amdgcn_mfma_f32_16x16x32_f16(av, bc0, c0, 0, 0, 0);
      c1 = __builtin_amdgcn_mfma_f32_16x16x32_f16(av, bc1, c1, 0, 0, 0);
      c2 = __builtin_amdgcn_mfma_f32_16x16x32_f16(av, bc2, c2, 0, 0, 0);
      c3 = __builtin_amdgcn_mfma_f32_16x16x32_f16(av, bc3, c3, 0, 0, 0);
    }
  }
  // phase 1: reduce g
  #pragma unroll
  for (int r = 0; r < 4; ++r) {
    int s = kseg * 4 + r;
    red[wv][s][srow] = g0[r];
    red[wv][s][16 + srow] = g1[r];
    red[wv][s][32 + srow] = g2[r];
    red[wv][s][48 + srow] = g3[r];
  }
  __syncthreads();
  float gsum[4];
  #pragma unroll
  for (int q = 0; q < 4; ++q) {
    int i = threadIdx.x + q * TPB;
    int s = i >> 6, co = i & 63;
    gsum[q] = red[0][s][co] + red[1][s][co] + red[2][s][co] + red[3][s][co];
  }
  __syncthreads();
  // phase 2: reduce c, combine, store
  #pragma unroll
  for (int r = 0; r < 4; ++r) {
    int s = kseg * 4 + r;
    red[wv][s][srow] = c0[r];
    red[wv][s][16 + srow] = c1[r];
    red[wv][s][32 + srow] = c2[r];
    red[wv][s][48 + srow] = c3[r];
  }
  __syncthreads();
  #pragma unroll
  for (int q = 0; q < 4; ++q) {
    int i = threadIdx.x + q * TPB;
    int s = i >> 6, co = i & 63;
    float cs = red[0][s][co] + red[1][s][co] + red[2][s][co] + red[3][s][co];
    int ss = base + s;
    if (ss < nact) {
      float u = 1.f / (1.f + expf(-gsum[q]));
      float v = u * tanhf(cs);
      if (hcomp) hcomp[(long)ss * CO + co0 + co] = (half_t)v;
      hdense[(long)list[ss] * CO + co0 + co] = v;
    }
  }
}

// ---------- BN ----------
template <int CO>
__global__ void bn_stats2_k(const float* __restrict__ y, const int* __restrict__ cnt,
                            float* __restrict__ stats) {
  __shared__ float ls[512];
  for (int i = threadIdx.x; i < 2 * CO; i += TPB) ls[i] = 0.f;
  __syncthreads();
  long total = (long)cnt[0] * CO;
  long i0 = (long)blockIdx.x * TPB + threadIdx.x;
  int c = (int)(i0 & (CO - 1));
  float s = 0.f, s2 = 0.f;
  for (long i = i0; i < total; i += (long)gridDim.x * TPB) {
    float v = y[i];
    s += v; s2 += v * v;
  }
  atomicAdd(&ls[c], s);
  atomicAdd(&ls[CO + c], s2);
  __syncthreads();
  for (int i = threadIdx.x; i < 2 * CO; i += TPB) atomicAdd(&stats[i], ls[i]);
}

__global__ void bn_fin_k(const float* __restrict__ stats, const int* __restrict__ cnt,
                         const float* __restrict__ gamma, const float* __restrict__ beta,
                         float* __restrict__ bnsc, int CO) {
  int c = threadIdx.x;
  if (c >= CO) return;
  float n = fmaxf((float)cnt[0], 1.f);
  float mean = stats[c] / n;
  float var = fmaxf(stats[CO + c] / n - mean * mean, 0.f);
  float sc = gamma[c] * rsqrtf(var + 1e-4f);
  bnsc[c] = sc;
  bnsc[CO + c] = beta[c] - mean * sc;
}

template <int C>
__global__ void bnapply_f16_k(const float* __restrict__ y, const int* __restrict__ cnt,
                              const float* __restrict__ bnsc, half_t* __restrict__ out) {
  long total = (long)cnt[0] * C;
  for (long i = (long)blockIdx.x * TPB + threadIdx.x; i < total; i += (long)gridDim.x * TPB) {
    int c = (int)(i & (C - 1));
    out[i] = (half_t)fmaxf(fmaf(y[i], bnsc[c], bnsc[C + c]), 0.f);
  }
}

// ---------- head ----------
#define KS 140
__global__ void lin1_part2_k(const float* __restrict__ h2, const float* __restrict__ W1,
                             float* __restrict__ part) {
  __shared__ float sh[32][65];
  int kc = blockIdx.x;
  int j = blockIdx.y * TPB + threadIdx.x;
  int k0 = kc * 64;
  for (int i = threadIdx.x; i < 32 * 64; i += TPB) {
    int b = i >> 6, kk = i & 63;
    int k = k0 + kk;
    int c = k / 35, s = k - c * 35;
    sh[b][kk] = h2[(long)b * 8960 + s * 256 + c];
  }
  __syncthreads();
  float acc[32];
  #pragma unroll
  for (int b = 0; b < 32; ++b) acc[b] = 0.f;
  #pragma unroll 4
  for (int kk = 0; kk < 64; ++kk) {
    float w = W1[(long)(k0 + kk) * 1024 + j];
    #pragma unroll
    for (int b = 0; b < 32; ++b) acc[b] = fmaf(sh[b][kk], w, acc[b]);
  }
  #pragma unroll
  for (int b = 0; b < 32; ++b) part[((long)(kc * 32 + b)) * 1024 + j] = acc[b];
}

__global__ void lin1_reduce_k(const float* __restrict__ part, const float* __restrict__ b1,
                              float* __restrict__ y1) {
  int i = blockIdx.x * TPB + threadIdx.x;
  if (i >= 32 * 1024) return;
  int b = i >> 10, j = i & 1023;
  float a = b1[j];
  for (int kc = 0; kc < KS; ++kc) a += part[(long)kc * 32768 + b * 1024 + j];
  y1[i] = fmaxf(a, 0.f);
}

#define JS2 8
__global__ void lin2_part_k(const float* __restrict__ y1, const float* __restrict__ W2,
                            float* __restrict__ part2) {
  int i = blockIdx.x * TPB + threadIdx.x;
  if (i >= 32 * 420) return;
  int b = i / 420, o = i - b * 420;
  int j0 = blockIdx.y * 128;
  float a = 0.f;
  const float* yp = y1 + b * 1024 + j0;
  const float* wp = W2 + (long)j0 * 420 + o;
  #pragma unroll 8
  for (int j = 0; j < 128; ++j) a = fmaf(yp[j], wp[(long)j * 420], a);
  part2[(long)blockIdx.y * 13440 + i] = a;
}

__global__ void lin2_fin_k(const float* __restrict__ part2, const float* __restrict__ b2,
                           float* __restrict__ out) {
  int i = blockIdx.x * TPB + threadIdx.x;
  if (i >= 32 * 420) return;
  int o = i % 420;
  float a = b2[o];
  #pragma unroll
  for (int js = 0; js < JS2; ++js) a += part2[(long)js * 13440 + i];
  out[i] = a;
}

extern "C" void kernel_launch(void* const* d_in, const int* in_sizes, int n_in,
                              void* d_out, int out_size, void* d_ws, size_t ws_size,
                              hipStream_t stream) {
  const float* x = (const float*)d_in[0];
  const float* ca[5] = {(const float*)d_in[2], (const float*)d_in[6], (const float*)d_in[10],
                        (const float*)d_in[14], (const float*)d_in[18]};
  const float* bg[5] = {(const float*)d_in[3], (const float*)d_in[7], (const float*)d_in[11],
                        (const float*)d_in[15], (const float*)d_in[19]};
  const float* bb[5] = {(const float*)d_in[4], (const float*)d_in[8], (const float*)d_in[12],
                        (const float*)d_in[16], (const float*)d_in[20]};
  const float* cb[5] = {(const float*)d_in[5], (const float*)d_in[9], (const float*)d_in[13],
                        (const float*)d_in[17], (const float*)d_in[21]};
  const float* g1Wg = (const float*)d_in[22];
  const float* g1Wc = (const float*)d_in[23];
  const float* g2Wg = (const float*)d_in[24];
  const float* g2Wc = (const float*)d_in[25];
  const float* W1 = (const float*)d_in[26];
  const float* b1 = (const float*)d_in[27];
  const float* W2 = (const float*)d_in[28];
  const float* b2 = (const float*)d_in[29];

  const int Hs[6] = {191, 95, 47, 23, 11, 5};
  const int Wd[6] = {255, 127, 63, 31, 15, 7};
  const long NS[6] = {1558560, 386080, 94752, 22816, 5280, 1120};
  const int cap[6] = {400000, 386080, 94752, 22816, 5280, 1120};

  float* ws = (float*)d_ws;
  const long BUF = 12354560;
  long off = 0;
  float* bufA = ws + off; off += BUF;
  float* bufB = ws + off; off += BUF;
  float* stats = ws + off; off += 512;
  float* bnsc = ws + off;  off += 512;
  float* y1 = ws + off;    off += 32L * 1024;

  half_t* hbase = (half_t*)(ws + off);
  long hoff = 0;
  half_t* hbufA = hbase + hoff; hoff += 6500000;
  half_t* hbufB = hbase + hoff; hoff += 6500000;
  half_t* xh = hbase + hoff;    hoff += 3117120;
  half_t* wp_ca0 = hbase + hoff; hoff += 16L * 32;
  half_t* wp_cb0 = hbase + hoff; hoff += 16L * 160;
  half_t* wp_ca1 = hbase + hoff; hoff += 32L * 160;
  half_t* wp_cb1 = hbase + hoff; hoff += 32L * 288;
  half_t* wt_ca2 = hbase + hoff; hoff += 9L * 64 * 32;
  half_t* wt_cb2 = hbase + hoff; hoff += 9L * 64 * 64;
  half_t* wt_ca3 = hbase + hoff; hoff += 9L * 128 * 64;
  half_t* wt_cb3 = hbase + hoff; hoff += 9L * 128 * 128;
  half_t* wt_ca4 = hbase + hoff; hoff += 9L * 256 * 128;
  half_t* wt_cb4 = hbase + hoff; hoff += 9L * 256 * 256;
  half_t* wt_g1g = hbase + hoff; hoff += 9L * 256 * 256;
  half_t* wt_g1c = hbase + hoff; hoff += 9L * 256 * 256;
  half_t* wt_g2g = hbase + hoff; hoff += 9L * 256 * 256;
  half_t* wt_g2c = hbase + hoff; hoff += 9L * 256 * 256;

  int* ip = (int*)(hbase + hoff);
  long ioff = 0;
  int* cnt = ip + ioff; ioff += 16;
  int* bcnt = ip + ioff; ioff += 8192;
  int* list[6]; int* inv[6];
  for (int l = 0; l < 6; ++l) { list[l] = ip + ioff; ioff += cap[l]; }
  for (int l = 0; l < 6; ++l) { inv[l] = ip + ioff; ioff += NS[l]; }
  size_t needed = (size_t)off * 4 + (size_t)hoff * 2 + (size_t)ioff * 4;
  if (ws_size < needed) return;

  float* h1d = (float*)d_out + 13440;
  float* h2d = h1d + 286720;

  // ---- weight packing ----
  wtrp_k<<<nblk(16L * 32), TPB, 0, stream>>>(ca[0], wp_ca0, 2, 16, 32, 2, 16);
  wtrp_k<<<nblk(16L * 160), TPB, 0, stream>>>(cb[0], wp_cb0, 16, 16, 160, 16, 16);
  wtrp_k<<<nblk(32L * 160), TPB, 0, stream>>>(ca[1], wp_ca1, 16, 32, 160, 16, 32);
  wtrp_k<<<nblk(32L * 288), TPB, 0, stream>>>(cb[1], wp_cb1, 32, 32, 288, 32, 32);
  wtr_k<<<nblk(9L * 64 * 32), TPB, 0, stream>>>(ca[2], wt_ca2, 32, 64, 32, 64);
  wtr_k<<<nblk(9L * 64 * 64), TPB, 0, stream>>>(cb[2], wt_cb2, 64, 64, 64, 64);
  wtr_k<<<nblk(9L * 128 * 64), TPB, 0, stream>>>(ca[3], wt_ca3, 64, 128, 64, 128);
  wtr_k<<<nblk(9L * 128 * 128), TPB, 0, stream>>>(cb[3], wt_cb3, 128, 128, 128, 128);
  wtr_k<<<nblk(9L * 256 * 128), TPB, 0, stream>>>(ca[4], wt_ca4, 128, 256, 128, 256);
  wtr_k<<<gmin(nblk(9L * 256 * 256), 2048), TPB, 0, stream>>>(cb[4], wt_cb4, 256, 256, 256, 256);
  wtr_k<<<gmin(nblk(9L * 256 * 256), 2048), TPB, 0, stream>>>(g1Wg, wt_g1g, 256, 256, 512, 512);
  wtr_k<<<gmin(nblk(9L * 256 * 256), 2048), TPB, 0, stream>>>(g1Wc, wt_g1c, 256, 256, 512, 256);
  wtr_k<<<gmin(nblk(9L * 256 * 256), 2048), TPB, 0, stream>>>(g2Wg, wt_g2g, 256, 256, 512, 512);
  wtr_k<<<gmin(nblk(9L * 256 * 256), 2048), TPB, 0, stream>>>(g2Wc, wt_g2c, 256, 256, 512, 256);
  cvt_x_k<<<4096, TPB, 0, stream>>>(x, xh, 3117120);

  // ---- level-0 compaction ----
  {
    int nb = nblk(NS[0]);
    cmpA0_k<<<nb, TPB, 0, stream>>>(x, (int)NS[0], bcnt);
    scan_k<<<1, 1024, 0, stream>>>(bcnt, nb, cnt + 0);
    cmpB0_k<<<nb, TPB, 0, stream>>>(x, (int)NS[0], bcnt, list[0], inv[0], cap[0]);
  }

  // ---------- level 1 (MFMA, K-packed) ----------
  hipMemsetAsync(stats, 0, 512 * 4, stream);
  mconvp_k<2, 16, true><<<(cap[0] + 63) / 64, TPB, 0, stream>>>(
      xh, wp_ca0, bufA, nullptr, list[0], cnt + 0, Hs[0], Wd[0]);
  bn_stats2_k<16><<<1024, TPB, 0, stream>>>(bufA, cnt + 0, stats);
  bn_fin_k<<<1, 256, 0, stream>>>(stats, cnt + 0, bg[0], bb[0], bnsc, 16);
  bnapply_f16_k<16><<<2048, TPB, 0, stream>>>(bufA, cnt + 0, bnsc, hbufA);
  mconvp_k<16, 16, false><<<(cap[0] + 63) / 64, TPB, 0, stream>>>(
      hbufA, wp_cb0, bufB, inv[0], list[0], cnt + 0, Hs[0], Wd[0]);
  {
    int nb = nblk(NS[1]);
    poolA_k<<<nb, TPB, 0, stream>>>(inv[0], Hs[0], Wd[0], Hs[1], Wd[1], (int)NS[1], bcnt);
    scan_k<<<1, 1024, 0, stream>>>(bcnt, nb, cnt + 1);
    poolB_k<<<nb, TPB, 0, stream>>>(inv[0], Hs[0], Wd[0], Hs[1], Wd[1], (int)NS[1], bcnt,
                                    list[1], inv[1], cap[1]);
  }
  pool_val_f16_k<16><<<2048, TPB, 0, stream>>>(bufB, inv[0], list[1], cnt + 1, Hs[0], Wd[0], Hs[1], Wd[1], hbufB);

  // ---------- level 2 (MFMA, K-packed) ----------
  hipMemsetAsync(stats, 0, 512 * 4, stream);
  mconvp_k<16, 32, false><<<(cap[1] + 63) / 64, TPB, 0, stream>>>(
      hbufB, wp_ca1, bufB, inv[1], list[1], cnt + 1, Hs[1], Wd[1]);
  bn_stats2_k<32><<<1024, TPB, 0, stream>>>(bufB, cnt + 1, stats);
  bn_fin_k<<<1, 256, 0, stream>>>(stats, cnt + 1, bg[1], bb[1], bnsc, 32);
  bnapply_f16_k<32><<<2048, TPB, 0, stream>>>(bufB, cnt + 1, bnsc, hbufA);
  mconvp_k<32, 32, false><<<(cap[1] + 63) / 64, TPB, 0, stream>>>(
      hbufA, wp_cb1, bufA, inv[1], list[1], cnt + 1, Hs[1], Wd[1]);
  {
    int nb = nblk(NS[2]);
    poolA_k<<<nb, TPB, 0, stream>>>(inv[1], Hs[1], Wd[1], Hs[2], Wd[2], (int)NS[2], bcnt);
    scan_k<<<1, 1024, 0, stream>>>(bcnt, nb, cnt + 2);
    poolB_k<<<nb, TPB, 0, stream>>>(inv[1], Hs[1], Wd[1], Hs[2], Wd[2], (int)NS[2], bcnt,
                                    list[2], inv[2], cap[2]);
  }
  pool_val_f16_k<32><<<2048, TPB, 0, stream>>>(bufA, inv[1], list[2], cnt + 2, Hs[1], Wd[1], Hs[2], Wd[2], hbufB);

  // ---------- level 3 (MFMA) ----------
  hipMemsetAsync(stats, 0, 512 * 4, stream);
  mconv_k<32, 64><<<dim3((cap[2] + 63) / 64, 1), TPB, 0, stream>>>(
      hbufB, wt_ca2, bufA, inv[2], list[2], cnt + 2, Hs[2], Wd[2]);
  bn_stats2_k<64><<<1024, TPB, 0, stream>>>(bufA, cnt + 2, stats);
  bn_fin_k<<<1, 256, 0, stream>>>(stats, cnt + 2, bg[2], bb[2], bnsc, 64);
  bnapply_f16_k<64><<<2048, TPB, 0, stream>>>(bufA, cnt + 2, bnsc, hbufA);
  mconv_k<64, 64><<<dim3((cap[2] + 63) / 64, 1), TPB, 0, stream>>>(
      hbufA, wt_cb2, bufB, inv[2], list[2], cnt + 2, Hs[2], Wd[2]);
  {
    int nb = nblk(NS[3]);
    poolA_k<<<nb, TPB, 0, stream>>>(inv[2], Hs[2], Wd[2], Hs[3], Wd[3], (int)NS[3], bcnt);
    scan_k<<<1, 1024, 0, stream>>>(bcnt, nb, cnt + 3);
    poolB_k<<<nb, TPB, 0, stream>>>(inv[2], Hs[2], Wd[2], Hs[3], Wd[3], (int)NS[3], bcnt,
                                    list[3], inv[3], cap[3]);
  }
  pool_val_f16_k<64><<<2048, TPB, 0, stream>>>(bufB, inv[2], list[3], cnt + 3, Hs[2], Wd[2], Hs[3], Wd[3], hbufB);

  // ---------- level 4 (MFMA) ----------
  hipMemsetAsync(stats, 0, 512 * 4, stream);
  mconv_k<64, 128><<<dim3((cap[3] + 63) / 64, 2), TPB, 0, stream>>>(
      hbufB, wt_ca3, bufA, inv[3], list[3], cnt + 3, Hs[3], Wd[3]);
  bn_stats2_k<128><<<1024, TPB, 0, stream>>>(bufA, cnt + 3, stats);
  bn_fin_k<<<1, 256, 0, stream>>>(stats, cnt + 3, bg[3], bb[3], bnsc, 128);
  bnapply_f16_k<128><<<2048, TPB, 0, stream>>>(bufA, cnt + 3, bnsc, hbufA);
  mconv_k<128, 128><<<dim3((cap[3] + 63) / 64, 2), TPB, 0, stream>>>(
      hbufA, wt_cb3, bufB, inv[3], list[3], cnt + 3, Hs[3], Wd[3]);
  {
    int nb = nblk(NS[4]);
    poolA_k<<<nb, TPB, 0, stream>>>(inv[3], Hs[3], Wd[3], Hs[4], Wd[4], (int)NS[4], bcnt);
    scan_k<<<1, 1024, 0, stream>>>(bcnt, nb, cnt + 4);
    poolB_k<<<nb, TPB, 0, stream>>>(inv[3], Hs[3], Wd[3], Hs[4], Wd[4], (int)NS[4], bcnt,
                                    list[4], inv[4], cap[4]);
  }
  pool_val_f16_k<128><<<2048, TPB, 0, stream>>>(bufB, inv[3], list[4], cnt + 4, Hs[3], Wd[3], Hs[4], Wd[4], hbufB);

  // ---------- level 5 (MFMA, K-split 16-site tiles) ----------
  hipMemsetAsync(stats, 0, 512 * 4, stream);
  mconv_ks_k<128, 256><<<dim3((cap[4] + 15) / 16, 4), TPB, 0, stream>>>(
      hbufB, wt_ca4, bufA, inv[4], list[4], cnt + 4, Hs[4], Wd[4]);
  bn_stats2_k<256><<<1024, TPB, 0, stream>>>(bufA, cnt + 4, stats);
  bn_fin_k<<<1, 256, 0, stream>>>(stats, cnt + 4, bg[4], bb[4], bnsc, 256);
  bnapply_f16_k<256><<<2048, TPB, 0, stream>>>(bufA, cnt + 4, bnsc, hbufA);
  mconv_ks_k<256, 256><<<dim3((cap[4] + 15) / 16, 4), TPB, 0, stream>>>(
      hbufA, wt_cb4, bufB, inv[4], list[4], cnt + 4, Hs[4], Wd[4]);
  {
    int nb = nblk(NS[5]);
    poolA_k<<<nb, TPB, 0, stream>>>(inv[4], Hs[4], Wd[4], Hs[5], Wd[5], (int)NS[5], bcnt);
    scan_k<<<1, 1024, 0, stream>>>(bcnt, nb, cnt + 5);
    poolB_k<<<nb, TPB, 0, stream>>>(inv[4], Hs[4], Wd[4], Hs[5], Wd[5], (int)NS[5], bcnt,
                                    list[5], inv[5], cap[5]);
  }
  pool_val_f16_k<256><<<1024, TPB, 0, stream>>>(bufB, inv[4], list[5], cnt + 5, Hs[4], Wd[4], Hs[5], Wd[5], hbufB);

  // ---------- GRUs (fused conv pair + pointwise) ----------
  long ngb = 286720L * 4;
  hipMemsetAsync(h1d, 0, ngb, stream);
  hipMemsetAsync(h2d, 0, ngb, stream);
  gruconv_k<256><<<dim3((cap[5] + 15) / 16, 4), TPB, 0, stream>>>(
      hbufB, wt_g1g, wt_g1c, h1d, hbufA, inv[5], list[5], cnt + 5, Hs[5], Wd[5]);
  gruconv_k<256><<<dim3((cap[5] + 15) / 16, 4), TPB, 0, stream>>>(
      hbufA, wt_g2g, wt_g2c, h2d, nullptr, inv[5], list[5], cnt + 5, Hs[5], Wd[5]);

  // ---------- head ----------
  float* part = bufA;
  float* part2 = bufB;
  lin1_part2_k<<<dim3(KS, 4), TPB, 0, stream>>>(h2d, W1, part);
  lin1_reduce_k<<<nblk(32L * 1024), TPB, 0, stream>>>(part, b1, y1);
  lin2_part_k<<<dim3(nblk(32L * 420), JS2), TPB, 0, stream>>>(y1, W2, part2);
  lin2_fin_k<<<nblk(32L * 420), TPB, 0, stream>>>(part2, b2, (float*)d_out);
}

// Round 8
// 899.412 us; speedup vs baseline: 7.1225x; 1.0296x over previous
//
#include <hip/hip_runtime.h>
#include <stdint.h>

#define TPB 256

typedef _Float16 half_t;
typedef __attribute__((ext_vector_type(8))) _Float16 f16x8;
typedef __attribute__((ext_vector_type(4))) float f32x4;

static inline int nblk(long n) { return (int)((n + TPB - 1) / TPB); }
static inline int gmin(long a, long b) { return (int)(a < b ? a : b); }

// ---------- scan-based compaction ----------
__device__ __forceinline__ bool act0(const float* x, int i) {
  float2 v = *(const float2*)(x + 2L * i);
  return (v.x != 0.f) || (v.y != 0.f);
}

__global__ void cmpA0_k(const float* __restrict__ x, int n, int* __restrict__ bcnt) {
  int i = blockIdx.x * TPB + threadIdx.x;
  bool a = (i < n) && act0(x, i);
  unsigned long long bal = __ballot(a);
  __shared__ int wc[4];
  if ((threadIdx.x & 63) == 0) wc[threadIdx.x >> 6] = __popcll(bal);
  __syncthreads();
  if (threadIdx.x == 0) bcnt[blockIdx.x] = wc[0] + wc[1] + wc[2] + wc[3];
}

__global__ void cmpB0_k(const float* __restrict__ x, int n, const int* __restrict__ bbase,
                        int* __restrict__ list, int* __restrict__ inv, int cap) {
  int i = blockIdx.x * TPB + threadIdx.x;
  bool a = (i < n) && act0(x, i);
  unsigned long long bal = __ballot(a);
  __shared__ int wc[4];
  int wid = threadIdx.x >> 6, lane = threadIdx.x & 63;
  if (lane == 0) wc[wid] = __popcll(bal);
  __syncthreads();
  int base = bbase[blockIdx.x];
  for (int w = 0; w < wid; ++w) base += wc[w];
  if (i < n) {
    int pos = base + __popcll(bal & ((1ull << lane) - 1));
    if (a && pos < cap) { list[pos] = i; inv[i] = pos; }
    else inv[i] = -1;
  }
}

__device__ __forceinline__ bool actp(const int* invp, int Hp, int Wp, int Ho, int Wo, int i) {
  int wo = i % Wo; int t = i / Wo; int ho = t % Ho; int bb = t / Ho;
  long rb = ((long)bb * Hp + 2 * ho) * Wp + 2 * wo;
  bool a = false;
  #pragma unroll
  for (int kh = 0; kh < 3; ++kh)
    #pragma unroll
    for (int kw = 0; kw < 3; ++kw)
      a |= (invp[rb + kh * Wp + kw] >= 0);
  return a;
}

__global__ void poolA_k(const int* __restrict__ invp, int Hp, int Wp, int Ho, int Wo,
                        int n, int* __restrict__ bcnt) {
  int i = blockIdx.x * TPB + threadIdx.x;
  bool a = (i < n) && actp(invp, Hp, Wp, Ho, Wo, i);
  unsigned long long bal = __ballot(a);
  __shared__ int wc[4];
  if ((threadIdx.x & 63) == 0) wc[threadIdx.x >> 6] = __popcll(bal);
  __syncthreads();
  if (threadIdx.x == 0) bcnt[blockIdx.x] = wc[0] + wc[1] + wc[2] + wc[3];
}

__global__ void poolB_k(const int* __restrict__ invp, int Hp, int Wp, int Ho, int Wo, int n,
                        const int* __restrict__ bbase, int* __restrict__ list,
                        int* __restrict__ inv, int cap) {
  int i = blockIdx.x * TPB + threadIdx.x;
  bool a = (i < n) && actp(invp, Hp, Wp, Ho, Wo, i);
  unsigned long long bal = __ballot(a);
  __shared__ int wc[4];
  int wid = threadIdx.x >> 6, lane = threadIdx.x & 63;
  if (lane == 0) wc[wid] = __popcll(bal);
  __syncthreads();
  int base = bbase[blockIdx.x];
  for (int w = 0; w < wid; ++w) base += wc[w];
  if (i < n) {
    int pos = base + __popcll(bal & ((1ull << lane) - 1));
    if (a && pos < cap) { list[pos] = i; inv[i] = pos; }
    else inv[i] = -1;
  }
}

__global__ void scan_k(int* __restrict__ b, int n, int* __restrict__ total) {
  __shared__ int sh[1024];
  __shared__ int sc;
  if (threadIdx.x == 0) sc = 0;
  __syncthreads();
  for (int base = 0; base < n; base += 1024) {
    int i = base + threadIdx.x;
    int v = (i < n) ? b[i] : 0;
    sh[threadIdx.x] = v;
    __syncthreads();
    for (int o = 1; o < 1024; o <<= 1) {
      int t = (threadIdx.x >= o) ? sh[threadIdx.x - o] : 0;
      __syncthreads();
      sh[threadIdx.x] += t;
      __syncthreads();
    }
    if (i < n) b[i] = sh[threadIdx.x] - v + sc;
    __syncthreads();
    if (threadIdx.x == 0) sc += sh[1023];
    __syncthreads();
  }
  if (threadIdx.x == 0) *total = sc;
}

// ---------- pooled values -> f16 compact rows ----------
template <int C>
__global__ void pool_val_f16_k(const float* __restrict__ xin, const int* __restrict__ invp,
                               const int* __restrict__ list, const int* __restrict__ cnt,
                               int Hp, int Wp, int Ho, int Wo, half_t* __restrict__ y) {
  long total = (long)cnt[0] * C;
  for (long i = (long)blockIdx.x * TPB + threadIdx.x; i < total; i += (long)gridDim.x * TPB) {
    int c = (int)(i & (C - 1));
    int r = (int)(i / C);
    int site = list[r];
    int wo = site % Wo; int t = site / Wo; int ho = t % Ho; int bb = t / Ho;
    long rb = ((long)bb * Hp + 2 * ho) * Wp + 2 * wo;
    float best = -1e30f;
    #pragma unroll
    for (int kh = 0; kh < 3; ++kh)
      #pragma unroll
      for (int kw = 0; kw < 3; ++kw) {
        int j = invp[rb + kh * Wp + kw];
        if (j >= 0) best = fmaxf(best, xin[(long)j * C + c]);
      }
    y[i] = (half_t)best;
  }
}

// ---------- dense x -> f16 ----------
__global__ void cvt_x_k(const float* __restrict__ x, half_t* __restrict__ xh, long n) {
  for (long i = (long)blockIdx.x * TPB + threadIdx.x; i < n; i += (long)gridDim.x * TPB)
    xh[i] = (half_t)x[i];
}

// ---------- weight pack: W[tap][ci][co] f32 -> per-tap [tap][co][ci] f16 ----------
__global__ void wtr_k(const float* __restrict__ Wsrc, half_t* __restrict__ dst,
                      int CI, int CO, int wci, int wco) {
  long total = 9L * CO * CI;
  for (long i = (long)blockIdx.x * TPB + threadIdx.x; i < total; i += (long)gridDim.x * TPB) {
    int ci = (int)(i % CI);
    long t = i / CI;
    int co = (int)(t % CO);
    int tap = (int)(t / CO);
    dst[i] = (half_t)Wsrc[((long)tap * wci + ci) * wco + co];
  }
}

// ---------- weight pack: K-packed [co][KP] f16 ----------
__global__ void wtrp_k(const float* __restrict__ Wsrc, half_t* __restrict__ dst,
                       int CI, int CO, int KP, int wci, int wco) {
  long total = (long)CO * KP;
  for (long i = (long)blockIdx.x * TPB + threadIdx.x; i < total; i += (long)gridDim.x * TPB) {
    int k = (int)(i % KP);
    int co = (int)(i / KP);
    int tap = k / CI, ci = k - tap * CI;
    float v = (tap < 9) ? Wsrc[((long)tap * wci + ci) * wco + co] : 0.f;
    dst[i] = (half_t)v;
  }
}

// ---------- K-packed MFMA conv (CO<=32); 64 sites/block ----------
template <int CI, int CO, bool DENSE>
__global__ __launch_bounds__(256) void mconvp_k(const half_t* __restrict__ X,
                                                const half_t* __restrict__ Wt,
                                                float* __restrict__ y,
                                                const int* __restrict__ inv,
                                                const int* __restrict__ list,
                                                const int* __restrict__ cnt,
                                                int H, int W) {
  constexpr int KP = ((9 * CI + 31) / 32) * 32;
  constexpr int NCO = CO / 16;
  const int nact = cnt[0];
  const int base = blockIdx.x * 64;
  if (base >= nact) return;
  __shared__ int nbr[64 * 9];
  for (int i = threadIdx.x; i < 64 * 9; i += TPB) {
    int s = i / 9, nb = i - s * 9;
    int j = -1;
    if (base + s < nact) {
      int site = list[base + s];
      int w = site % W; int t = site / W; int h = t % H; int bb = t / H;
      int hh = h + nb / 3 - 1, ww = w + nb % 3 - 1;
      if ((unsigned)hh < (unsigned)H && (unsigned)ww < (unsigned)W) {
        int ss = (bb * H + hh) * W + ww;
        j = DENSE ? ss : inv[ss];
      }
    }
    nbr[i] = j;
  }
  __syncthreads();
  const int lane = threadIdx.x & 63, wv = threadIdx.x >> 6;
  const int srow = lane & 15, kseg = lane >> 4;
  const int sloc = wv * 16 + srow;
  f32x4 acc[NCO];
  #pragma unroll
  for (int c = 0; c < NCO; ++c) acc[c] = (f32x4){0.f, 0.f, 0.f, 0.f};
  #pragma unroll
  for (int k0 = 0; k0 < KP; k0 += 32) {
    const int k = k0 + kseg * 8;
    f16x8 av;
    #pragma unroll
    for (int z = 0; z < 8; ++z) av[z] = (_Float16)0.f;
    if (CI >= 8) {
      int tap = k / CI;
      int ci = k - tap * CI;
      if (tap < 9) {
        int j = nbr[sloc * 9 + tap];
        if (j >= 0) av = *(const f16x8*)(X + (long)j * CI + ci);
      }
    } else {  // CI == 2
      #pragma unroll
      for (int q = 0; q < 4; ++q) {
        int kk = k + 2 * q;
        int tap = kk >> 1;
        if (tap < 9) {
          int j = nbr[sloc * 9 + tap];
          if (j >= 0) {
            const half_t* xp = X + (long)j * 2;
            av[2 * q] = xp[0];
            av[2 * q + 1] = xp[1];
          }
        }
      }
    }
    #pragma unroll
    for (int c = 0; c < NCO; ++c) {
      f16x8 bv = *(const f16x8*)(Wt + (long)(c * 16 + srow) * KP + k);
      acc[c] = __builtin_amdgcn_mfma_f32_16x16x32_f16(av, bv, acc[c], 0, 0, 0);
    }
  }
  #pragma unroll
  for (int c = 0; c < NCO; ++c)
    #pragma unroll
    for (int r = 0; r < 4; ++r) {
      int ss = base + wv * 16 + kseg * 4 + r;
      if (ss < nact) y[(long)ss * CO + c * 16 + srow] = acc[c][r];
    }
}

// ---------- mid-level MFMA conv: NG site-groups of 16 per wave, 64 co per block-y ----------
// All 9 neighbor indices precomputed in registers (18 independent gathers in flight),
// tap loop fully unrolled so A/B loads hoist ahead of MFMAs.
template <int CI, int CO, int NG>
__global__ __launch_bounds__(256) void mconv2_k(const half_t* __restrict__ X,
                                                const half_t* __restrict__ Wt,
                                                float* __restrict__ y,
                                                const int* __restrict__ inv,
                                                const int* __restrict__ list,
                                                const int* __restrict__ cnt,
                                                int H, int W) {
  const int nact = cnt[0];
  const int base = blockIdx.x * (64 * NG);
  if (base >= nact) return;
  const int lane = threadIdx.x & 63, wv = threadIdx.x >> 6;
  const int srow = lane & 15, kseg = lane >> 4;
  const int co0 = blockIdx.y * 64;
  int jj[NG][9];
  #pragma unroll
  for (int g = 0; g < NG; ++g) {
    int s = base + (wv * NG + g) * 16 + srow;
    bool sv = (s < nact);
    int h = 0, w = 0, bb = 0;
    if (sv) {
      int site = list[s];
      w = site % W;
      int t = site / W;
      h = t % H;
      bb = t / H;
    }
    #pragma unroll
    for (int tap = 0; tap < 9; ++tap) {
      int j = -1;
      if (sv) {
        int hh = h + tap / 3 - 1, ww = w + tap % 3 - 1;
        if ((unsigned)hh < (unsigned)H && (unsigned)ww < (unsigned)W)
          j = inv[(bb * H + hh) * W + ww];
      }
      jj[g][tap] = j;
    }
  }
  f32x4 acc[NG][4];
  #pragma unroll
  for (int g = 0; g < NG; ++g)
    #pragma unroll
    for (int b = 0; b < 4; ++b) acc[g][b] = (f32x4){0.f, 0.f, 0.f, 0.f};
  #pragma unroll
  for (int tap = 0; tap < 9; ++tap) {
    const half_t* wp = Wt + ((long)tap * CO + co0 + srow) * CI + kseg * 8;
    #pragma unroll
    for (int k0 = 0; k0 < CI; k0 += 32) {
      f16x8 av[NG];
      #pragma unroll
      for (int g = 0; g < NG; ++g) {
        #pragma unroll
        for (int z = 0; z < 8; ++z) av[g][z] = (_Float16)0.f;
        if (jj[g][tap] >= 0)
          av[g] = *(const f16x8*)(X + (long)jj[g][tap] * CI + kseg * 8 + k0);
      }
      #pragma unroll
      for (int b = 0; b < 4; ++b) {
        f16x8 bv = *(const f16x8*)(wp + (long)b * 16 * CI + k0);
        #pragma unroll
        for (int g = 0; g < NG; ++g)
          acc[g][b] = __builtin_amdgcn_mfma_f32_16x16x32_f16(av[g], bv, acc[g][b], 0, 0, 0);
      }
    }
  }
  #pragma unroll
  for (int g = 0; g < NG; ++g)
    #pragma unroll
    for (int b = 0; b < 4; ++b)
      #pragma unroll
      for (int r = 0; r < 4; ++r) {
        int ss = base + (wv * NG + g) * 16 + kseg * 4 + r;
        if (ss < nact) y[(long)ss * CO + co0 + b * 16 + srow] = acc[g][b][r];
      }
}

// ---------- K-split deep conv: 16 sites x 64 co per block, 4 waves split taps ----------
template <int CI, int CO>
__global__ __launch_bounds__(256) void mconv_ks_k(const half_t* __restrict__ X,
                                                  const half_t* __restrict__ Wt,
                                                  float* __restrict__ y,
                                                  const int* __restrict__ inv,
                                                  const int* __restrict__ list,
                                                  const int* __restrict__ cnt,
                                                  int H, int W) {
  const int nact = cnt[0];
  const int base = blockIdx.x * 16;
  if (base >= nact) return;
  __shared__ int nbr[16 * 9];
  __shared__ float red[4][16][65];
  for (int i = threadIdx.x; i < 16 * 9; i += TPB) {
    int s = i / 9, nb = i - s * 9;
    int j = -1;
    if (base + s < nact) {
      int site = list[base + s];
      int w = site % W; int t = site / W; int h = t % H; int bb = t / H;
      int hh = h + nb / 3 - 1, ww = w + nb % 3 - 1;
      if ((unsigned)hh < (unsigned)H && (unsigned)ww < (unsigned)W)
        j = inv[(bb * H + hh) * W + ww];
    }
    nbr[i] = j;
  }
  __syncthreads();
  const int lane = threadIdx.x & 63, wv = threadIdx.x >> 6;
  const int srow = lane & 15, kseg = lane >> 4;
  const int co0 = blockIdx.y * 64;
  const int t0 = (wv * 9) / 4, t1 = ((wv + 1) * 9) / 4;
  f32x4 acc0 = {0.f, 0.f, 0.f, 0.f};
  f32x4 acc1 = acc0, acc2 = acc0, acc3 = acc0;
  for (int tap = t0; tap < t1; ++tap) {
    int j = nbr[srow * 9 + tap];
    const half_t* xp = X + (long)j * CI + kseg * 8;
    const half_t* wp = Wt + ((long)tap * CO + co0 + srow) * CI + kseg * 8;
    #pragma unroll
    for (int k0 = 0; k0 < CI; k0 += 32) {
      f16x8 av;
      #pragma unroll
      for (int z = 0; z < 8; ++z) av[z] = (_Float16)0.f;
      if (j >= 0) av = *(const f16x8*)(xp + k0);
      f16x8 b0 = *(const f16x8*)(wp + k0);
      f16x8 b1 = *(const f16x8*)(wp + 16 * CI + k0);
      f16x8 b2 = *(const f16x8*)(wp + 32 * CI + k0);
      f16x8 b3 = *(const f16x8*)(wp + 48 * CI + k0);
      acc0 = __builtin_amdgcn_mfma_f32_16x16x32_f16(av, b0, acc0, 0, 0, 0);
      acc1 = __builtin_amdgcn_mfma_f32_16x16x32_f16(av, b1, acc1, 0, 0, 0);
      acc2 = __builtin_amdgcn_mfma_f32_16x16x32_f16(av, b2, acc2, 0, 0, 0);
      acc3 = __builtin_amdgcn_mfma_f32_16x16x32_f16(av, b3, acc3, 0, 0, 0);
    }
  }
  #pragma unroll
  for (int r = 0; r < 4; ++r) {
    int s = kseg * 4 + r;
    red[wv][s][srow] = acc0[r];
    red[wv][s][16 + srow] = acc1[r];
    red[wv][s][32 + srow] = acc2[r];
    red[wv][s][48 + srow] = acc3[r];
  }
  __syncthreads();
  for (int i = threadIdx.x; i < 16 * 64; i += TPB) {
    int s = i >> 6, co = i & 63;
    float v = red[0][s][co] + red[1][s][co] + red[2][s][co] + red[3][s][co];
    int ss = base + s;
    if (ss < nact) y[(long)ss * CO + co0 + co] = v;
  }
}

// ---------- fused GRU conv: h=sigmoid(conv(X,Wg))*tanh(conv(X,Wc)) ----------
template <int CI>
__global__ __launch_bounds__(256) void gruconv_k(const half_t* __restrict__ X,
                                                 const half_t* __restrict__ Wg,
                                                 const half_t* __restrict__ Wc,
                                                 float* __restrict__ hdense,
                                                 half_t* __restrict__ hcomp,
                                                 const int* __restrict__ inv,
                                                 const int* __restrict__ list,
                                                 const int* __restrict__ cnt,
                                                 int H, int W) {
  constexpr int CO = 256;
  const int nact = cnt[0];
  const int base = blockIdx.x * 16;
  if (base >= nact) return;
  __shared__ int nbr[16 * 9];
  __shared__ float red[4][16][65];
  for (int i = threadIdx.x; i < 16 * 9; i += TPB) {
    int s = i / 9, nb = i - s * 9;
    int j = -1;
    if (base + s < nact) {
      int site = list[base + s];
      int w = site % W; int t = site / W; int h = t % H; int bb = t / H;
      int hh = h + nb / 3 - 1, ww = w + nb % 3 - 1;
      if ((unsigned)hh < (unsigned)H && (unsigned)ww < (unsigned)W)
        j = inv[(bb * H + hh) * W + ww];
    }
    nbr[i] = j;
  }
  __syncthreads();
  const int lane = threadIdx.x & 63, wv = threadIdx.x >> 6;
  const int srow = lane & 15, kseg = lane >> 4;
  const int co0 = blockIdx.y * 64;
  const int t0 = (wv * 9) / 4, t1 = ((wv + 1) * 9) / 4;
  f32x4 g0 = {0.f, 0.f, 0.f, 0.f};
  f32x4 g1 = g0, g2 = g0, g3 = g0, c0 = g0, c1 = g0, c2 = g0, c3 = g0;
  for (int tap = t0; tap < t1; ++tap) {
    int j = nbr[srow * 9 + tap];
    const half_t* xp = X + (long)j * CI + kseg * 8;
    const half_t* wgp = Wg + ((long)tap * CO + co0 + srow) * CI + kseg * 8;
    const half_t* wcp = Wc + ((long)tap * CO + co0 + srow) * CI + kseg * 8;
    #pragma unroll
    for (int k0 = 0; k0 < CI; k0 += 32) {
      f16x8 av;
      #pragma unroll
      for (int z = 0; z < 8; ++z) av[z] = (_Float16)0.f;
      if (j >= 0) av = *(const f16x8*)(xp + k0);
      f16x8 bg0 = *(const f16x8*)(wgp + k0);
      f16x8 bg1 = *(const f16x8*)(wgp + 16 * CI + k0);
      f16x8 bg2 = *(const f16x8*)(wgp + 32 * CI + k0);
      f16x8 bg3 = *(const f16x8*)(wgp + 48 * CI + k0);
      f16x8 bc0 = *(const f16x8*)(wcp + k0);
      f16x8 bc1 = *(const f16x8*)(wcp + 16 * CI + k0);
      f16x8 bc2 = *(const f16x8*)(wcp + 32 * CI + k0);
      f16x8 bc3 = *(const f16x8*)(wcp + 48 * CI + k0);
      g0 = __builtin_amdgcn_mfma_f32_16x16x32_f16(av, bg0, g0, 0, 0, 0);
      g1 = __builtin_amdgcn_mfma_f32_16x16x32_f16(av, bg1, g1, 0, 0, 0);
      g2 = __builtin_amdgcn_mfma_f32_16x16x32_f16(av, bg2, g2, 0, 0, 0);
      g3 = __builtin_amdgcn_mfma_f32_16x16x32_f16(av, bg3, g3, 0, 0, 0);
      c0 = __builtin_amdgcn_mfma_f32_16x16x32_f16(av, bc0, c0, 0, 0, 0);
      c1 = __builtin_amdgcn_mfma_f32_16x16x32_f16(av, bc1, c1, 0, 0, 0);
      c2 = __builtin_amdgcn_mfma_f32_16x16x32_f16(av, bc2, c2, 0, 0, 0);
      c3 = __builtin_amdgcn_mfma_f32_16x16x32_f16(av, bc3, c3, 0, 0, 0);
    }
  }
  #pragma unroll
  for (int r = 0; r < 4; ++r) {
    int s = kseg * 4 + r;
    red[wv][s][srow] = g0[r];
    red[wv][s][16 + srow] = g1[r];
    red[wv][s][32 + srow] = g2[r];
    red[wv][s][48 + srow] = g3[r];
  }
  __syncthreads();
  float gsum[4];
  #pragma unroll
  for (int q = 0; q < 4; ++q) {
    int i = threadIdx.x + q * TPB;
    int s = i >> 6, co = i & 63;
    gsum[q] = red[0][s][co] + red[1][s][co] + red[2][s][co] + red[3][s][co];
  }
  __syncthreads();
  #pragma unroll
  for (int r = 0; r < 4; ++r) {
    int s = kseg * 4 + r;
    red[wv][s][srow] = c0[r];
    red[wv][s][16 + srow] = c1[r];
    red[wv][s][32 + srow] = c2[r];
    red[wv][s][48 + srow] = c3[r];
  }
  __syncthreads();
  #pragma unroll
  for (int q = 0; q < 4; ++q) {
    int i = threadIdx.x + q * TPB;
    int s = i >> 6, co = i & 63;
    float cs = red[0][s][co] + red[1][s][co] + red[2][s][co] + red[3][s][co];
    int ss = base + s;
    if (ss < nact) {
      float u = 1.f / (1.f + expf(-gsum[q]));
      float v = u * tanhf(cs);
      if (hcomp) hcomp[(long)ss * CO + co0 + co] = (half_t)v;
      hdense[(long)list[ss] * CO + co0 + co] = v;
    }
  }
}

// ---------- BN ----------
template <int CO>
__global__ void bn_stats2_k(const float* __restrict__ y, const int* __restrict__ cnt,
                            float* __restrict__ stats) {
  __shared__ float ls[512];
  for (int i = threadIdx.x; i < 2 * CO; i += TPB) ls[i] = 0.f;
  __syncthreads();
  long total = (long)cnt[0] * CO;
  long i0 = (long)blockIdx.x * TPB + threadIdx.x;
  int c = (int)(i0 & (CO - 1));
  float s = 0.f, s2 = 0.f;
  for (long i = i0; i < total; i += (long)gridDim.x * TPB) {
    float v = y[i];
    s += v; s2 += v * v;
  }
  atomicAdd(&ls[c], s);
  atomicAdd(&ls[CO + c], s2);
  __syncthreads();
  for (int i = threadIdx.x; i < 2 * CO; i += TPB) atomicAdd(&stats[i], ls[i]);
}

__global__ void bn_fin_k(const float* __restrict__ stats, const int* __restrict__ cnt,
                         const float* __restrict__ gamma, const float* __restrict__ beta,
                         float* __restrict__ bnsc, int CO) {
  int c = threadIdx.x;
  if (c >= CO) return;
  float n = fmaxf((float)cnt[0], 1.f);
  float mean = stats[c] / n;
  float var = fmaxf(stats[CO + c] / n - mean * mean, 0.f);
  float sc = gamma[c] * rsqrtf(var + 1e-4f);
  bnsc[c] = sc;
  bnsc[CO + c] = beta[c] - mean * sc;
}

template <int C>
__global__ void bnapply_f16_k(const float* __restrict__ y, const int* __restrict__ cnt,
                              const float* __restrict__ bnsc, half_t* __restrict__ out) {
  long total = (long)cnt[0] * C;
  for (long i = (long)blockIdx.x * TPB + threadIdx.x; i < total; i += (long)gridDim.x * TPB) {
    int c = (int)(i & (C - 1));
    out[i] = (half_t)fmaxf(fmaf(y[i], bnsc[c], bnsc[C + c]), 0.f);
  }
}

// ---------- head ----------
#define KS 140
__global__ void lin1_part2_k(const float* __restrict__ h2, const float* __restrict__ W1,
                             float* __restrict__ part) {
  __shared__ float sh[32][65];
  int kc = blockIdx.x;
  int j = blockIdx.y * TPB + threadIdx.x;
  int k0 = kc * 64;
  for (int i = threadIdx.x; i < 32 * 64; i += TPB) {
    int b = i >> 6, kk = i & 63;
    int k = k0 + kk;
    int c = k / 35, s = k - c * 35;
    sh[b][kk] = h2[(long)b * 8960 + s * 256 + c];
  }
  __syncthreads();
  float acc[32];
  #pragma unroll
  for (int b = 0; b < 32; ++b) acc[b] = 0.f;
  #pragma unroll 4
  for (int kk = 0; kk < 64; ++kk) {
    float w = W1[(long)(k0 + kk) * 1024 + j];
    #pragma unroll
    for (int b = 0; b < 32; ++b) acc[b] = fmaf(sh[b][kk], w, acc[b]);
  }
  #pragma unroll
  for (int b = 0; b < 32; ++b) part[((long)(kc * 32 + b)) * 1024 + j] = acc[b];
}

__global__ void lin1_reduce_k(const float* __restrict__ part, const float* __restrict__ b1,
                              float* __restrict__ y1) {
  int i = blockIdx.x * TPB + threadIdx.x;
  if (i >= 32 * 1024) return;
  int b = i >> 10, j = i & 1023;
  float a = b1[j];
  for (int kc = 0; kc < KS; ++kc) a += part[(long)kc * 32768 + b * 1024 + j];
  y1[i] = fmaxf(a, 0.f);
}

#define JS2 8
__global__ void lin2_part_k(const float* __restrict__ y1, const float* __restrict__ W2,
                            float* __restrict__ part2) {
  int i = blockIdx.x * TPB + threadIdx.x;
  if (i >= 32 * 420) return;
  int b = i / 420, o = i - b * 420;
  int j0 = blockIdx.y * 128;
  float a = 0.f;
  const float* yp = y1 + b * 1024 + j0;
  const float* wp = W2 + (long)j0 * 420 + o;
  #pragma unroll 8
  for (int j = 0; j < 128; ++j) a = fmaf(yp[j], wp[(long)j * 420], a);
  part2[(long)blockIdx.y * 13440 + i] = a;
}

__global__ void lin2_fin_k(const float* __restrict__ part2, const float* __restrict__ b2,
                           float* __restrict__ out) {
  int i = blockIdx.x * TPB + threadIdx.x;
  if (i >= 32 * 420) return;
  int o = i % 420;
  float a = b2[o];
  #pragma unroll
  for (int js = 0; js < JS2; ++js) a += part2[(long)js * 13440 + i];
  out[i] = a;
}

extern "C" void kernel_launch(void* const* d_in, const int* in_sizes, int n_in,
                              void* d_out, int out_size, void* d_ws, size_t ws_size,
                              hipStream_t stream) {
  const float* x = (const float*)d_in[0];
  const float* ca[5] = {(const float*)d_in[2], (const float*)d_in[6], (const float*)d_in[10],
                        (const float*)d_in[14], (const float*)d_in[18]};
  const float* bg[5] = {(const float*)d_in[3], (const float*)d_in[7], (const float*)d_in[11],
                        (const float*)d_in[15], (const float*)d_in[19]};
  const float* bb[5] = {(const float*)d_in[4], (const float*)d_in[8], (const float*)d_in[12],
                        (const float*)d_in[16], (const float*)d_in[20]};
  const float* cb[5] = {(const float*)d_in[5], (const float*)d_in[9], (const float*)d_in[13],
                        (const float*)d_in[17], (const float*)d_in[21]};
  const float* g1Wg = (const float*)d_in[22];
  const float* g1Wc = (const float*)d_in[23];
  const float* g2Wg = (const float*)d_in[24];
  const float* g2Wc = (const float*)d_in[25];
  const float* W1 = (const float*)d_in[26];
  const float* b1 = (const float*)d_in[27];
  const float* W2 = (const float*)d_in[28];
  const float* b2 = (const float*)d_in[29];

  const int Hs[6] = {191, 95, 47, 23, 11, 5};
  const int Wd[6] = {255, 127, 63, 31, 15, 7};
  const long NS[6] = {1558560, 386080, 94752, 22816, 5280, 1120};
  const int cap[6] = {200000, 386080, 94752, 22816, 5280, 1120};

  float* ws = (float*)d_ws;
  const long BUF = 12354560;
  long off = 0;
  float* bufA = ws + off; off += BUF;
  float* bufB = ws + off; off += BUF;
  float* stats = ws + off; off += 512;
  float* bnsc = ws + off;  off += 512;
  float* y1 = ws + off;    off += 32L * 1024;

  half_t* hbase = (half_t*)(ws + off);
  long hoff = 0;
  half_t* hbufA = hbase + hoff; hoff += 6500000;
  half_t* hbufB = hbase + hoff; hoff += 6500000;
  half_t* xh = hbase + hoff;    hoff += 3117120;
  half_t* wp_ca0 = hbase + hoff; hoff += 16L * 32;
  half_t* wp_cb0 = hbase + hoff; hoff += 16L * 160;
  half_t* wp_ca1 = hbase + hoff; hoff += 32L * 160;
  half_t* wp_cb1 = hbase + hoff; hoff += 32L * 288;
  half_t* wt_ca2 = hbase + hoff; hoff += 9L * 64 * 32;
  half_t* wt_cb2 = hbase + hoff; hoff += 9L * 64 * 64;
  half_t* wt_ca3 = hbase + hoff; hoff += 9L * 128 * 64;
  half_t* wt_cb3 = hbase + hoff; hoff += 9L * 128 * 128;
  half_t* wt_ca4 = hbase + hoff; hoff += 9L * 256 * 128;
  half_t* wt_cb4 = hbase + hoff; hoff += 9L * 256 * 256;
  half_t* wt_g1g = hbase + hoff; hoff += 9L * 256 * 256;
  half_t* wt_g1c = hbase + hoff; hoff += 9L * 256 * 256;
  half_t* wt_g2g = hbase + hoff; hoff += 9L * 256 * 256;
  half_t* wt_g2c = hbase + hoff; hoff += 9L * 256 * 256;

  int* ip = (int*)(hbase + hoff);
  long ioff = 0;
  int* cnt = ip + ioff; ioff += 16;
  int* bcnt = ip + ioff; ioff += 8192;
  int* list[6]; int* inv[6];
  for (int l = 0; l < 6; ++l) { list[l] = ip + ioff; ioff += cap[l]; }
  for (int l = 0; l < 6; ++l) { inv[l] = ip + ioff; ioff += NS[l]; }
  size_t needed = (size_t)off * 4 + (size_t)hoff * 2 + (size_t)ioff * 4;
  if (ws_size < needed) return;

  float* h1d = (float*)d_out + 13440;
  float* h2d = h1d + 286720;

  // ---- weight packing ----
  wtrp_k<<<nblk(16L * 32), TPB, 0, stream>>>(ca[0], wp_ca0, 2, 16, 32, 2, 16);
  wtrp_k<<<nblk(16L * 160), TPB, 0, stream>>>(cb[0], wp_cb0, 16, 16, 160, 16, 16);
  wtrp_k<<<nblk(32L * 160), TPB, 0, stream>>>(ca[1], wp_ca1, 16, 32, 160, 16, 32);
  wtrp_k<<<nblk(32L * 288), TPB, 0, stream>>>(cb[1], wp_cb1, 32, 32, 288, 32, 32);
  wtr_k<<<nblk(9L * 64 * 32), TPB, 0, stream>>>(ca[2], wt_ca2, 32, 64, 32, 64);
  wtr_k<<<nblk(9L * 64 * 64), TPB, 0, stream>>>(cb[2], wt_cb2, 64, 64, 64, 64);
  wtr_k<<<nblk(9L * 128 * 64), TPB, 0, stream>>>(ca[3], wt_ca3, 64, 128, 64, 128);
  wtr_k<<<nblk(9L * 128 * 128), TPB, 0, stream>>>(cb[3], wt_cb3, 128, 128, 128, 128);
  wtr_k<<<nblk(9L * 256 * 128), TPB, 0, stream>>>(ca[4], wt_ca4, 128, 256, 128, 256);
  wtr_k<<<gmin(nblk(9L * 256 * 256), 2048), TPB, 0, stream>>>(cb[4], wt_cb4, 256, 256, 256, 256);
  wtr_k<<<gmin(nblk(9L * 256 * 256), 2048), TPB, 0, stream>>>(g1Wg, wt_g1g, 256, 256, 512, 512);
  wtr_k<<<gmin(nblk(9L * 256 * 256), 2048), TPB, 0, stream>>>(g1Wc, wt_g1c, 256, 256, 512, 256);
  wtr_k<<<gmin(nblk(9L * 256 * 256), 2048), TPB, 0, stream>>>(g2Wg, wt_g2g, 256, 256, 512, 512);
  wtr_k<<<gmin(nblk(9L * 256 * 256), 2048), TPB, 0, stream>>>(g2Wc, wt_g2c, 256, 256, 512, 256);
  cvt_x_k<<<4096, TPB, 0, stream>>>(x, xh, 3117120);

  // ---- level-0 compaction ----
  {
    int nb = nblk(NS[0]);
    cmpA0_k<<<nb, TPB, 0, stream>>>(x, (int)NS[0], bcnt);
    scan_k<<<1, 1024, 0, stream>>>(bcnt, nb, cnt + 0);
    cmpB0_k<<<nb, TPB, 0, stream>>>(x, (int)NS[0], bcnt, list[0], inv[0], cap[0]);
  }

  // ---------- level 1 (MFMA, K-packed) ----------
  hipMemsetAsync(stats, 0, 512 * 4, stream);
  mconvp_k<2, 16, true><<<(cap[0] + 63) / 64, TPB, 0, stream>>>(
      xh, wp_ca0, bufA, nullptr, list[0], cnt + 0, Hs[0], Wd[0]);
  bn_stats2_k<16><<<1024, TPB, 0, stream>>>(bufA, cnt + 0, stats);
  bn_fin_k<<<1, 256, 0, stream>>>(stats, cnt + 0, bg[0], bb[0], bnsc, 16);
  bnapply_f16_k<16><<<2048, TPB, 0, stream>>>(bufA, cnt + 0, bnsc, hbufA);
  mconvp_k<16, 16, false><<<(cap[0] + 63) / 64, TPB, 0, stream>>>(
      hbufA, wp_cb0, bufB, inv[0], list[0], cnt + 0, Hs[0], Wd[0]);
  {
    int nb = nblk(NS[1]);
    poolA_k<<<nb, TPB, 0, stream>>>(inv[0], Hs[0], Wd[0], Hs[1], Wd[1], (int)NS[1], bcnt);
    scan_k<<<1, 1024, 0, stream>>>(bcnt, nb, cnt + 1);
    poolB_k<<<nb, TPB, 0, stream>>>(inv[0], Hs[0], Wd[0], Hs[1], Wd[1], (int)NS[1], bcnt,
                                    list[1], inv[1], cap[1]);
  }
  pool_val_f16_k<16><<<2048, TPB, 0, stream>>>(bufB, inv[0], list[1], cnt + 1, Hs[0], Wd[0], Hs[1], Wd[1], hbufB);

  // ---------- level 2 (MFMA, K-packed) ----------
  hipMemsetAsync(stats, 0, 512 * 4, stream);
  mconvp_k<16, 32, false><<<(cap[1] + 63) / 64, TPB, 0, stream>>>(
      hbufB, wp_ca1, bufB, inv[1], list[1], cnt + 1, Hs[1], Wd[1]);
  bn_stats2_k<32><<<1024, TPB, 0, stream>>>(bufB, cnt + 1, stats);
  bn_fin_k<<<1, 256, 0, stream>>>(stats, cnt + 1, bg[1], bb[1], bnsc, 32);
  bnapply_f16_k<32><<<2048, TPB, 0, stream>>>(bufB, cnt + 1, bnsc, hbufA);
  mconvp_k<32, 32, false><<<(cap[1] + 63) / 64, TPB, 0, stream>>>(
      hbufA, wp_cb1, bufA, inv[1], list[1], cnt + 1, Hs[1], Wd[1]);
  {
    int nb = nblk(NS[2]);
    poolA_k<<<nb, TPB, 0, stream>>>(inv[1], Hs[1], Wd[1], Hs[2], Wd[2], (int)NS[2], bcnt);
    scan_k<<<1, 1024, 0, stream>>>(bcnt, nb, cnt + 2);
    poolB_k<<<nb, TPB, 0, stream>>>(inv[1], Hs[1], Wd[1], Hs[2], Wd[2], (int)NS[2], bcnt,
                                    list[2], inv[2], cap[2]);
  }
  pool_val_f16_k<32><<<2048, TPB, 0, stream>>>(bufA, inv[1], list[2], cnt + 2, Hs[1], Wd[1], Hs[2], Wd[2], hbufB);

  // ---------- level 3 (MFMA, 128-site blocks, j-prefetch) ----------
  hipMemsetAsync(stats, 0, 512 * 4, stream);
  mconv2_k<32, 64, 2><<<dim3((cap[2] + 127) / 128, 1), TPB, 0, stream>>>(
      hbufB, wt_ca2, bufA, inv[2], list[2], cnt + 2, Hs[2], Wd[2]);
  bn_stats2_k<64><<<1024, TPB, 0, stream>>>(bufA, cnt + 2, stats);
  bn_fin_k<<<1, 256, 0, stream>>>(stats, cnt + 2, bg[2], bb[2], bnsc, 64);
  bnapply_f16_k<64><<<2048, TPB, 0, stream>>>(bufA, cnt + 2, bnsc, hbufA);
  mconv2_k<64, 64, 2><<<dim3((cap[2] + 127) / 128, 1), TPB, 0, stream>>>(
      hbufA, wt_cb2, bufB, inv[2], list[2], cnt + 2, Hs[2], Wd[2]);
  {
    int nb = nblk(NS[3]);
    poolA_k<<<nb, TPB, 0, stream>>>(inv[2], Hs[2], Wd[2], Hs[3], Wd[3], (int)NS[3], bcnt);
    scan_k<<<1, 1024, 0, stream>>>(bcnt, nb, cnt + 3);
    poolB_k<<<nb, TPB, 0, stream>>>(inv[2], Hs[2], Wd[2], Hs[3], Wd[3], (int)NS[3], bcnt,
                                    list[3], inv[3], cap[3]);
  }
  pool_val_f16_k<64><<<2048, TPB, 0, stream>>>(bufB, inv[2], list[3], cnt + 3, Hs[2], Wd[2], Hs[3], Wd[3], hbufB);

  // ---------- level 4 (MFMA, 64-site blocks, j-prefetch) ----------
  hipMemsetAsync(stats, 0, 512 * 4, stream);
  mconv2_k<64, 128, 1><<<dim3((cap[3] + 63) / 64, 2), TPB, 0, stream>>>(
      hbufB, wt_ca3, bufA, inv[3], list[3], cnt + 3, Hs[3], Wd[3]);
  bn_stats2_k<128><<<1024, TPB, 0, stream>>>(bufA, cnt + 3, stats);
  bn_fin_k<<<1, 256, 0, stream>>>(stats, cnt + 3, bg[3], bb[3], bnsc, 128);
  bnapply_f16_k<128><<<2048, TPB, 0, stream>>>(bufA, cnt + 3, bnsc, hbufA);
  mconv2_k<128, 128, 1><<<dim3((cap[3] + 63) / 64, 2), TPB, 0, stream>>>(
      hbufA, wt_cb3, bufB, inv[3], list[3], cnt + 3, Hs[3], Wd[3]);
  {
    int nb = nblk(NS[4]);
    poolA_k<<<nb, TPB, 0, stream>>>(inv[3], Hs[3], Wd[3], Hs[4], Wd[4], (int)NS[4], bcnt);
    scan_k<<<1, 1024, 0, stream>>>(bcnt, nb, cnt + 4);
    poolB_k<<<nb, TPB, 0, stream>>>(inv[3], Hs[3], Wd[3], Hs[4], Wd[4], (int)NS[4], bcnt,
                                    list[4], inv[4], cap[4]);
  }
  pool_val_f16_k<128><<<2048, TPB, 0, stream>>>(bufB, inv[3], list[4], cnt + 4, Hs[3], Wd[3], Hs[4], Wd[4], hbufB);

  // ---------- level 5 (MFMA, K-split 16-site tiles) ----------
  hipMemsetAsync(stats, 0, 512 * 4, stream);
  mconv_ks_k<128, 256><<<dim3((cap[4] + 15) / 16, 4), TPB, 0, stream>>>(
      hbufB, wt_ca4, bufA, inv[4], list[4], cnt + 4, Hs[4], Wd[4]);
  bn_stats2_k<256><<<1024, TPB, 0, stream>>>(bufA, cnt + 4, stats);
  bn_fin_k<<<1, 256, 0, stream>>>(stats, cnt + 4, bg[4], bb[4], bnsc, 256);
  bnapply_f16_k<256><<<2048, TPB, 0, stream>>>(bufA, cnt + 4, bnsc, hbufA);
  mconv_ks_k<256, 256><<<dim3((cap[4] + 15) / 16, 4), TPB, 0, stream>>>(
      hbufA, wt_cb4, bufB, inv[4], list[4], cnt + 4, Hs[4], Wd[4]);
  {
    int nb = nblk(NS[5]);
    poolA_k<<<nb, TPB, 0, stream>>>(inv[4], Hs[4], Wd[4], Hs[5], Wd[5], (int)NS[5], bcnt);
    scan_k<<<1, 1024, 0, stream>>>(bcnt, nb, cnt + 5);
    poolB_k<<<nb, TPB, 0, stream>>>(inv[4], Hs[4], Wd[4], Hs[5], Wd[5], (int)NS[5], bcnt,
                                    list[5], inv[5], cap[5]);
  }
  pool_val_f16_k<256><<<1024, TPB, 0, stream>>>(bufB, inv[4], list[5], cnt + 5, Hs[4], Wd[4], Hs[5], Wd[5], hbufB);

  // ---------- GRUs (fused conv pair + pointwise) ----------
  long ngb = 286720L * 4;
  hipMemsetAsync(h1d, 0, ngb, stream);
  hipMemsetAsync(h2d, 0, ngb, stream);
  gruconv_k<256><<<dim3((cap[5] + 15) / 16, 4), TPB, 0, stream>>>(
      hbufB, wt_g1g, wt_g1c, h1d, hbufA, inv[5], list[5], cnt + 5, Hs[5], Wd[5]);
  gruconv_k<256><<<dim3((cap[5] + 15) / 16, 4), TPB, 0, stream>>>(
      hbufA, wt_g2g, wt_g2c, h2d, nullptr, inv[5], list[5], cnt + 5, Hs[5], Wd[5]);

  // ---------- head ----------
  float* part = bufA;
  float* part2 = bufB;
  lin1_part2_k<<<dim3(KS, 4), TPB, 0, stream>>>(h2d, W1, part);
  lin1_reduce_k<<<nblk(32L * 1024), TPB, 0, stream>>>(part, b1, y1);
  lin2_part_k<<<dim3(nblk(32L * 420), JS2), TPB, 0, stream>>>(y1, W2, part2);
  lin2_fin_k<<<nblk(32L * 420), TPB, 0, stream>>>(part2, b2, (float*)d_out);
}

// Round 9
// 870.911 us; speedup vs baseline: 7.3556x; 1.0327x over previous
//
#include <hip/hip_runtime.h>
#include <stdint.h>

#define TPB 256

typedef _Float16 half_t;
typedef __attribute__((ext_vector_type(8))) _Float16 f16x8;
typedef __attribute__((ext_vector_type(4))) float f32x4;

static inline int nblk(long n) { return (int)((n + TPB - 1) / TPB); }
static inline int gmin(long a, long b) { return (int)(a < b ? a : b); }

// ---------- scan-based compaction ----------
__device__ __forceinline__ bool act0(const float* x, int i) {
  float2 v = *(const float2*)(x + 2L * i);
  return (v.x != 0.f) || (v.y != 0.f);
}

__global__ void cmpA0_k(const float* __restrict__ x, int n, int* __restrict__ bcnt) {
  int i = blockIdx.x * TPB + threadIdx.x;
  bool a = (i < n) && act0(x, i);
  unsigned long long bal = __ballot(a);
  __shared__ int wc[4];
  if ((threadIdx.x & 63) == 0) wc[threadIdx.x >> 6] = __popcll(bal);
  __syncthreads();
  if (threadIdx.x == 0) bcnt[blockIdx.x] = wc[0] + wc[1] + wc[2] + wc[3];
}

__global__ void cmpB0_k(const float* __restrict__ x, int n, const int* __restrict__ bbase,
                        int* __restrict__ list, int* __restrict__ inv, int cap) {
  int i = blockIdx.x * TPB + threadIdx.x;
  bool a = (i < n) && act0(x, i);
  unsigned long long bal = __ballot(a);
  __shared__ int wc[4];
  int wid = threadIdx.x >> 6, lane = threadIdx.x & 63;
  if (lane == 0) wc[wid] = __popcll(bal);
  __syncthreads();
  int base = bbase[blockIdx.x];
  for (int w = 0; w < wid; ++w) base += wc[w];
  if (i < n) {
    int pos = base + __popcll(bal & ((1ull << lane) - 1));
    if (a && pos < cap) { list[pos] = i; inv[i] = pos; }
    else inv[i] = -1;
  }
}

__device__ __forceinline__ bool actp(const int* invp, int Hp, int Wp, int Ho, int Wo, int i) {
  int wo = i % Wo; int t = i / Wo; int ho = t % Ho; int bb = t / Ho;
  long rb = ((long)bb * Hp + 2 * ho) * Wp + 2 * wo;
  bool a = false;
  #pragma unroll
  for (int kh = 0; kh < 3; ++kh)
    #pragma unroll
    for (int kw = 0; kw < 3; ++kw)
      a |= (invp[rb + kh * Wp + kw] >= 0);
  return a;
}

__global__ void poolA_k(const int* __restrict__ invp, int Hp, int Wp, int Ho, int Wo,
                        int n, int* __restrict__ bcnt) {
  int i = blockIdx.x * TPB + threadIdx.x;
  bool a = (i < n) && actp(invp, Hp, Wp, Ho, Wo, i);
  unsigned long long bal = __ballot(a);
  __shared__ int wc[4];
  if ((threadIdx.x & 63) == 0) wc[threadIdx.x >> 6] = __popcll(bal);
  __syncthreads();
  if (threadIdx.x == 0) bcnt[blockIdx.x] = wc[0] + wc[1] + wc[2] + wc[3];
}

__global__ void poolB_k(const int* __restrict__ invp, int Hp, int Wp, int Ho, int Wo, int n,
                        const int* __restrict__ bbase, int* __restrict__ list,
                        int* __restrict__ inv, int cap) {
  int i = blockIdx.x * TPB + threadIdx.x;
  bool a = (i < n) && actp(invp, Hp, Wp, Ho, Wo, i);
  unsigned long long bal = __ballot(a);
  __shared__ int wc[4];
  int wid = threadIdx.x >> 6, lane = threadIdx.x & 63;
  if (lane == 0) wc[wid] = __popcll(bal);
  __syncthreads();
  int base = bbase[blockIdx.x];
  for (int w = 0; w < wid; ++w) base += wc[w];
  if (i < n) {
    int pos = base + __popcll(bal & ((1ull << lane) - 1));
    if (a && pos < cap) { list[pos] = i; inv[i] = pos; }
    else inv[i] = -1;
  }
}

__global__ void scan_k(int* __restrict__ b, int n, int* __restrict__ total) {
  __shared__ int sh[1024];
  __shared__ int sc;
  if (threadIdx.x == 0) sc = 0;
  __syncthreads();
  for (int base = 0; base < n; base += 1024) {
    int i = base + threadIdx.x;
    int v = (i < n) ? b[i] : 0;
    sh[threadIdx.x] = v;
    __syncthreads();
    for (int o = 1; o < 1024; o <<= 1) {
      int t = (threadIdx.x >= o) ? sh[threadIdx.x - o] : 0;
      __syncthreads();
      sh[threadIdx.x] += t;
      __syncthreads();
    }
    if (i < n) b[i] = sh[threadIdx.x] - v + sc;
    __syncthreads();
    if (threadIdx.x == 0) sc += sh[1023];
    __syncthreads();
  }
  if (threadIdx.x == 0) *total = sc;
}

// ---------- pooled values -> f16 compact rows ----------
template <int C>
__global__ void pool_val_f16_k(const float* __restrict__ xin, const int* __restrict__ invp,
                               const int* __restrict__ list, const int* __restrict__ cnt,
                               int Hp, int Wp, int Ho, int Wo, half_t* __restrict__ y) {
  long total = (long)cnt[0] * C;
  for (long i = (long)blockIdx.x * TPB + threadIdx.x; i < total; i += (long)gridDim.x * TPB) {
    int c = (int)(i & (C - 1));
    int r = (int)(i / C);
    int site = list[r];
    int wo = site % Wo; int t = site / Wo; int ho = t % Ho; int bb = t / Ho;
    long rb = ((long)bb * Hp + 2 * ho) * Wp + 2 * wo;
    float best = -1e30f;
    #pragma unroll
    for (int kh = 0; kh < 3; ++kh)
      #pragma unroll
      for (int kw = 0; kw < 3; ++kw) {
        int j = invp[rb + kh * Wp + kw];
        if (j >= 0) best = fmaxf(best, xin[(long)j * C + c]);
      }
    y[i] = (half_t)best;
  }
}

// ---------- dense x -> f16 ----------
__global__ void cvt_x_k(const float* __restrict__ x, half_t* __restrict__ xh, long n) {
  for (long i = (long)blockIdx.x * TPB + threadIdx.x; i < n; i += (long)gridDim.x * TPB)
    xh[i] = (half_t)x[i];
}

// ---------- weight pack: W[tap][ci][co] f32 -> per-tap [tap][co][ci] f16 ----------
__global__ void wtr_k(const float* __restrict__ Wsrc, half_t* __restrict__ dst,
                      int CI, int CO, int wci, int wco) {
  long total = 9L * CO * CI;
  for (long i = (long)blockIdx.x * TPB + threadIdx.x; i < total; i += (long)gridDim.x * TPB) {
    int ci = (int)(i % CI);
    long t = i / CI;
    int co = (int)(t % CO);
    int tap = (int)(t / CO);
    dst[i] = (half_t)Wsrc[((long)tap * wci + ci) * wco + co];
  }
}

// ---------- weight pack: K-packed [co][KP] f16 ----------
__global__ void wtrp_k(const float* __restrict__ Wsrc, half_t* __restrict__ dst,
                       int CI, int CO, int KP, int wci, int wco) {
  long total = (long)CO * KP;
  for (long i = (long)blockIdx.x * TPB + threadIdx.x; i < total; i += (long)gridDim.x * TPB) {
    int k = (int)(i % KP);
    int co = (int)(i / KP);
    int tap = k / CI, ci = k - tap * CI;
    float v = (tap < 9) ? Wsrc[((long)tap * wci + ci) * wco + co] : 0.f;
    dst[i] = (half_t)v;
  }
}

// ---------- W1 transpose+convert: W1[8960][1024] f32 -> W1T[1024][8960] f16 ----------
__global__ void w1tr_k(const float* __restrict__ W1, half_t* __restrict__ w1t) {
  __shared__ float tile[64][65];
  int k0 = blockIdx.x * 64, j0 = blockIdx.y * 64;
  for (int i = threadIdx.x; i < 4096; i += TPB) {
    int r = i >> 6, c = i & 63;
    tile[r][c] = W1[(long)(k0 + r) * 1024 + j0 + c];
  }
  __syncthreads();
  for (int i = threadIdx.x; i < 4096; i += TPB) {
    int r = i >> 6, c = i & 63;
    w1t[(long)(j0 + r) * 8960 + k0 + c] = (half_t)tile[c][r];
  }
}

// ---------- K-packed MFMA conv (CO<=32); 64 sites/block ----------
template <int CI, int CO, bool DENSE>
__global__ __launch_bounds__(256) void mconvp_k(const half_t* __restrict__ X,
                                                const half_t* __restrict__ Wt,
                                                float* __restrict__ y,
                                                const int* __restrict__ inv,
                                                const int* __restrict__ list,
                                                const int* __restrict__ cnt,
                                                int H, int W) {
  constexpr int KP = ((9 * CI + 31) / 32) * 32;
  constexpr int NCO = CO / 16;
  const int nact = cnt[0];
  const int base = blockIdx.x * 64;
  if (base >= nact) return;
  __shared__ int nbr[64 * 9];
  for (int i = threadIdx.x; i < 64 * 9; i += TPB) {
    int s = i / 9, nb = i - s * 9;
    int j = -1;
    if (base + s < nact) {
      int site = list[base + s];
      int w = site % W; int t = site / W; int h = t % H; int bb = t / H;
      int hh = h + nb / 3 - 1, ww = w + nb % 3 - 1;
      if ((unsigned)hh < (unsigned)H && (unsigned)ww < (unsigned)W) {
        int ss = (bb * H + hh) * W + ww;
        j = DENSE ? ss : inv[ss];
      }
    }
    nbr[i] = j;
  }
  __syncthreads();
  const int lane = threadIdx.x & 63, wv = threadIdx.x >> 6;
  const int srow = lane & 15, kseg = lane >> 4;
  const int sloc = wv * 16 + srow;
  f32x4 acc[NCO];
  #pragma unroll
  for (int c = 0; c < NCO; ++c) acc[c] = (f32x4){0.f, 0.f, 0.f, 0.f};
  #pragma unroll
  for (int k0 = 0; k0 < KP; k0 += 32) {
    const int k = k0 + kseg * 8;
    f16x8 av;
    #pragma unroll
    for (int z = 0; z < 8; ++z) av[z] = (_Float16)0.f;
    if (CI >= 8) {
      int tap = k / CI;
      int ci = k - tap * CI;
      if (tap < 9) {
        int j = nbr[sloc * 9 + tap];
        if (j >= 0) av = *(const f16x8*)(X + (long)j * CI + ci);
      }
    } else {  // CI == 2
      #pragma unroll
      for (int q = 0; q < 4; ++q) {
        int kk = k + 2 * q;
        int tap = kk >> 1;
        if (tap < 9) {
          int j = nbr[sloc * 9 + tap];
          if (j >= 0) {
            const half_t* xp = X + (long)j * 2;
            av[2 * q] = xp[0];
            av[2 * q + 1] = xp[1];
          }
        }
      }
    }
    #pragma unroll
    for (int c = 0; c < NCO; ++c) {
      f16x8 bv = *(const f16x8*)(Wt + (long)(c * 16 + srow) * KP + k);
      acc[c] = __builtin_amdgcn_mfma_f32_16x16x32_f16(av, bv, acc[c], 0, 0, 0);
    }
  }
  #pragma unroll
  for (int c = 0; c < NCO; ++c)
    #pragma unroll
    for (int r = 0; r < 4; ++r) {
      int ss = base + wv * 16 + kseg * 4 + r;
      if (ss < nact) y[(long)ss * CO + c * 16 + srow] = acc[c][r];
    }
}

// ---------- mid-level MFMA conv: NG site-groups of 16 per wave ----------
template <int CI, int CO, int NG>
__global__ __launch_bounds__(256) void mconv2_k(const half_t* __restrict__ X,
                                                const half_t* __restrict__ Wt,
                                                float* __restrict__ y,
                                                const int* __restrict__ inv,
                                                const int* __restrict__ list,
                                                const int* __restrict__ cnt,
                                                int H, int W) {
  const int nact = cnt[0];
  const int base = blockIdx.x * (64 * NG);
  if (base >= nact) return;
  const int lane = threadIdx.x & 63, wv = threadIdx.x >> 6;
  const int srow = lane & 15, kseg = lane >> 4;
  const int co0 = blockIdx.y * 64;
  int jj[NG][9];
  #pragma unroll
  for (int g = 0; g < NG; ++g) {
    int s = base + (wv * NG + g) * 16 + srow;
    bool sv = (s < nact);
    int h = 0, w = 0, bb = 0;
    if (sv) {
      int site = list[s];
      w = site % W;
      int t = site / W;
      h = t % H;
      bb = t / H;
    }
    #pragma unroll
    for (int tap = 0; tap < 9; ++tap) {
      int j = -1;
      if (sv) {
        int hh = h + tap / 3 - 1, ww = w + tap % 3 - 1;
        if ((unsigned)hh < (unsigned)H && (unsigned)ww < (unsigned)W)
          j = inv[(bb * H + hh) * W + ww];
      }
      jj[g][tap] = j;
    }
  }
  f32x4 acc[NG][4];
  #pragma unroll
  for (int g = 0; g < NG; ++g)
    #pragma unroll
    for (int b = 0; b < 4; ++b) acc[g][b] = (f32x4){0.f, 0.f, 0.f, 0.f};
  #pragma unroll
  for (int tap = 0; tap < 9; ++tap) {
    const half_t* wp = Wt + ((long)tap * CO + co0 + srow) * CI + kseg * 8;
    #pragma unroll
    for (int k0 = 0; k0 < CI; k0 += 32) {
      f16x8 av[NG];
      #pragma unroll
      for (int g = 0; g < NG; ++g) {
        #pragma unroll
        for (int z = 0; z < 8; ++z) av[g][z] = (_Float16)0.f;
        if (jj[g][tap] >= 0)
          av[g] = *(const f16x8*)(X + (long)jj[g][tap] * CI + kseg * 8 + k0);
      }
      #pragma unroll
      for (int b = 0; b < 4; ++b) {
        f16x8 bv = *(const f16x8*)(wp + (long)b * 16 * CI + k0);
        #pragma unroll
        for (int g = 0; g < NG; ++g)
          acc[g][b] = __builtin_amdgcn_mfma_f32_16x16x32_f16(av[g], bv, acc[g][b], 0, 0, 0);
      }
    }
  }
  #pragma unroll
  for (int g = 0; g < NG; ++g)
    #pragma unroll
    for (int b = 0; b < 4; ++b)
      #pragma unroll
      for (int r = 0; r < 4; ++r) {
        int ss = base + (wv * NG + g) * 16 + kseg * 4 + r;
        if (ss < nact) y[(long)ss * CO + co0 + b * 16 + srow] = acc[g][b][r];
      }
}

// ---------- K-split deep conv: 16 sites x 64 co per block, 4 waves split taps ----------
template <int CI, int CO>
__global__ __launch_bounds__(256) void mconv_ks_k(const half_t* __restrict__ X,
                                                  const half_t* __restrict__ Wt,
                                                  float* __restrict__ y,
                                                  const int* __restrict__ inv,
                                                  const int* __restrict__ list,
                                                  const int* __restrict__ cnt,
                                                  int H, int W) {
  const int nact = cnt[0];
  const int base = blockIdx.x * 16;
  if (base >= nact) return;
  __shared__ int nbr[16 * 9];
  __shared__ float red[4][16][65];
  for (int i = threadIdx.x; i < 16 * 9; i += TPB) {
    int s = i / 9, nb = i - s * 9;
    int j = -1;
    if (base + s < nact) {
      int site = list[base + s];
      int w = site % W; int t = site / W; int h = t % H; int bb = t / H;
      int hh = h + nb / 3 - 1, ww = w + nb % 3 - 1;
      if ((unsigned)hh < (unsigned)H && (unsigned)ww < (unsigned)W)
        j = inv[(bb * H + hh) * W + ww];
    }
    nbr[i] = j;
  }
  __syncthreads();
  const int lane = threadIdx.x & 63, wv = threadIdx.x >> 6;
  const int srow = lane & 15, kseg = lane >> 4;
  const int co0 = blockIdx.y * 64;
  const int t0 = (wv * 9) / 4, t1 = ((wv + 1) * 9) / 4;
  f32x4 acc0 = {0.f, 0.f, 0.f, 0.f};
  f32x4 acc1 = acc0, acc2 = acc0, acc3 = acc0;
  for (int tap = t0; tap < t1; ++tap) {
    int j = nbr[srow * 9 + tap];
    const half_t* xp = X + (long)j * CI + kseg * 8;
    const half_t* wp = Wt + ((long)tap * CO + co0 + srow) * CI + kseg * 8;
    #pragma unroll
    for (int k0 = 0; k0 < CI; k0 += 32) {
      f16x8 av;
      #pragma unroll
      for (int z = 0; z < 8; ++z) av[z] = (_Float16)0.f;
      if (j >= 0) av = *(const f16x8*)(xp + k0);
      f16x8 b0 = *(const f16x8*)(wp + k0);
      f16x8 b1 = *(const f16x8*)(wp + 16 * CI + k0);
      f16x8 b2 = *(const f16x8*)(wp + 32 * CI + k0);
      f16x8 b3 = *(const f16x8*)(wp + 48 * CI + k0);
      acc0 = __builtin_amdgcn_mfma_f32_16x16x32_f16(av, b0, acc0, 0, 0, 0);
      acc1 = __builtin_amdgcn_mfma_f32_16x16x32_f16(av, b1, acc1, 0, 0, 0);
      acc2 = __builtin_amdgcn_mfma_f32_16x16x32_f16(av, b2, acc2, 0, 0, 0);
      acc3 = __builtin_amdgcn_mfma_f32_16x16x32_f16(av, b3, acc3, 0, 0, 0);
    }
  }
  #pragma unroll
  for (int r = 0; r < 4; ++r) {
    int s = kseg * 4 + r;
    red[wv][s][srow] = acc0[r];
    red[wv][s][16 + srow] = acc1[r];
    red[wv][s][32 + srow] = acc2[r];
    red[wv][s][48 + srow] = acc3[r];
  }
  __syncthreads();
  for (int i = threadIdx.x; i < 16 * 64; i += TPB) {
    int s = i >> 6, co = i & 63;
    float v = red[0][s][co] + red[1][s][co] + red[2][s][co] + red[3][s][co];
    int ss = base + s;
    if (ss < nact) y[(long)ss * CO + co0 + co] = v;
  }
}

// ---------- fused GRU conv: h=sigmoid(conv(X,Wg))*tanh(conv(X,Wc)) ----------
// dflat (optional): NCHW-flattened f16 dense vector for the MLP head.
template <int CI>
__global__ __launch_bounds__(256) void gruconv_k(const half_t* __restrict__ X,
                                                 const half_t* __restrict__ Wg,
                                                 const half_t* __restrict__ Wc,
                                                 float* __restrict__ hdense,
                                                 half_t* __restrict__ hcomp,
                                                 half_t* __restrict__ dflat,
                                                 const int* __restrict__ inv,
                                                 const int* __restrict__ list,
                                                 const int* __restrict__ cnt,
                                                 int H, int W) {
  constexpr int CO = 256;
  const int nact = cnt[0];
  const int base = blockIdx.x * 16;
  if (base >= nact) return;
  __shared__ int nbr[16 * 9];
  __shared__ float red[4][16][65];
  for (int i = threadIdx.x; i < 16 * 9; i += TPB) {
    int s = i / 9, nb = i - s * 9;
    int j = -1;
    if (base + s < nact) {
      int site = list[base + s];
      int w = site % W; int t = site / W; int h = t % H; int bb = t / H;
      int hh = h + nb / 3 - 1, ww = w + nb % 3 - 1;
      if ((unsigned)hh < (unsigned)H && (unsigned)ww < (unsigned)W)
        j = inv[(bb * H + hh) * W + ww];
    }
    nbr[i] = j;
  }
  __syncthreads();
  const int lane = threadIdx.x & 63, wv = threadIdx.x >> 6;
  const int srow = lane & 15, kseg = lane >> 4;
  const int co0 = blockIdx.y * 64;
  const int t0 = (wv * 9) / 4, t1 = ((wv + 1) * 9) / 4;
  f32x4 g0 = {0.f, 0.f, 0.f, 0.f};
  f32x4 g1 = g0, g2 = g0, g3 = g0, c0 = g0, c1 = g0, c2 = g0, c3 = g0;
  for (int tap = t0; tap < t1; ++tap) {
    int j = nbr[srow * 9 + tap];
    const half_t* xp = X + (long)j * CI + kseg * 8;
    const half_t* wgp = Wg + ((long)tap * CO + co0 + srow) * CI + kseg * 8;
    const half_t* wcp = Wc + ((long)tap * CO + co0 + srow) * CI + kseg * 8;
    #pragma unroll
    for (int k0 = 0; k0 < CI; k0 += 32) {
      f16x8 av;
      #pragma unroll
      for (int z = 0; z < 8; ++z) av[z] = (_Float16)0.f;
      if (j >= 0) av = *(const f16x8*)(xp + k0);
      f16x8 bg0 = *(const f16x8*)(wgp + k0);
      f16x8 bg1 = *(const f16x8*)(wgp + 16 * CI + k0);
      f16x8 bg2 = *(const f16x8*)(wgp + 32 * CI + k0);
      f16x8 bg3 = *(const f16x8*)(wgp + 48 * CI + k0);
      f16x8 bc0 = *(const f16x8*)(wcp + k0);
      f16x8 bc1 = *(const f16x8*)(wcp + 16 * CI + k0);
      f16x8 bc2 = *(const f16x8*)(wcp + 32 * CI + k0);
      f16x8 bc3 = *(const f16x8*)(wcp + 48 * CI + k0);
      g0 = __builtin_amdgcn_mfma_f32_16x16x32_f16(av, bg0, g0, 0, 0, 0);
      g1 = __builtin_amdgcn_mfma_f32_16x16x32_f16(av, bg1, g1, 0, 0, 0);
      g2 = __builtin_amdgcn_mfma_f32_16x16x32_f16(av, bg2, g2, 0, 0, 0);
      g3 = __builtin_amdgcn_mfma_f32_16x16x32_f16(av, bg3, g3, 0, 0, 0);
      c0 = __builtin_amdgcn_mfma_f32_16x16x32_f16(av, bc0, c0, 0, 0, 0);
      c1 = __builtin_amdgcn_mfma_f32_16x16x32_f16(av, bc1, c1, 0, 0, 0);
      c2 = __builtin_amdgcn_mfma_f32_16x16x32_f16(av, bc2, c2, 0, 0, 0);
      c3 = __builtin_amdgcn_mfma_f32_16x16x32_f16(av, bc3, c3, 0, 0, 0);
    }
  }
  #pragma unroll
  for (int r = 0; r < 4; ++r) {
    int s = kseg * 4 + r;
    red[wv][s][srow] = g0[r];
    red[wv][s][16 + srow] = g1[r];
    red[wv][s][32 + srow] = g2[r];
    red[wv][s][48 + srow] = g3[r];
  }
  __syncthreads();
  float gsum[4];
  #pragma unroll
  for (int q = 0; q < 4; ++q) {
    int i = threadIdx.x + q * TPB;
    int s = i >> 6, co = i & 63;
    gsum[q] = red[0][s][co] + red[1][s][co] + red[2][s][co] + red[3][s][co];
  }
  __syncthreads();
  #pragma unroll
  for (int r = 0; r < 4; ++r) {
    int s = kseg * 4 + r;
    red[wv][s][srow] = c0[r];
    red[wv][s][16 + srow] = c1[r];
    red[wv][s][32 + srow] = c2[r];
    red[wv][s][48 + srow] = c3[r];
  }
  __syncthreads();
  #pragma unroll
  for (int q = 0; q < 4; ++q) {
    int i = threadIdx.x + q * TPB;
    int s = i >> 6, co = i & 63;
    float cs = red[0][s][co] + red[1][s][co] + red[2][s][co] + red[3][s][co];
    int ss = base + s;
    if (ss < nact) {
      float u = 1.f / (1.f + expf(-gsum[q]));
      float v = u * tanhf(cs);
      if (hcomp) hcomp[(long)ss * CO + co0 + co] = (half_t)v;
      int site = list[ss];
      hdense[(long)site * CO + co0 + co] = v;
      if (dflat) {
        int b = site / 35, s2 = site - b * 35;
        dflat[(long)b * 8960 + (co0 + co) * 35 + s2] = (half_t)v;
      }
    }
  }
}

// ---------- BN ----------
template <int CO>
__global__ void bn_stats2_k(const float* __restrict__ y, const int* __restrict__ cnt,
                            float* __restrict__ stats) {
  __shared__ float ls[512];
  for (int i = threadIdx.x; i < 2 * CO; i += TPB) ls[i] = 0.f;
  __syncthreads();
  long total = (long)cnt[0] * CO;
  long i0 = (long)blockIdx.x * TPB + threadIdx.x;
  int c = (int)(i0 & (CO - 1));
  float s = 0.f, s2 = 0.f;
  for (long i = i0; i < total; i += (long)gridDim.x * TPB) {
    float v = y[i];
    s += v; s2 += v * v;
  }
  atomicAdd(&ls[c], s);
  atomicAdd(&ls[CO + c], s2);
  __syncthreads();
  for (int i = threadIdx.x; i < 2 * CO; i += TPB) atomicAdd(&stats[i], ls[i]);
}

__global__ void bn_fin_k(const float* __restrict__ stats, const int* __restrict__ cnt,
                         const float* __restrict__ gamma, const float* __restrict__ beta,
                         float* __restrict__ bnsc, int CO) {
  int c = threadIdx.x;
  if (c >= CO) return;
  float n = fmaxf((float)cnt[0], 1.f);
  float mean = stats[c] / n;
  float var = fmaxf(stats[CO + c] / n - mean * mean, 0.f);
  float sc = gamma[c] * rsqrtf(var + 1e-4f);
  bnsc[c] = sc;
  bnsc[CO + c] = beta[c] - mean * sc;
}

template <int C>
__global__ void bnapply_f16_k(const float* __restrict__ y, const int* __restrict__ cnt,
                              const float* __restrict__ bnsc, half_t* __restrict__ out) {
  long total = (long)cnt[0] * C;
  for (long i = (long)blockIdx.x * TPB + threadIdx.x; i < total; i += (long)gridDim.x * TPB) {
    int c = (int)(i & (C - 1));
    out[i] = (half_t)fmaxf(fmaf(y[i], bnsc[c], bnsc[C + c]), 0.f);
  }
}

// ---------- head: MFMA lin1 ----------
// D[32][8960] f16, W1T[1024][8960] f16; grid (35, 16); per-block K-chunk 256 (wave: 64).
#define KS1 35
__global__ __launch_bounds__(256) void lin1m_k(const half_t* __restrict__ D,
                                               const half_t* __restrict__ W1T,
                                               float* __restrict__ part) {
  __shared__ float red[4][32][65];
  const int lane = threadIdx.x & 63, wv = threadIdx.x >> 6;
  const int srow = lane & 15, kseg = lane >> 4;
  const int kc = blockIdx.x, j0 = blockIdx.y * 64;
  const int kbase = kc * 256 + wv * 64;
  f32x4 acc[2][4];
  #pragma unroll
  for (int m = 0; m < 2; ++m)
    #pragma unroll
    for (int b = 0; b < 4; ++b) acc[m][b] = (f32x4){0.f, 0.f, 0.f, 0.f};
  #pragma unroll
  for (int step = 0; step < 2; ++step) {
    int k = kbase + step * 32 + kseg * 8;
    f16x8 a0 = *(const f16x8*)(D + (long)srow * 8960 + k);
    f16x8 a1 = *(const f16x8*)(D + (long)(16 + srow) * 8960 + k);
    #pragma unroll
    for (int b = 0; b < 4; ++b) {
      f16x8 bv = *(const f16x8*)(W1T + (long)(j0 + b * 16 + srow) * 8960 + k);
      acc[0][b] = __builtin_amdgcn_mfma_f32_16x16x32_f16(a0, bv, acc[0][b], 0, 0, 0);
      acc[1][b] = __builtin_amdgcn_mfma_f32_16x16x32_f16(a1, bv, acc[1][b], 0, 0, 0);
    }
  }
  #pragma unroll
  for (int m = 0; m < 2; ++m)
    #pragma unroll
    for (int b = 0; b < 4; ++b)
      #pragma unroll
      for (int r = 0; r < 4; ++r)
        red[wv][m * 16 + kseg * 4 + r][b * 16 + srow] = acc[m][b][r];
  __syncthreads();
  for (int i = threadIdx.x; i < 32 * 64; i += TPB) {
    int row = i >> 6, col = i & 63;
    float v = red[0][row][col] + red[1][row][col] + red[2][row][col] + red[3][row][col];
    part[(long)kc * 32768 + row * 1024 + j0 + col] = v;
  }
}

__global__ void lin1_reduce_k(const float* __restrict__ part, const float* __restrict__ b1,
                              float* __restrict__ y1) {
  int i = blockIdx.x * TPB + threadIdx.x;
  if (i >= 32 * 1024) return;
  int b = i >> 10, j = i & 1023;
  float a = b1[j];
  #pragma unroll
  for (int kc = 0; kc < KS1; ++kc) a += part[(long)kc * 32768 + b * 1024 + j];
  y1[i] = fmaxf(a, 0.f);
}

#define JS2 8
__global__ void lin2_part_k(const float* __restrict__ y1, const float* __restrict__ W2,
                            float* __restrict__ part2) {
  int i = blockIdx.x * TPB + threadIdx.x;
  if (i >= 32 * 420) return;
  int b = i / 420, o = i - b * 420;
  int j0 = blockIdx.y * 128;
  float a = 0.f;
  const float* yp = y1 + b * 1024 + j0;
  const float* wp = W2 + (long)j0 * 420 + o;
  #pragma unroll 8
  for (int j = 0; j < 128; ++j) a = fmaf(yp[j], wp[(long)j * 420], a);
  part2[(long)blockIdx.y * 13440 + i] = a;
}

__global__ void lin2_fin_k(const float* __restrict__ part2, const float* __restrict__ b2,
                           float* __restrict__ out) {
  int i = blockIdx.x * TPB + threadIdx.x;
  if (i >= 32 * 420) return;
  int o = i % 420;
  float a = b2[o];
  #pragma unroll
  for (int js = 0; js < JS2; ++js) a += part2[(long)js * 13440 + i];
  out[i] = a;
}

extern "C" void kernel_launch(void* const* d_in, const int* in_sizes, int n_in,
                              void* d_out, int out_size, void* d_ws, size_t ws_size,
                              hipStream_t stream) {
  const float* x = (const float*)d_in[0];
  const float* ca[5] = {(const float*)d_in[2], (const float*)d_in[6], (const float*)d_in[10],
                        (const float*)d_in[14], (const float*)d_in[18]};
  const float* bg[5] = {(const float*)d_in[3], (const float*)d_in[7], (const float*)d_in[11],
                        (const float*)d_in[15], (const float*)d_in[19]};
  const float* bb[5] = {(const float*)d_in[4], (const float*)d_in[8], (const float*)d_in[12],
                        (const float*)d_in[16], (const float*)d_in[20]};
  const float* cb[5] = {(const float*)d_in[5], (const float*)d_in[9], (const float*)d_in[13],
                        (const float*)d_in[17], (const float*)d_in[21]};
  const float* g1Wg = (const float*)d_in[22];
  const float* g1Wc = (const float*)d_in[23];
  const float* g2Wg = (const float*)d_in[24];
  const float* g2Wc = (const float*)d_in[25];
  const float* W1 = (const float*)d_in[26];
  const float* b1 = (const float*)d_in[27];
  const float* W2 = (const float*)d_in[28];
  const float* b2 = (const float*)d_in[29];

  const int Hs[6] = {191, 95, 47, 23, 11, 5};
  const int Wd[6] = {255, 127, 63, 31, 15, 7};
  const long NS[6] = {1558560, 386080, 94752, 22816, 5280, 1120};
  const int cap[6] = {200000, 386080, 94752, 22816, 5280, 1120};

  float* ws = (float*)d_ws;
  const long BUF = 12354560;
  long off = 0;
  float* bufA = ws + off; off += BUF;
  float* bufB = ws + off; off += BUF;
  float* stats = ws + off; off += 512;
  float* bnsc = ws + off;  off += 512;
  float* y1 = ws + off;    off += 32L * 1024;

  half_t* hbase = (half_t*)(ws + off);
  long hoff = 0;
  half_t* hbufA = hbase + hoff; hoff += 6500000;
  half_t* hbufB = hbase + hoff; hoff += 6500000;
  half_t* xh = hbase + hoff;    hoff += 3117120;
  half_t* w1t = hbase + hoff;   hoff += 9175040;   // 1024 x 8960
  half_t* df16 = hbase + hoff;  hoff += 286720;    // 32 x 8960
  half_t* wp_ca0 = hbase + hoff; hoff += 16L * 32;
  half_t* wp_cb0 = hbase + hoff; hoff += 16L * 160;
  half_t* wp_ca1 = hbase + hoff; hoff += 32L * 160;
  half_t* wp_cb1 = hbase + hoff; hoff += 32L * 288;
  half_t* wt_ca2 = hbase + hoff; hoff += 9L * 64 * 32;
  half_t* wt_cb2 = hbase + hoff; hoff += 9L * 64 * 64;
  half_t* wt_ca3 = hbase + hoff; hoff += 9L * 128 * 64;
  half_t* wt_cb3 = hbase + hoff; hoff += 9L * 128 * 128;
  half_t* wt_ca4 = hbase + hoff; hoff += 9L * 256 * 128;
  half_t* wt_cb4 = hbase + hoff; hoff += 9L * 256 * 256;
  half_t* wt_g1g = hbase + hoff; hoff += 9L * 256 * 256;
  half_t* wt_g1c = hbase + hoff; hoff += 9L * 256 * 256;
  half_t* wt_g2g = hbase + hoff; hoff += 9L * 256 * 256;
  half_t* wt_g2c = hbase + hoff; hoff += 9L * 256 * 256;

  int* ip = (int*)(hbase + hoff);
  long ioff = 0;
  int* cnt = ip + ioff; ioff += 16;
  int* bcnt = ip + ioff; ioff += 8192;
  int* list[6]; int* inv[6];
  for (int l = 0; l < 6; ++l) { list[l] = ip + ioff; ioff += cap[l]; }
  for (int l = 0; l < 6; ++l) { inv[l] = ip + ioff; ioff += NS[l]; }
  size_t needed = (size_t)off * 4 + (size_t)hoff * 2 + (size_t)ioff * 4;
  if (ws_size < needed) return;

  float* h1d = (float*)d_out + 13440;
  float* h2d = h1d + 286720;

  // ---- weight packing ----
  wtrp_k<<<nblk(16L * 32), TPB, 0, stream>>>(ca[0], wp_ca0, 2, 16, 32, 2, 16);
  wtrp_k<<<nblk(16L * 160), TPB, 0, stream>>>(cb[0], wp_cb0, 16, 16, 160, 16, 16);
  wtrp_k<<<nblk(32L * 160), TPB, 0, stream>>>(ca[1], wp_ca1, 16, 32, 160, 16, 32);
  wtrp_k<<<nblk(32L * 288), TPB, 0, stream>>>(cb[1], wp_cb1, 32, 32, 288, 32, 32);
  wtr_k<<<nblk(9L * 64 * 32), TPB, 0, stream>>>(ca[2], wt_ca2, 32, 64, 32, 64);
  wtr_k<<<nblk(9L * 64 * 64), TPB, 0, stream>>>(cb[2], wt_cb2, 64, 64, 64, 64);
  wtr_k<<<nblk(9L * 128 * 64), TPB, 0, stream>>>(ca[3], wt_ca3, 64, 128, 64, 128);
  wtr_k<<<nblk(9L * 128 * 128), TPB, 0, stream>>>(cb[3], wt_cb3, 128, 128, 128, 128);
  wtr_k<<<nblk(9L * 256 * 128), TPB, 0, stream>>>(ca[4], wt_ca4, 128, 256, 128, 256);
  wtr_k<<<gmin(nblk(9L * 256 * 256), 2048), TPB, 0, stream>>>(cb[4], wt_cb4, 256, 256, 256, 256);
  wtr_k<<<gmin(nblk(9L * 256 * 256), 2048), TPB, 0, stream>>>(g1Wg, wt_g1g, 256, 256, 512, 512);
  wtr_k<<<gmin(nblk(9L * 256 * 256), 2048), TPB, 0, stream>>>(g1Wc, wt_g1c, 256, 256, 512, 256);
  wtr_k<<<gmin(nblk(9L * 256 * 256), 2048), TPB, 0, stream>>>(g2Wg, wt_g2g, 256, 256, 512, 512);
  wtr_k<<<gmin(nblk(9L * 256 * 256), 2048), TPB, 0, stream>>>(g2Wc, wt_g2c, 256, 256, 512, 256);
  w1tr_k<<<dim3(140, 16), TPB, 0, stream>>>(W1, w1t);
  cvt_x_k<<<4096, TPB, 0, stream>>>(x, xh, 3117120);

  // ---- level-0 compaction ----
  {
    int nb = nblk(NS[0]);
    cmpA0_k<<<nb, TPB, 0, stream>>>(x, (int)NS[0], bcnt);
    scan_k<<<1, 1024, 0, stream>>>(bcnt, nb, cnt + 0);
    cmpB0_k<<<nb, TPB, 0, stream>>>(x, (int)NS[0], bcnt, list[0], inv[0], cap[0]);
  }

  // ---------- level 1 (MFMA, K-packed) ----------
  hipMemsetAsync(stats, 0, 512 * 4, stream);
  mconvp_k<2, 16, true><<<(cap[0] + 63) / 64, TPB, 0, stream>>>(
      xh, wp_ca0, bufA, nullptr, list[0], cnt + 0, Hs[0], Wd[0]);
  bn_stats2_k<16><<<1024, TPB, 0, stream>>>(bufA, cnt + 0, stats);
  bn_fin_k<<<1, 256, 0, stream>>>(stats, cnt + 0, bg[0], bb[0], bnsc, 16);
  bnapply_f16_k<16><<<2048, TPB, 0, stream>>>(bufA, cnt + 0, bnsc, hbufA);
  mconvp_k<16, 16, false><<<(cap[0] + 63) / 64, TPB, 0, stream>>>(
      hbufA, wp_cb0, bufB, inv[0], list[0], cnt + 0, Hs[0], Wd[0]);
  {
    int nb = nblk(NS[1]);
    poolA_k<<<nb, TPB, 0, stream>>>(inv[0], Hs[0], Wd[0], Hs[1], Wd[1], (int)NS[1], bcnt);
    scan_k<<<1, 1024, 0, stream>>>(bcnt, nb, cnt + 1);
    poolB_k<<<nb, TPB, 0, stream>>>(inv[0], Hs[0], Wd[0], Hs[1], Wd[1], (int)NS[1], bcnt,
                                    list[1], inv[1], cap[1]);
  }
  pool_val_f16_k<16><<<2048, TPB, 0, stream>>>(bufB, inv[0], list[1], cnt + 1, Hs[0], Wd[0], Hs[1], Wd[1], hbufB);

  // ---------- level 2 (MFMA, K-packed) ----------
  hipMemsetAsync(stats, 0, 512 * 4, stream);
  mconvp_k<16, 32, false><<<(cap[1] + 63) / 64, TPB, 0, stream>>>(
      hbufB, wp_ca1, bufB, inv[1], list[1], cnt + 1, Hs[1], Wd[1]);
  bn_stats2_k<32><<<1024, TPB, 0, stream>>>(bufB, cnt + 1, stats);
  bn_fin_k<<<1, 256, 0, stream>>>(stats, cnt + 1, bg[1], bb[1], bnsc, 32);
  bnapply_f16_k<32><<<2048, TPB, 0, stream>>>(bufB, cnt + 1, bnsc, hbufA);
  mconvp_k<32, 32, false><<<(cap[1] + 63) / 64, TPB, 0, stream>>>(
      hbufA, wp_cb1, bufA, inv[1], list[1], cnt + 1, Hs[1], Wd[1]);
  {
    int nb = nblk(NS[2]);
    poolA_k<<<nb, TPB, 0, stream>>>(inv[1], Hs[1], Wd[1], Hs[2], Wd[2], (int)NS[2], bcnt);
    scan_k<<<1, 1024, 0, stream>>>(bcnt, nb, cnt + 2);
    poolB_k<<<nb, TPB, 0, stream>>>(inv[1], Hs[1], Wd[1], Hs[2], Wd[2], (int)NS[2], bcnt,
                                    list[2], inv[2], cap[2]);
  }
  pool_val_f16_k<32><<<2048, TPB, 0, stream>>>(bufA, inv[1], list[2], cnt + 2, Hs[1], Wd[1], Hs[2], Wd[2], hbufB);

  // ---------- level 3 (MFMA) ----------
  hipMemsetAsync(stats, 0, 512 * 4, stream);
  mconv2_k<32, 64, 2><<<dim3((cap[2] + 127) / 128, 1), TPB, 0, stream>>>(
      hbufB, wt_ca2, bufA, inv[2], list[2], cnt + 2, Hs[2], Wd[2]);
  bn_stats2_k<64><<<1024, TPB, 0, stream>>>(bufA, cnt + 2, stats);
  bn_fin_k<<<1, 256, 0, stream>>>(stats, cnt + 2, bg[2], bb[2], bnsc, 64);
  bnapply_f16_k<64><<<2048, TPB, 0, stream>>>(bufA, cnt + 2, bnsc, hbufA);
  mconv2_k<64, 64, 2><<<dim3((cap[2] + 127) / 128, 1), TPB, 0, stream>>>(
      hbufA, wt_cb2, bufB, inv[2], list[2], cnt + 2, Hs[2], Wd[2]);
  {
    int nb = nblk(NS[3]);
    poolA_k<<<nb, TPB, 0, stream>>>(inv[2], Hs[2], Wd[2], Hs[3], Wd[3], (int)NS[3], bcnt);
    scan_k<<<1, 1024, 0, stream>>>(bcnt, nb, cnt + 3);
    poolB_k<<<nb, TPB, 0, stream>>>(inv[2], Hs[2], Wd[2], Hs[3], Wd[3], (int)NS[3], bcnt,
                                    list[3], inv[3], cap[3]);
  }
  pool_val_f16_k<64><<<2048, TPB, 0, stream>>>(bufB, inv[2], list[3], cnt + 3, Hs[2], Wd[2], Hs[3], Wd[3], hbufB);

  // ---------- level 4 (MFMA) ----------
  hipMemsetAsync(stats, 0, 512 * 4, stream);
  mconv2_k<64, 128, 1><<<dim3((cap[3] + 63) / 64, 2), TPB, 0, stream>>>(
      hbufB, wt_ca3, bufA, inv[3], list[3], cnt + 3, Hs[3], Wd[3]);
  bn_stats2_k<128><<<1024, TPB, 0, stream>>>(bufA, cnt + 3, stats);
  bn_fin_k<<<1, 256, 0, stream>>>(stats, cnt + 3, bg[3], bb[3], bnsc, 128);
  bnapply_f16_k<128><<<2048, TPB, 0, stream>>>(bufA, cnt + 3, bnsc, hbufA);
  mconv2_k<128, 128, 1><<<dim3((cap[3] + 63) / 64, 2), TPB, 0, stream>>>(
      hbufA, wt_cb3, bufB, inv[3], list[3], cnt + 3, Hs[3], Wd[3]);
  {
    int nb = nblk(NS[4]);
    poolA_k<<<nb, TPB, 0, stream>>>(inv[3], Hs[3], Wd[3], Hs[4], Wd[4], (int)NS[4], bcnt);
    scan_k<<<1, 1024, 0, stream>>>(bcnt, nb, cnt + 4);
    poolB_k<<<nb, TPB, 0, stream>>>(inv[3], Hs[3], Wd[3], Hs[4], Wd[4], (int)NS[4], bcnt,
                                    list[4], inv[4], cap[4]);
  }
  pool_val_f16_k<128><<<2048, TPB, 0, stream>>>(bufB, inv[3], list[4], cnt + 4, Hs[3], Wd[3], Hs[4], Wd[4], hbufB);

  // ---------- level 5 (MFMA, K-split 16-site tiles) ----------
  hipMemsetAsync(stats, 0, 512 * 4, stream);
  mconv_ks_k<128, 256><<<dim3((cap[4] + 15) / 16, 4), TPB, 0, stream>>>(
      hbufB, wt_ca4, bufA, inv[4], list[4], cnt + 4, Hs[4], Wd[4]);
  bn_stats2_k<256><<<1024, TPB, 0, stream>>>(bufA, cnt + 4, stats);
  bn_fin_k<<<1, 256, 0, stream>>>(stats, cnt + 4, bg[4], bb[4], bnsc, 256);
  bnapply_f16_k<256><<<2048, TPB, 0, stream>>>(bufA, cnt + 4, bnsc, hbufA);
  mconv_ks_k<256, 256><<<dim3((cap[4] + 15) / 16, 4), TPB, 0, stream>>>(
      hbufA, wt_cb4, bufB, inv[4], list[4], cnt + 4, Hs[4], Wd[4]);
  {
    int nb = nblk(NS[5]);
    poolA_k<<<nb, TPB, 0, stream>>>(inv[4], Hs[4], Wd[4], Hs[5], Wd[5], (int)NS[5], bcnt);
    scan_k<<<1, 1024, 0, stream>>>(bcnt, nb, cnt + 5);
    poolB_k<<<nb, TPB, 0, stream>>>(inv[4], Hs[4], Wd[4], Hs[5], Wd[5], (int)NS[5], bcnt,
                                    list[5], inv[5], cap[5]);
  }
  pool_val_f16_k<256><<<1024, TPB, 0, stream>>>(bufB, inv[4], list[5], cnt + 5, Hs[4], Wd[4], Hs[5], Wd[5], hbufB);

  // ---------- GRUs (fused conv pair + pointwise) ----------
  long ngb = 286720L * 4;
  hipMemsetAsync(h1d, 0, ngb, stream);
  hipMemsetAsync(h2d, 0, ngb, stream);
  hipMemsetAsync(df16, 0, 286720 * 2, stream);
  gruconv_k<256><<<dim3((cap[5] + 15) / 16, 4), TPB, 0, stream>>>(
      hbufB, wt_g1g, wt_g1c, h1d, hbufA, nullptr, inv[5], list[5], cnt + 5, Hs[5], Wd[5]);
  gruconv_k<256><<<dim3((cap[5] + 15) / 16, 4), TPB, 0, stream>>>(
      hbufA, wt_g2g, wt_g2c, h2d, nullptr, df16, inv[5], list[5], cnt + 5, Hs[5], Wd[5]);

  // ---------- head (MFMA lin1) ----------
  float* part = bufA;    // KS1*32*1024 = 1,146,880 floats
  float* part2 = bufB;
  lin1m_k<<<dim3(KS1, 16), TPB, 0, stream>>>(df16, w1t, part);
  lin1_reduce_k<<<nblk(32L * 1024), TPB, 0, stream>>>(part, b1, y1);
  lin2_part_k<<<dim3(nblk(32L * 420), JS2), TPB, 0, stream>>>(y1, W2, part2);
  lin2_fin_k<<<nblk(32L * 420), TPB, 0, stream>>>(part2, b2, (float*)d_out);
}